// Round 3
// baseline (3115.816 us; speedup 1.0000x reference)
//
#include <hip/hip_runtime.h>
#include <stdint.h>

typedef __attribute__((ext_vector_type(8))) short short8;
typedef __attribute__((ext_vector_type(4))) float floatx4;

__device__ __forceinline__ float bf2f(unsigned int u) {
  union { unsigned int i; float f; } x;
  x.i = u << 16;
  return x.f;
}

__device__ __forceinline__ unsigned short f2bf(float f) {
  union { float f; unsigned int u; } x; x.f = f;
  unsigned int r = x.u + 0x7fffu + ((x.u >> 16) & 1u);
  return (unsigned short)(r >> 16);
}

__device__ __forceinline__ float wave_sum(float v) {
  #pragma unroll
  for (int m = 32; m > 0; m >>= 1) v += __shfl_xor(v, m, 64);
  return v;
}

__device__ __forceinline__ float wave_max(float v) {
  #pragma unroll
  for (int m = 32; m > 0; m >>= 1) v = fmaxf(v, __shfl_xor(v, m, 64));
  return v;
}

// -------- dtype detection: flags[0]=edges int64, flags[1]=floats fp32 --------

__global__ void detect_kernel(const int* __restrict__ ei, const unsigned int* __restrict__ w1,
                              int* __restrict__ flags, int E) {
  __shared__ int nz, sane;
  if (threadIdx.x == 0) { nz = 0; sane = 0; }
  __syncthreads();
  for (int i = threadIdx.x; i < 2048; i += blockDim.x) {
    // edges: int64 little-endian => odd int32 words are high words == 0
    if (i < E && ei[2 * i + 1] != 0) atomicAdd(&nz, 1);
    // floats: fp32 N(0,0.05) words are "sane" magnitudes; bf16-pairs decode to 2^±115
    union { unsigned int u; float f; } c; c.u = w1[i];
    float af = fabsf(c.f);
    if (c.f == c.f && af > 1e-10f && af < 1e10f) atomicAdd(&sane, 1);
  }
  __syncthreads();
  if (threadIdx.x == 0) {
    flags[0] = (nz == 0) ? 1 : 0;
    flags[1] = (sane > 1024) ? 1 : 0;
  }
}

__global__ void normalize_kernel(const int* __restrict__ ei, const int* __restrict__ flags,
                                 int* __restrict__ srcN, int* __restrict__ dstN,
                                 int E, int N) {
  int e = blockIdx.x * blockDim.x + threadIdx.x;
  if (e >= E) return;
  int s, d;
  if (flags[0]) { s = ei[2 * e]; d = ei[2 * (E + e)]; }
  else          { s = ei[e];     d = ei[E + e]; }
  srcN[e] = ((unsigned)s < (unsigned)N) ? s : 0;
  dstN[e] = ((unsigned)d < (unsigned)N) ? d : 0;
}

// ---------------- CSR build (by dst) ----------------

__global__ void count_kernel(const int* __restrict__ dst, int* __restrict__ cnt, int E) {
  int e = blockIdx.x * blockDim.x + threadIdx.x;
  if (e < E) atomicAdd(&cnt[dst[e]], 1);
}

__global__ void scan_kernel(const int* __restrict__ cnt, int* __restrict__ off, int n) {
  __shared__ int buf[1024];
  __shared__ int carry;
  int t = threadIdx.x;
  if (t == 0) { carry = 0; off[0] = 0; }
  __syncthreads();
  for (int base = 0; base < n; base += 1024) {
    int i = base + t;
    int v = (i < n) ? cnt[i] : 0;
    buf[t] = v;
    __syncthreads();
    for (int ofs = 1; ofs < 1024; ofs <<= 1) {
      int add = (t >= ofs) ? buf[t - ofs] : 0;
      __syncthreads();
      buf[t] += add;
      __syncthreads();
    }
    if (i < n) off[i + 1] = carry + buf[t];
    __syncthreads();
    if (t == 0) carry += buf[1023];
    __syncthreads();
  }
}

__global__ void copy_kernel(const int* __restrict__ off, int* __restrict__ cur, int n) {
  int i = blockIdx.x * blockDim.x + threadIdx.x;
  if (i < n) cur[i] = off[i];
}

__global__ void fill_kernel(const int* __restrict__ dst, int* __restrict__ cur,
                            int* __restrict__ eid, int E) {
  int e = blockIdx.x * blockDim.x + threadIdx.x;
  if (e < E) {
    int pos = atomicAdd(&cur[dst[e]], 1);
    eid[pos] = e;
  }
}

// ---------------- attention stages, layer 1 (dual-dtype input) ----------------

__global__ __launch_bounds__(256) void norm8_kernel(const unsigned short* __restrict__ hb,
                                                    const float* __restrict__ hf,
                                                    const int* __restrict__ flags,
                                                    float* __restrict__ invn, int n) {
  int wid = blockIdx.x * (blockDim.x >> 6) + (threadIdx.x >> 6);
  int lane = threadIdx.x & 63;
  if (wid >= n) return;
  int f32 = flags[1];
  float s = 0.f;
  if (f32) {
    const float4* vp = reinterpret_cast<const float4*>(hf + (size_t)wid * 512) + lane * 2;
    float4 a = vp[0], b = vp[1];
    s = a.x*a.x + a.y*a.y + a.z*a.z + a.w*a.w + b.x*b.x + b.y*b.y + b.z*b.z + b.w*b.w;
  } else {
    uint4 v = *(reinterpret_cast<const uint4*>(hb + (size_t)wid * 512) + lane);
    unsigned int a[4] = {v.x, v.y, v.z, v.w};
    #pragma unroll
    for (int i = 0; i < 4; i++) {
      float lo = bf2f(a[i] & 0xffffu), hi = bf2f(a[i] >> 16);
      s += lo * lo + hi * hi;
    }
  }
  s = wave_sum(s);
  if (lane == 0) invn[wid] = (s == 0.f) ? 1.0f : rsqrtf(s);
}

__global__ __launch_bounds__(256) void sim8_kernel(const unsigned short* __restrict__ hb,
                                                   const float* __restrict__ hf,
                                                   const int* __restrict__ flags,
                                                   const int* __restrict__ src,
                                                   const int* __restrict__ dst,
                                                   const float* __restrict__ invn,
                                                   float* __restrict__ w,
                                                   float* __restrict__ rowsum,
                                                   float* __restrict__ degcnt, int E) {
  int e = blockIdx.x * (blockDim.x >> 6) + (threadIdx.x >> 6);
  int lane = threadIdx.x & 63;
  if (e >= E) return;
  int f32 = flags[1];
  int s = src[e], t = dst[e];
  float acc = 0.f;
  if (f32) {
    const float4* ap = reinterpret_cast<const float4*>(hf + (size_t)s * 512) + lane * 2;
    const float4* bp = reinterpret_cast<const float4*>(hf + (size_t)t * 512) + lane * 2;
    float4 a0 = ap[0], a1 = ap[1], b0 = bp[0], b1 = bp[1];
    acc = a0.x*b0.x + a0.y*b0.y + a0.z*b0.z + a0.w*b0.w
        + a1.x*b1.x + a1.y*b1.y + a1.z*b1.z + a1.w*b1.w;
  } else {
    uint4 a = *(reinterpret_cast<const uint4*>(hb + (size_t)s * 512) + lane);
    uint4 b = *(reinterpret_cast<const uint4*>(hb + (size_t)t * 512) + lane);
    unsigned int av[4] = {a.x, a.y, a.z, a.w};
    unsigned int bv[4] = {b.x, b.y, b.z, b.w};
    #pragma unroll
    for (int i = 0; i < 4; i++)
      acc += bf2f(av[i] & 0xffffu) * bf2f(bv[i] & 0xffffu)
           + bf2f(av[i] >> 16) * bf2f(bv[i] >> 16);
  }
  acc = wave_sum(acc);
  if (lane == 0) {
    float simv = acc * invn[s] * invn[t];
    float wv = (s != t && simv > 0.f) ? simv : 0.f;
    w[e] = wv;
    if (wv > 0.f) {
      atomicAdd(&rowsum[s], wv);
      atomicAdd(&degcnt[s], 1.0f);
    }
  }
}

// ---------------- attention stages, layers 2/3 (bf16 internal) ----------------

template<int EPL>
__global__ __launch_bounds__(256) void norm_kernel(const unsigned short* __restrict__ h,
                                                   float* __restrict__ invn, int n) {
  int wid = blockIdx.x * (blockDim.x >> 6) + (threadIdx.x >> 6);
  int lane = threadIdx.x & 63;
  if (wid >= n) return;
  float s = 0.f;
  if constexpr (EPL == 4) {
    uint2 v = *(reinterpret_cast<const uint2*>(h + (size_t)wid * 256) + lane);
    unsigned int a[2] = {v.x, v.y};
    #pragma unroll
    for (int i = 0; i < 2; i++) {
      float lo = bf2f(a[i] & 0xffffu), hi = bf2f(a[i] >> 16);
      s += lo * lo + hi * hi;
    }
  } else {
    float v0 = bf2f((unsigned int)h[(size_t)wid * 64 + lane]);
    s = v0 * v0;
  }
  s = wave_sum(s);
  if (lane == 0) invn[wid] = (s == 0.f) ? 1.0f : rsqrtf(s);
}

template<int EPL>
__global__ __launch_bounds__(256) void sim_kernel(const unsigned short* __restrict__ h,
                                                  const int* __restrict__ src,
                                                  const int* __restrict__ dst,
                                                  const float* __restrict__ invn,
                                                  float* __restrict__ w,
                                                  float* __restrict__ rowsum,
                                                  float* __restrict__ degcnt, int E) {
  int e = blockIdx.x * (blockDim.x >> 6) + (threadIdx.x >> 6);
  int lane = threadIdx.x & 63;
  if (e >= E) return;
  int s = src[e], t = dst[e];
  float acc = 0.f;
  if constexpr (EPL == 4) {
    uint2 a = *(reinterpret_cast<const uint2*>(h + (size_t)s * 256) + lane);
    uint2 b = *(reinterpret_cast<const uint2*>(h + (size_t)t * 256) + lane);
    unsigned int av[2] = {a.x, a.y};
    unsigned int bv[2] = {b.x, b.y};
    #pragma unroll
    for (int i = 0; i < 2; i++)
      acc += bf2f(av[i] & 0xffffu) * bf2f(bv[i] & 0xffffu)
           + bf2f(av[i] >> 16) * bf2f(bv[i] >> 16);
  } else {
    acc = bf2f((unsigned int)h[(size_t)s * 64 + lane]) *
          bf2f((unsigned int)h[(size_t)t * 64 + lane]);
  }
  acc = wave_sum(acc);
  if (lane == 0) {
    float simv = acc * invn[s] * invn[t];
    float wv = (s != t && simv > 0.f) ? simv : 0.f;
    w[e] = wv;
    if (wv > 0.f) {
      atomicAdd(&rowsum[s], wv);
      atomicAdd(&degcnt[s], 1.0f);
    }
  }
}

__global__ void node_a_kernel(float* __restrict__ rowsum, const float* __restrict__ degcnt,
                              float* __restrict__ sw, float* __restrict__ deg2, int n) {
  int i = blockIdx.x * blockDim.x + threadIdx.x;
  if (i >= n) return;
  float rs = rowsum[i];
  rowsum[i] = (rs > 0.f) ? 1.0f / rs : 0.0f;
  float lam = 1.0f / (degcnt[i] + 1.0f);
  float s = expf(lam);
  sw[i] = s;
  deg2[i] = s;
}

__global__ void edge_b_kernel(float* __restrict__ w, const int* __restrict__ src,
                              const int* __restrict__ dst, const float* __restrict__ invrs,
                              float* __restrict__ deg2, int E) {
  int e = blockIdx.x * blockDim.x + threadIdx.x;
  if (e >= E) return;
  float wv = w[e];
  if (wv > 0.f) {
    float ewv = expf(wv * invrs[src[e]]);
    w[e] = ewv;
    atomicAdd(&deg2[dst[e]], ewv);
  }
}

__global__ void node_b_kernel(const float* __restrict__ deg2, float* __restrict__ dinv, int n) {
  int i = blockIdx.x * blockDim.x + threadIdx.x;
  if (i < n) dinv[i] = rsqrtf(deg2[i]);
}

// ---------------- GEMM ----------------

__global__ void transpose_kernel(const unsigned short* __restrict__ Wb,
                                 const float* __restrict__ Wf,
                                 const int* __restrict__ flags,
                                 unsigned short* __restrict__ WT,
                                 int K, int Nc, int Npad) {
  int idx = blockIdx.x * blockDim.x + threadIdx.x;
  if (idx >= Npad * K) return;
  int nn = idx / K, k = idx - nn * K;
  unsigned short v = 0;
  if (nn < Nc) {
    if (flags[1]) v = f2bf(Wf[(size_t)k * Nc + nn]);
    else          v = Wb[(size_t)k * Nc + nn];
  }
  WT[idx] = v;
}

// layer 1: dual-dtype A
__global__ __launch_bounds__(256) void gemm1_kernel(const unsigned short* __restrict__ Ab,
                                                    const float* __restrict__ Af,
                                                    const int* __restrict__ flags,
                                                    const unsigned short* __restrict__ BT,
                                                    unsigned short* __restrict__ C,
                                                    int M, int K, int Npad) {
  int wv = threadIdx.x >> 6;
  int lane = threadIdx.x & 63;
  int mt = blockIdx.y * 4 + wv;
  if (mt * 16 >= M) return;
  int f32 = flags[1];
  int m0 = mt * 16, n0 = blockIdx.x * 16;
  int r = lane & 15, quad = lane >> 4;
  const short8* bp = reinterpret_cast<const short8*>(BT + (size_t)(n0 + r) * K);
  floatx4 acc = {0.f, 0.f, 0.f, 0.f};
  const int ksteps = K >> 5;
  if (f32) {
    const float* arow = Af + (size_t)(m0 + r) * K + quad * 8;
    for (int kk = 0; kk < ksteps; kk++) {
      float4 x0 = *reinterpret_cast<const float4*>(arow + kk * 32);
      float4 x1 = *reinterpret_cast<const float4*>(arow + kk * 32 + 4);
      short8 a;
      a[0] = (short)f2bf(x0.x); a[1] = (short)f2bf(x0.y);
      a[2] = (short)f2bf(x0.z); a[3] = (short)f2bf(x0.w);
      a[4] = (short)f2bf(x1.x); a[5] = (short)f2bf(x1.y);
      a[6] = (short)f2bf(x1.z); a[7] = (short)f2bf(x1.w);
      short8 b = bp[(kk << 2) + quad];
      acc = __builtin_amdgcn_mfma_f32_16x16x32_bf16(a, b, acc, 0, 0, 0);
    }
  } else {
    const short8* ap = reinterpret_cast<const short8*>(Ab + (size_t)(m0 + r) * K);
    for (int kk = 0; kk < ksteps; kk++) {
      short8 a = ap[(kk << 2) + quad];
      short8 b = bp[(kk << 2) + quad];
      acc = __builtin_amdgcn_mfma_f32_16x16x32_bf16(a, b, acc, 0, 0, 0);
    }
  }
  #pragma unroll
  for (int i = 0; i < 4; i++) {
    int row = quad * 4 + i;
    C[(size_t)(m0 + row) * Npad + n0 + r] = f2bf(acc[i]);
  }
}

// layers 2/3: bf16 A
__global__ __launch_bounds__(256) void gemm_kernel(const unsigned short* __restrict__ A,
                                                   const unsigned short* __restrict__ BT,
                                                   unsigned short* __restrict__ C,
                                                   int M, int K, int Npad) {
  int wv = threadIdx.x >> 6;
  int lane = threadIdx.x & 63;
  int mt = blockIdx.y * 4 + wv;
  if (mt * 16 >= M) return;
  int m0 = mt * 16, n0 = blockIdx.x * 16;
  int r = lane & 15, quad = lane >> 4;
  const short8* ap = reinterpret_cast<const short8*>(A + (size_t)(m0 + r) * K);
  const short8* bp = reinterpret_cast<const short8*>(BT + (size_t)(n0 + r) * K);
  floatx4 acc = {0.f, 0.f, 0.f, 0.f};
  const int ksteps = K >> 5;
  for (int kk = 0; kk < ksteps; kk++) {
    short8 a = ap[(kk << 2) + quad];
    short8 b = bp[(kk << 2) + quad];
    acc = __builtin_amdgcn_mfma_f32_16x16x32_bf16(a, b, acc, 0, 0, 0);
  }
  #pragma unroll
  for (int i = 0; i < 4; i++) {
    int row = quad * 4 + i;
    C[(size_t)(m0 + row) * Npad + n0 + r] = f2bf(acc[i]);
  }
}

// ---------------- aggregation (CSR by dst) ----------------

template<int BLK, int NC, int STRIDE>
__global__ __launch_bounds__(BLK) void agg_relu_kernel(
    const unsigned short* __restrict__ hp, const float* __restrict__ ew,
    const int* __restrict__ src, const int* __restrict__ off,
    const int* __restrict__ eid, const float* __restrict__ dinv,
    const float* __restrict__ sw, const unsigned short* __restrict__ biasb,
    const float* __restrict__ biasf, const int* __restrict__ flags,
    unsigned short* __restrict__ out, int n) {
  int i = blockIdx.x;
  if (i >= n) return;
  int c = threadIdx.x;
  __shared__ float scoef[BLK];
  __shared__ int ssrc[BLK];
  float di = dinv[i];
  float acc = 0.f;
  if (c < NC) acc = sw[i] * di * di * bf2f((unsigned int)hp[(size_t)i * STRIDE + c]);
  int e0 = off[i], e1 = off[i + 1];
  for (int base = e0; base < e1; base += BLK) {
    int j = base + c;
    if (j < e1) {
      int e = eid[j];
      int s = src[e];
      ssrc[c] = s;
      scoef[c] = ew[e] * dinv[s] * di;
    }
    __syncthreads();
    int m = min(BLK, e1 - base);
    for (int k = 0; k < m; k++) {
      float cf = scoef[k];
      if (cf != 0.f && c < NC)
        acc += cf * bf2f((unsigned int)hp[(size_t)ssrc[k] * STRIDE + c]);
    }
    __syncthreads();
  }
  if (c < NC) {
    float bb = flags[1] ? biasf[c] : bf2f((unsigned int)biasb[c]);
    float v = acc + bb;
    out[(size_t)i * NC + c] = f2bf(v > 0.f ? v : 0.f);
  }
}

__global__ __launch_bounds__(64) void agg_lsm_kernel(
    const unsigned short* __restrict__ hp, const float* __restrict__ ew,
    const int* __restrict__ src, const int* __restrict__ off,
    const int* __restrict__ eid, const float* __restrict__ dinv,
    const float* __restrict__ sw, const unsigned short* __restrict__ biasb,
    const float* __restrict__ biasf, const int* __restrict__ flags,
    void* __restrict__ outv, int n) {
  constexpr int BLK = 64, NC = 40, STRIDE = 48;
  int i = blockIdx.x;
  if (i >= n) return;
  int c = threadIdx.x;
  __shared__ float scoef[BLK];
  __shared__ int ssrc[BLK];
  float di = dinv[i];
  float acc = 0.f;
  if (c < NC) acc = sw[i] * di * di * bf2f((unsigned int)hp[(size_t)i * STRIDE + c]);
  int e0 = off[i], e1 = off[i + 1];
  for (int base = e0; base < e1; base += BLK) {
    int j = base + c;
    if (j < e1) {
      int e = eid[j];
      int s = src[e];
      ssrc[c] = s;
      scoef[c] = ew[e] * dinv[s] * di;
    }
    __syncthreads();
    int m = min(BLK, e1 - base);
    for (int k = 0; k < m; k++) {
      float cf = scoef[k];
      if (cf != 0.f && c < NC)
        acc += cf * bf2f((unsigned int)hp[(size_t)ssrc[k] * STRIDE + c]);
    }
    __syncthreads();
  }
  int f32 = flags[1];
  float bb = 0.f;
  if (c < NC) bb = f32 ? biasf[c] : bf2f((unsigned int)biasb[c]);
  float v = (c < NC) ? acc + bb : -3.0e38f;
  float vm = wave_max(v);
  float ex = (c < NC) ? expf(v - vm) : 0.f;
  float se = wave_sum(ex);
  float ls = logf(se);
  if (c < NC) {
    float r = v - vm - ls;
    if (f32) ((float*)outv)[(size_t)i * NC + c] = r;
    else ((unsigned short*)outv)[(size_t)i * NC + c] = f2bf(r);
  }
}

// ---------------- host ----------------

extern "C" void kernel_launch(void* const* d_in, const int* in_sizes, int n_in,
                              void* d_out, int out_size, void* d_ws, size_t ws_size,
                              hipStream_t stream) {
  const unsigned short* xb  = (const unsigned short*)d_in[0];
  const float* xf           = (const float*)d_in[0];
  const int* ei             = (const int*)d_in[1];

  const int H  = in_sizes[3];            // 256
  const int F  = in_sizes[2] / H;        // 512
  const int D2 = in_sizes[5];            // 64
  const int C  = in_sizes[7];            // 40
  const int N  = in_sizes[0] / F;        // 50000
  const int E  = in_sizes[1] / 2;        // 1600000
  const int CP = 48;

  char* p = (char*)d_ws;
  auto alloc = [&](size_t bytes) -> char* {
    char* r = p;
    p += (bytes + 255) & ~(size_t)255;
    return r;
  };
  int*   srcN   = (int*)alloc((size_t)E * 4);
  int*   dstN   = (int*)alloc((size_t)E * 4);
  float* wbuf   = (float*)alloc((size_t)E * 4);
  int*   eid    = (int*)alloc((size_t)E * 4);
  int*   off    = (int*)alloc((size_t)(N + 1) * 4);
  int*   cur    = (int*)alloc((size_t)N * 4);
  float* invn   = (float*)alloc((size_t)N * 4);
  float* rowsum = (float*)alloc((size_t)N * 4);
  float* degcnt = (float*)alloc((size_t)N * 4);
  float* sw     = (float*)alloc((size_t)N * 4);
  float* deg2   = (float*)alloc((size_t)N * 4);
  float* dinv   = (float*)alloc((size_t)N * 4);
  int*   flags  = (int*)alloc(256);
  unsigned short* WT = (unsigned short*)alloc((size_t)256 * 512 * 2);
  unsigned short* hp = (unsigned short*)alloc((size_t)N * 256 * 2);
  // h1 overwrites the (consumed) x input buffer; internal state is always bf16.
  unsigned short* h1 = (unsigned short*)d_in[0];
  // h2 in hp tail: layer-2 gemm writes hp[0,N*64), layer-3 gemm hp[0,N*48) — disjoint.
  unsigned short* h2 = hp + (size_t)N * 64;

  const int TB = 256;
  int nblk  = (N + TB - 1) / TB;
  int eblk  = (E + TB - 1) / TB;
  int nwav  = (N + 3) / 4;
  int ewav  = (E + 3) / 4;
  int mtile4 = (N / 16 + 3) / 4;

  detect_kernel<<<1, 256, 0, stream>>>(ei, (const unsigned int*)d_in[2], flags, E);
  normalize_kernel<<<eblk, TB, 0, stream>>>(ei, flags, srcN, dstN, E, N);

  hipMemsetAsync(cur, 0, (size_t)N * 4, stream);
  count_kernel<<<eblk, TB, 0, stream>>>(dstN, cur, E);
  scan_kernel<<<1, 1024, 0, stream>>>(cur, off, N);
  copy_kernel<<<nblk, TB, 0, stream>>>(off, cur, N);
  fill_kernel<<<eblk, TB, 0, stream>>>(dstN, cur, eid, E);

  // ---------- layer 1: x(512) -> h1(256) ----------
  hipMemsetAsync(rowsum, 0, (size_t)N * 4, stream);
  hipMemsetAsync(degcnt, 0, (size_t)N * 4, stream);
  norm8_kernel<<<nwav, TB, 0, stream>>>(xb, xf, flags, invn, N);
  sim8_kernel<<<ewav, TB, 0, stream>>>(xb, xf, flags, srcN, dstN, invn, wbuf, rowsum, degcnt, E);
  node_a_kernel<<<nblk, TB, 0, stream>>>(rowsum, degcnt, sw, deg2, N);
  edge_b_kernel<<<eblk, TB, 0, stream>>>(wbuf, srcN, dstN, rowsum, deg2, E);
  node_b_kernel<<<nblk, TB, 0, stream>>>(deg2, dinv, N);
  transpose_kernel<<<(H * F + TB - 1) / TB, TB, 0, stream>>>(
      (const unsigned short*)d_in[2], (const float*)d_in[2], flags, WT, F, H, H);
  gemm1_kernel<<<dim3(H / 16, mtile4), TB, 0, stream>>>(xb, xf, flags, WT, hp, N, F, H);
  agg_relu_kernel<256, 256, 256><<<N, 256, 0, stream>>>(
      hp, wbuf, srcN, off, eid, dinv, sw,
      (const unsigned short*)d_in[3], (const float*)d_in[3], flags, h1, N);

  // ---------- layer 2: h1(256) -> h2(64) ----------
  hipMemsetAsync(rowsum, 0, (size_t)N * 4, stream);
  hipMemsetAsync(degcnt, 0, (size_t)N * 4, stream);
  norm_kernel<4><<<nwav, TB, 0, stream>>>(h1, invn, N);
  sim_kernel<4><<<ewav, TB, 0, stream>>>(h1, srcN, dstN, invn, wbuf, rowsum, degcnt, E);
  node_a_kernel<<<nblk, TB, 0, stream>>>(rowsum, degcnt, sw, deg2, N);
  edge_b_kernel<<<eblk, TB, 0, stream>>>(wbuf, srcN, dstN, rowsum, deg2, E);
  node_b_kernel<<<nblk, TB, 0, stream>>>(deg2, dinv, N);
  transpose_kernel<<<(D2 * H + TB - 1) / TB, TB, 0, stream>>>(
      (const unsigned short*)d_in[4], (const float*)d_in[4], flags, WT, H, D2, D2);
  gemm_kernel<<<dim3(D2 / 16, mtile4), TB, 0, stream>>>(h1, WT, hp, N, H, D2);
  agg_relu_kernel<64, 64, 64><<<N, 64, 0, stream>>>(
      hp, wbuf, srcN, off, eid, dinv, sw,
      (const unsigned short*)d_in[5], (const float*)d_in[5], flags, h2, N);

  // ---------- layer 3: h2(64) -> out(40), fused log_softmax ----------
  hipMemsetAsync(rowsum, 0, (size_t)N * 4, stream);
  hipMemsetAsync(degcnt, 0, (size_t)N * 4, stream);
  norm_kernel<1><<<nwav, TB, 0, stream>>>(h2, invn, N);
  sim_kernel<1><<<ewav, TB, 0, stream>>>(h2, srcN, dstN, invn, wbuf, rowsum, degcnt, E);
  node_a_kernel<<<nblk, TB, 0, stream>>>(rowsum, degcnt, sw, deg2, N);
  edge_b_kernel<<<eblk, TB, 0, stream>>>(wbuf, srcN, dstN, rowsum, deg2, E);
  node_b_kernel<<<nblk, TB, 0, stream>>>(deg2, dinv, N);
  transpose_kernel<<<(CP * D2 + TB - 1) / TB, TB, 0, stream>>>(
      (const unsigned short*)d_in[6], (const float*)d_in[6], flags, WT, D2, C, CP);
  gemm_kernel<<<dim3(CP / 16, mtile4), TB, 0, stream>>>(h2, WT, hp, N, D2, CP);
  agg_lsm_kernel<<<N, 64, 0, stream>>>(
      hp, wbuf, srcN, off, eid, dinv, sw,
      (const unsigned short*)d_in[7], (const float*)d_in[7], flags, d_out, N);
}

// Round 4
// 2411.200 us; speedup vs baseline: 1.2922x; 1.2922x over previous
//
#include <hip/hip_runtime.h>
#include <stdint.h>

typedef __attribute__((ext_vector_type(8))) short short8;
typedef __attribute__((ext_vector_type(4))) float floatx4;

__device__ __forceinline__ float bf2f(unsigned int u) {
  union { unsigned int i; float f; } x;
  x.i = u << 16;
  return x.f;
}

__device__ __forceinline__ unsigned short f2bf(float f) {
  union { float f; unsigned int u; } x; x.f = f;
  unsigned int r = x.u + 0x7fffu + ((x.u >> 16) & 1u);
  return (unsigned short)(r >> 16);
}

__device__ __forceinline__ float wave_sum(float v) {
  #pragma unroll
  for (int m = 32; m > 0; m >>= 1) v += __shfl_xor(v, m, 64);
  return v;
}

__device__ __forceinline__ float wave_max(float v) {
  #pragma unroll
  for (int m = 32; m > 0; m >>= 1) v = fmaxf(v, __shfl_xor(v, m, 64));
  return v;
}

// -------- dtype detection: flags[0]=edges int64, flags[1]=floats fp32 --------

__global__ void detect_kernel(const int* __restrict__ ei, const unsigned int* __restrict__ w1,
                              int* __restrict__ flags, int E) {
  __shared__ int nz, sane;
  if (threadIdx.x == 0) { nz = 0; sane = 0; }
  __syncthreads();
  for (int i = threadIdx.x; i < 2048; i += blockDim.x) {
    if (i < E && ei[2 * i + 1] != 0) atomicAdd(&nz, 1);
    union { unsigned int u; float f; } c; c.u = w1[i];
    float af = fabsf(c.f);
    if (c.f == c.f && af > 1e-10f && af < 1e10f) atomicAdd(&sane, 1);
  }
  __syncthreads();
  if (threadIdx.x == 0) {
    flags[0] = (nz == 0) ? 1 : 0;
    flags[1] = (sane > 1024) ? 1 : 0;
  }
}

// ---------------- CSR build (by dst) with inline edge decode ----------------

__global__ void count_kernel(const int* __restrict__ ei, const int* __restrict__ flags,
                             int* __restrict__ cnt, int E, int N) {
  int e = blockIdx.x * blockDim.x + threadIdx.x;
  if (e >= E) return;
  int d = flags[0] ? ei[2 * (E + e)] : ei[E + e];
  d = ((unsigned)d < (unsigned)N) ? d : 0;
  atomicAdd(&cnt[d], 1);
}

__global__ void scan1_kernel(const int* __restrict__ cnt, int* __restrict__ off,
                             int* __restrict__ bsum, int n) {
  __shared__ int buf[1024];
  int t = threadIdx.x;
  int i = blockIdx.x * 1024 + t;
  int v = (i < n) ? cnt[i] : 0;
  buf[t] = v;
  __syncthreads();
  for (int o = 1; o < 1024; o <<= 1) {
    int a = (t >= o) ? buf[t - o] : 0;
    __syncthreads();
    buf[t] += a;
    __syncthreads();
  }
  if (i < n) off[i + 1] = buf[t];
  if (t == 1023) bsum[blockIdx.x] = buf[1023];
}

__global__ void scan2_kernel(int* __restrict__ bsum, int nb) {
  __shared__ int buf[1024];
  int t = threadIdx.x;
  int v = (t < nb) ? bsum[t] : 0;
  buf[t] = v;
  __syncthreads();
  for (int o = 1; o < 1024; o <<= 1) {
    int a = (t >= o) ? buf[t - o] : 0;
    __syncthreads();
    buf[t] += a;
    __syncthreads();
  }
  if (t < nb) bsum[t] = buf[t];
}

__global__ void scan3_kernel(int* __restrict__ off, const int* __restrict__ bsum, int n) {
  int i = blockIdx.x * blockDim.x + threadIdx.x;
  if (i == 0) off[0] = 0;
  if (i < n) {
    int b = i >> 10;
    if (b > 0) off[i + 1] += bsum[b - 1];
  }
}

__global__ void copy_kernel(const int* __restrict__ off, int* __restrict__ cur, int n) {
  int i = blockIdx.x * blockDim.x + threadIdx.x;
  if (i < n) cur[i] = off[i];
}

__global__ void fill_kernel(const int* __restrict__ ei, const int* __restrict__ flags,
                            int* __restrict__ cur, int* __restrict__ srcP,
                            int* __restrict__ dstP, int E, int N) {
  int e = blockIdx.x * blockDim.x + threadIdx.x;
  if (e >= E) return;
  int s, d;
  if (flags[0]) { s = ei[2 * e]; d = ei[2 * (E + e)]; }
  else          { s = ei[e];     d = ei[E + e]; }
  s = ((unsigned)s < (unsigned)N) ? s : 0;
  d = ((unsigned)d < (unsigned)N) ? d : 0;
  int pos = atomicAdd(&cur[d], 1);
  srcP[pos] = s;
  dstP[pos] = d;
}

// -------- layer-1 convert+norm (fp32 or bf16 input -> bf16 rows + invn) --------

__global__ __launch_bounds__(256) void convert_norm_kernel(
    const float* __restrict__ xf, const unsigned short* __restrict__ xb,
    const int* __restrict__ flags, unsigned short* __restrict__ xo,
    float* __restrict__ invn, int n) {
  int row = blockIdx.x * 4 + (threadIdx.x >> 6);
  int lane = threadIdx.x & 63;
  if (row >= n) return;
  float ss = 0.f;
  if (flags[1]) {
    const float4* vp = reinterpret_cast<const float4*>(xf + (size_t)row * 512) + lane * 2;
    float4 a = vp[0], b = vp[1];
    ss = a.x*a.x + a.y*a.y + a.z*a.z + a.w*a.w + b.x*b.x + b.y*b.y + b.z*b.z + b.w*b.w;
    short8 o;
    o[0] = (short)f2bf(a.x); o[1] = (short)f2bf(a.y);
    o[2] = (short)f2bf(a.z); o[3] = (short)f2bf(a.w);
    o[4] = (short)f2bf(b.x); o[5] = (short)f2bf(b.y);
    o[6] = (short)f2bf(b.z); o[7] = (short)f2bf(b.w);
    *(reinterpret_cast<short8*>(xo + (size_t)row * 512) + lane) = o;
  } else {
    uint4 v = *(reinterpret_cast<const uint4*>(xb + (size_t)row * 512) + lane);
    unsigned int a[4] = {v.x, v.y, v.z, v.w};
    #pragma unroll
    for (int i = 0; i < 4; i++) {
      float lo = bf2f(a[i] & 0xffffu), hi = bf2f(a[i] >> 16);
      ss += lo * lo + hi * hi;
    }
    *(reinterpret_cast<uint4*>(xo + (size_t)row * 512) + lane) = v;
  }
  ss = wave_sum(ss);
  if (lane == 0) invn[row] = (ss == 0.f) ? 1.0f : rsqrtf(ss);
}

__global__ __launch_bounds__(256) void norm8_kernel(const unsigned short* __restrict__ hb,
                                                    const float* __restrict__ hf,
                                                    const int* __restrict__ flags,
                                                    float* __restrict__ invn, int n) {
  int wid = blockIdx.x * 4 + (threadIdx.x >> 6);
  int lane = threadIdx.x & 63;
  if (wid >= n) return;
  float s = 0.f;
  if (flags[1]) {
    const float4* vp = reinterpret_cast<const float4*>(hf + (size_t)wid * 512) + lane * 2;
    float4 a = vp[0], b = vp[1];
    s = a.x*a.x + a.y*a.y + a.z*a.z + a.w*a.w + b.x*b.x + b.y*b.y + b.z*b.z + b.w*b.w;
  } else {
    uint4 v = *(reinterpret_cast<const uint4*>(hb + (size_t)wid * 512) + lane);
    unsigned int a[4] = {v.x, v.y, v.z, v.w};
    #pragma unroll
    for (int i = 0; i < 4; i++) {
      float lo = bf2f(a[i] & 0xffffu), hi = bf2f(a[i] >> 16);
      s += lo * lo + hi * hi;
    }
  }
  s = wave_sum(s);
  if (lane == 0) invn[wid] = (s == 0.f) ? 1.0f : rsqrtf(s);
}

__global__ __launch_bounds__(256) void norm256_kernel(const unsigned short* __restrict__ h,
                                                      float* __restrict__ invn, int n) {
  int wid = blockIdx.x * 4 + (threadIdx.x >> 6);
  int lane = threadIdx.x & 63;
  if (wid >= n) return;
  uint2 v = *(reinterpret_cast<const uint2*>(h + (size_t)wid * 256) + lane);
  unsigned int a[2] = {v.x, v.y};
  float s = 0.f;
  #pragma unroll
  for (int i = 0; i < 2; i++) {
    float lo = bf2f(a[i] & 0xffffu), hi = bf2f(a[i] >> 16);
    s += lo * lo + hi * hi;
  }
  s = wave_sum(s);
  if (lane == 0) invn[wid] = (s == 0.f) ? 1.0f : rsqrtf(s);
}

__global__ __launch_bounds__(256) void norm64_kernel(const unsigned short* __restrict__ h,
                                                     float* __restrict__ invn, int n) {
  int wid = blockIdx.x * 4 + (threadIdx.x >> 6);
  int lane = threadIdx.x & 63;
  if (wid >= n) return;
  float v0 = bf2f((unsigned int)h[(size_t)wid * 64 + lane]);
  float s = wave_sum(v0 * v0);
  if (lane == 0) invn[wid] = (s == 0.f) ? 1.0f : rsqrtf(s);
}

// ---------------- per-edge cosine sim (dst-sorted order) ----------------

template<int DIM>
__global__ __launch_bounds__(256) void simb_kernel(const unsigned short* __restrict__ h,
                                                   const int* __restrict__ srcP,
                                                   const int* __restrict__ dstP,
                                                   const float* __restrict__ invn,
                                                   float* __restrict__ w,
                                                   float* __restrict__ rowsum,
                                                   float* __restrict__ degcnt, int E) {
  int j = blockIdx.x * 4 + (threadIdx.x >> 6);
  int lane = threadIdx.x & 63;
  if (j >= E) return;
  int s = srcP[j], t = dstP[j];
  float acc = 0.f;
  if constexpr (DIM == 512) {
    uint4 a = *(reinterpret_cast<const uint4*>(h + (size_t)s * 512) + lane);
    uint4 b = *(reinterpret_cast<const uint4*>(h + (size_t)t * 512) + lane);
    unsigned int av[4] = {a.x, a.y, a.z, a.w};
    unsigned int bv[4] = {b.x, b.y, b.z, b.w};
    #pragma unroll
    for (int i = 0; i < 4; i++)
      acc += bf2f(av[i] & 0xffffu) * bf2f(bv[i] & 0xffffu)
           + bf2f(av[i] >> 16) * bf2f(bv[i] >> 16);
  } else if constexpr (DIM == 256) {
    uint2 a = *(reinterpret_cast<const uint2*>(h + (size_t)s * 256) + lane);
    uint2 b = *(reinterpret_cast<const uint2*>(h + (size_t)t * 256) + lane);
    unsigned int av[2] = {a.x, a.y};
    unsigned int bv[2] = {b.x, b.y};
    #pragma unroll
    for (int i = 0; i < 2; i++)
      acc += bf2f(av[i] & 0xffffu) * bf2f(bv[i] & 0xffffu)
           + bf2f(av[i] >> 16) * bf2f(bv[i] >> 16);
  } else {
    acc = bf2f((unsigned int)h[(size_t)s * 64 + lane]) *
          bf2f((unsigned int)h[(size_t)t * 64 + lane]);
  }
  acc = wave_sum(acc);
  if (lane == 0) {
    float simv = acc * invn[s] * invn[t];
    float wv = (s != t && simv > 0.f) ? simv : 0.f;
    w[j] = wv;
    if (wv > 0.f) {
      atomicAdd(&rowsum[s], wv);
      atomicAdd(&degcnt[s], 1.0f);
    }
  }
}

__global__ __launch_bounds__(256) void simf_kernel(const unsigned short* __restrict__ hb,
                                                   const float* __restrict__ hf,
                                                   const int* __restrict__ flags,
                                                   const int* __restrict__ srcP,
                                                   const int* __restrict__ dstP,
                                                   const float* __restrict__ invn,
                                                   float* __restrict__ w,
                                                   float* __restrict__ rowsum,
                                                   float* __restrict__ degcnt, int E) {
  int j = blockIdx.x * 4 + (threadIdx.x >> 6);
  int lane = threadIdx.x & 63;
  if (j >= E) return;
  int s = srcP[j], t = dstP[j];
  float acc = 0.f;
  if (flags[1]) {
    const float4* ap = reinterpret_cast<const float4*>(hf + (size_t)s * 512) + lane * 2;
    const float4* bp = reinterpret_cast<const float4*>(hf + (size_t)t * 512) + lane * 2;
    float4 a0 = ap[0], a1 = ap[1], b0 = bp[0], b1 = bp[1];
    acc = a0.x*b0.x + a0.y*b0.y + a0.z*b0.z + a0.w*b0.w
        + a1.x*b1.x + a1.y*b1.y + a1.z*b1.z + a1.w*b1.w;
  } else {
    uint4 a = *(reinterpret_cast<const uint4*>(hb + (size_t)s * 512) + lane);
    uint4 b = *(reinterpret_cast<const uint4*>(hb + (size_t)t * 512) + lane);
    unsigned int av[4] = {a.x, a.y, a.z, a.w};
    unsigned int bv[4] = {b.x, b.y, b.z, b.w};
    #pragma unroll
    for (int i = 0; i < 4; i++)
      acc += bf2f(av[i] & 0xffffu) * bf2f(bv[i] & 0xffffu)
           + bf2f(av[i] >> 16) * bf2f(bv[i] >> 16);
  }
  acc = wave_sum(acc);
  if (lane == 0) {
    float simv = acc * invn[s] * invn[t];
    float wv = (s != t && simv > 0.f) ? simv : 0.f;
    w[j] = wv;
    if (wv > 0.f) {
      atomicAdd(&rowsum[s], wv);
      atomicAdd(&degcnt[s], 1.0f);
    }
  }
}

// ---------------- node / edge scalar stages ----------------

__global__ void node_a_kernel(float* __restrict__ rowsum, const float* __restrict__ degcnt,
                              float* __restrict__ sw, float* __restrict__ deg2, int n) {
  int i = blockIdx.x * blockDim.x + threadIdx.x;
  if (i >= n) return;
  float rs = rowsum[i];
  rowsum[i] = (rs > 0.f) ? 1.0f / rs : 0.0f;
  float lam = 1.0f / (degcnt[i] + 1.0f);
  float s = expf(lam);
  sw[i] = s;
  deg2[i] = s;
}

__global__ void edge_b_kernel(float* __restrict__ w, const int* __restrict__ srcP,
                              const int* __restrict__ dstP, const float* __restrict__ invrs,
                              float* __restrict__ deg2, int E) {
  int j = blockIdx.x * blockDim.x + threadIdx.x;
  if (j >= E) return;
  float wv = w[j];
  if (wv > 0.f) {
    float ewv = expf(wv * invrs[srcP[j]]);
    w[j] = ewv;
    atomicAdd(&deg2[dstP[j]], ewv);
  }
}

__global__ void node_b_kernel(const float* __restrict__ deg2, float* __restrict__ dinv, int n) {
  int i = blockIdx.x * blockDim.x + threadIdx.x;
  if (i < n) dinv[i] = rsqrtf(deg2[i]);
}

// ---------------- GEMM ----------------

__global__ void transpose_kernel(const unsigned short* __restrict__ Wb,
                                 const float* __restrict__ Wf,
                                 const int* __restrict__ flags,
                                 unsigned short* __restrict__ WT,
                                 int K, int Nc, int Npad) {
  int idx = blockIdx.x * blockDim.x + threadIdx.x;
  if (idx >= Npad * K) return;
  int nn = idx / K, k = idx - nn * K;
  unsigned short v = 0;
  if (nn < Nc) {
    if (flags[1]) v = f2bf(Wf[(size_t)k * Nc + nn]);
    else          v = Wb[(size_t)k * Nc + nn];
  }
  WT[idx] = v;
}

// wide GEMM: one wave owns a 16-row m-tile and all NT n-tiles; A read once.
template<int NT, int KSTEPS>
__global__ __launch_bounds__(256) void gemmw_kernel(const unsigned short* __restrict__ Ab,
                                                    const float* __restrict__ Af,
                                                    const int* __restrict__ flags,
                                                    int useflags,
                                                    const unsigned short* __restrict__ BT,
                                                    unsigned short* __restrict__ C,
                                                    int M, int Npad) {
  constexpr int K = KSTEPS * 32;
  int mt = blockIdx.x * 4 + (threadIdx.x >> 6);
  if (mt * 16 >= M) return;
  int lane = threadIdx.x & 63;
  int r = lane & 15, quad = lane >> 4;
  int m0 = mt * 16;
  int f32A = useflags ? flags[1] : 0;
  floatx4 acc[NT];
  #pragma unroll
  for (int nt = 0; nt < NT; nt++) acc[nt] = floatx4{0.f, 0.f, 0.f, 0.f};
  const short8* ap = reinterpret_cast<const short8*>(Ab + (size_t)(m0 + r) * K);
  const float* af = Af + (size_t)(m0 + r) * K + quad * 8;
  for (int kk = 0; kk < KSTEPS; kk++) {
    short8 a;
    if (f32A) {
      float4 x0 = *reinterpret_cast<const float4*>(af + kk * 32);
      float4 x1 = *reinterpret_cast<const float4*>(af + kk * 32 + 4);
      a[0] = (short)f2bf(x0.x); a[1] = (short)f2bf(x0.y);
      a[2] = (short)f2bf(x0.z); a[3] = (short)f2bf(x0.w);
      a[4] = (short)f2bf(x1.x); a[5] = (short)f2bf(x1.y);
      a[6] = (short)f2bf(x1.z); a[7] = (short)f2bf(x1.w);
    } else {
      a = ap[(kk << 2) + quad];
    }
    #pragma unroll
    for (int nt = 0; nt < NT; nt++) {
      short8 b = *reinterpret_cast<const short8*>(BT + (size_t)(nt * 16 + r) * K + kk * 32 + quad * 8);
      acc[nt] = __builtin_amdgcn_mfma_f32_16x16x32_bf16(a, b, acc[nt], 0, 0, 0);
    }
  }
  #pragma unroll
  for (int nt = 0; nt < NT; nt++) {
    #pragma unroll
    for (int i = 0; i < 4; i++)
      C[(size_t)(m0 + quad * 4 + i) * Npad + nt * 16 + r] = f2bf(acc[nt][i]);
  }
}

// ---------------- aggregation (dst-sorted contiguous edges) ----------------

template<int BLK, int NC, int STRIDE>
__global__ __launch_bounds__(BLK) void agg_relu_kernel(
    const unsigned short* __restrict__ hp, const float* __restrict__ ew,
    const int* __restrict__ srcP, const int* __restrict__ off,
    const float* __restrict__ dinv, const float* __restrict__ sw,
    const unsigned short* __restrict__ biasb, const float* __restrict__ biasf,
    const int* __restrict__ flags, unsigned short* __restrict__ out, int n) {
  int i = blockIdx.x;
  if (i >= n) return;
  int c = threadIdx.x;
  __shared__ float scoef[BLK];
  __shared__ int ssrc[BLK];
  float di = dinv[i];
  float acc = 0.f;
  if (c < NC) acc = sw[i] * di * di * bf2f((unsigned int)hp[(size_t)i * STRIDE + c]);
  int e0 = off[i], e1 = off[i + 1];
  for (int base = e0; base < e1; base += BLK) {
    int j = base + c;
    if (j < e1) {
      int s = srcP[j];
      ssrc[c] = s;
      scoef[c] = ew[j] * dinv[s] * di;
    }
    __syncthreads();
    int m = min(BLK, e1 - base);
    for (int k = 0; k < m; k++) {
      float cf = scoef[k];
      if (cf != 0.f && c < NC)
        acc += cf * bf2f((unsigned int)hp[(size_t)ssrc[k] * STRIDE + c]);
    }
    __syncthreads();
  }
  if (c < NC) {
    float bb = flags[1] ? biasf[c] : bf2f((unsigned int)biasb[c]);
    float v = acc + bb;
    out[(size_t)i * NC + c] = f2bf(v > 0.f ? v : 0.f);
  }
}

__global__ __launch_bounds__(64) void agg_lsm_kernel(
    const unsigned short* __restrict__ hp, const float* __restrict__ ew,
    const int* __restrict__ srcP, const int* __restrict__ off,
    const float* __restrict__ dinv, const float* __restrict__ sw,
    const unsigned short* __restrict__ biasb, const float* __restrict__ biasf,
    const int* __restrict__ flags, void* __restrict__ outv, int n) {
  constexpr int BLK = 64, NC = 40, STRIDE = 48;
  int i = blockIdx.x;
  if (i >= n) return;
  int c = threadIdx.x;
  __shared__ float scoef[BLK];
  __shared__ int ssrc[BLK];
  float di = dinv[i];
  float acc = 0.f;
  if (c < NC) acc = sw[i] * di * di * bf2f((unsigned int)hp[(size_t)i * STRIDE + c]);
  int e0 = off[i], e1 = off[i + 1];
  for (int base = e0; base < e1; base += BLK) {
    int j = base + c;
    if (j < e1) {
      int s = srcP[j];
      ssrc[c] = s;
      scoef[c] = ew[j] * dinv[s] * di;
    }
    __syncthreads();
    int m = min(BLK, e1 - base);
    for (int k = 0; k < m; k++) {
      float cf = scoef[k];
      if (cf != 0.f && c < NC)
        acc += cf * bf2f((unsigned int)hp[(size_t)ssrc[k] * STRIDE + c]);
    }
    __syncthreads();
  }
  int f32 = flags[1];
  float bb = 0.f;
  if (c < NC) bb = f32 ? biasf[c] : bf2f((unsigned int)biasb[c]);
  float v = (c < NC) ? acc + bb : -3.0e38f;
  float vm = wave_max(v);
  float ex = (c < NC) ? expf(v - vm) : 0.f;
  float se = wave_sum(ex);
  float ls = logf(se);
  if (c < NC) {
    float r = v - vm - ls;
    if (f32) ((float*)outv)[(size_t)i * NC + c] = r;
    else ((unsigned short*)outv)[(size_t)i * NC + c] = f2bf(r);
  }
}

// ---------------- host ----------------

extern "C" void kernel_launch(void* const* d_in, const int* in_sizes, int n_in,
                              void* d_out, int out_size, void* d_ws, size_t ws_size,
                              hipStream_t stream) {
  const unsigned short* xb = (const unsigned short*)d_in[0];
  const float* xf          = (const float*)d_in[0];
  const int* ei            = (const int*)d_in[1];

  const int H  = in_sizes[3];            // 256
  const int F  = in_sizes[2] / H;        // 512
  const int D2 = in_sizes[5];            // 64
  const int C  = in_sizes[7];            // 40
  const int N  = in_sizes[0] / F;        // 50000
  const int E  = in_sizes[1] / 2;        // 1600000
  const int CP = 48;

  char* p = (char*)d_ws;
  auto alloc = [&](size_t bytes) -> char* {
    char* r = p;
    p += (bytes + 255) & ~(size_t)255;
    return r;
  };
  int*   srcP   = (int*)alloc((size_t)E * 4);
  int*   dstP   = (int*)alloc((size_t)E * 4);
  float* wbuf   = (float*)alloc((size_t)E * 4);
  int*   off    = (int*)alloc((size_t)(N + 1) * 4);
  int*   cur    = (int*)alloc((size_t)N * 4);
  float* invn   = (float*)alloc((size_t)N * 4);
  float* rowsum = (float*)alloc((size_t)N * 4);
  float* degcnt = (float*)alloc((size_t)N * 4);
  float* sw     = (float*)alloc((size_t)N * 4);
  float* deg2   = (float*)alloc((size_t)N * 4);
  float* dinv   = (float*)alloc((size_t)N * 4);
  int*   flags  = (int*)alloc(256);
  int*   bsum   = (int*)alloc(4096 * 4);
  unsigned short* WT = (unsigned short*)alloc((size_t)256 * 512 * 2);
  unsigned short* hp = (unsigned short*)alloc((size_t)N * 256 * 2);
  size_t used = (size_t)(p - (char*)d_ws);
  size_t xbf_bytes = (size_t)N * 512 * 2;
  bool big = (used + xbf_bytes + 256) <= ws_size;
  unsigned short* xbf = big ? (unsigned short*)alloc(xbf_bytes) : (unsigned short*)hp;

  unsigned short* h1 = (unsigned short*)d_in[0];     // x dead after layer-1 reads
  unsigned short* h2 = hp + (size_t)N * 64;          // disjoint from later hp use

  const int TB = 256;
  int nblk = (N + TB - 1) / TB;
  int eblk = (E + TB - 1) / TB;
  int nwav = (N + 3) / 4;
  int ewav = (E + 3) / 4;
  int mt4  = (N / 16 + 3) / 4;
  int nb1024 = (N + 1023) / 1024;

  detect_kernel<<<1, 256, 0, stream>>>(ei, (const unsigned int*)d_in[2], flags, E);

  // CSR by dst -> permuted edge arrays
  hipMemsetAsync(cur, 0, (size_t)N * 4, stream);
  count_kernel<<<eblk, TB, 0, stream>>>(ei, flags, cur, E, N);
  scan1_kernel<<<nb1024, 1024, 0, stream>>>(cur, off, bsum, N);
  scan2_kernel<<<1, 1024, 0, stream>>>(bsum, nb1024);
  scan3_kernel<<<nblk, TB, 0, stream>>>(off, bsum, N);
  copy_kernel<<<nblk, TB, 0, stream>>>(off, cur, N);
  fill_kernel<<<eblk, TB, 0, stream>>>(ei, flags, cur, srcP, dstP, E, N);

  // ---------- layer 1: x(512) -> h1(256) ----------
  hipMemsetAsync(rowsum, 0, (size_t)N * 4, stream);
  hipMemsetAsync(degcnt, 0, (size_t)N * 4, stream);
  if (big) {
    convert_norm_kernel<<<nwav, TB, 0, stream>>>(xf, xb, flags, xbf, invn, N);
    simb_kernel<512><<<ewav, TB, 0, stream>>>(xbf, srcP, dstP, invn, wbuf, rowsum, degcnt, E);
  } else {
    norm8_kernel<<<nwav, TB, 0, stream>>>(xb, xf, flags, invn, N);
    simf_kernel<<<ewav, TB, 0, stream>>>(xb, xf, flags, srcP, dstP, invn, wbuf, rowsum, degcnt, E);
  }
  node_a_kernel<<<nblk, TB, 0, stream>>>(rowsum, degcnt, sw, deg2, N);
  edge_b_kernel<<<eblk, TB, 0, stream>>>(wbuf, srcP, dstP, rowsum, deg2, E);
  node_b_kernel<<<nblk, TB, 0, stream>>>(deg2, dinv, N);
  transpose_kernel<<<(H * F + TB - 1) / TB, TB, 0, stream>>>(
      (const unsigned short*)d_in[2], (const float*)d_in[2], flags, WT, F, H, H);
  gemmw_kernel<16, 16><<<mt4, TB, 0, stream>>>(
      big ? xbf : xb, xf, flags, big ? 0 : 1, WT, hp, N, H);
  agg_relu_kernel<256, 256, 256><<<N, 256, 0, stream>>>(
      hp, wbuf, srcP, off, dinv, sw,
      (const unsigned short*)d_in[3], (const float*)d_in[3], flags, h1, N);

  // ---------- layer 2: h1(256) -> h2(64) ----------
  hipMemsetAsync(rowsum, 0, (size_t)N * 4, stream);
  hipMemsetAsync(degcnt, 0, (size_t)N * 4, stream);
  norm256_kernel<<<nwav, TB, 0, stream>>>(h1, invn, N);
  simb_kernel<256><<<ewav, TB, 0, stream>>>(h1, srcP, dstP, invn, wbuf, rowsum, degcnt, E);
  node_a_kernel<<<nblk, TB, 0, stream>>>(rowsum, degcnt, sw, deg2, N);
  edge_b_kernel<<<eblk, TB, 0, stream>>>(wbuf, srcP, dstP, rowsum, deg2, E);
  node_b_kernel<<<nblk, TB, 0, stream>>>(deg2, dinv, N);
  transpose_kernel<<<(D2 * H + TB - 1) / TB, TB, 0, stream>>>(
      (const unsigned short*)d_in[4], (const float*)d_in[4], flags, WT, H, D2, D2);
  gemmw_kernel<4, 8><<<mt4, TB, 0, stream>>>(h1, xf, flags, 0, WT, hp, N, D2);
  agg_relu_kernel<64, 64, 64><<<N, 64, 0, stream>>>(
      hp, wbuf, srcP, off, dinv, sw,
      (const unsigned short*)d_in[5], (const float*)d_in[5], flags, h2, N);

  // ---------- layer 3: h2(64) -> out(40), fused log_softmax ----------
  hipMemsetAsync(rowsum, 0, (size_t)N * 4, stream);
  hipMemsetAsync(degcnt, 0, (size_t)N * 4, stream);
  norm64_kernel<<<nwav, TB, 0, stream>>>(h2, invn, N);
  simb_kernel<64><<<ewav, TB, 0, stream>>>(h2, srcP, dstP, invn, wbuf, rowsum, degcnt, E);
  node_a_kernel<<<nblk, TB, 0, stream>>>(rowsum, degcnt, sw, deg2, N);
  edge_b_kernel<<<eblk, TB, 0, stream>>>(wbuf, srcP, dstP, rowsum, deg2, E);
  node_b_kernel<<<nblk, TB, 0, stream>>>(deg2, dinv, N);
  transpose_kernel<<<(CP * D2 + TB - 1) / TB, TB, 0, stream>>>(
      (const unsigned short*)d_in[6], (const float*)d_in[6], flags, WT, D2, C, CP);
  gemmw_kernel<3, 2><<<mt4, TB, 0, stream>>>(h2, xf, flags, 0, WT, hp, N, CP);
  agg_lsm_kernel<<<N, 64, 0, stream>>>(
      hp, wbuf, srcP, off, dinv, sw,
      (const unsigned short*)d_in[7], (const float*)d_in[7], flags, d_out, N);
}

// Round 5
// 2354.943 us; speedup vs baseline: 1.3231x; 1.0239x over previous
//
#include <hip/hip_runtime.h>
#include <stdint.h>

typedef __attribute__((ext_vector_type(8))) _Float16 half8v;
typedef __attribute__((ext_vector_type(2))) _Float16 half2v;
typedef __attribute__((ext_vector_type(4))) float floatx4;

union H8 { uint4 u; half8v v; half2v h[4]; };
union H4 { uint2 u; half2v h[2]; };

__device__ __forceinline__ float bf2f(unsigned int u) {
  union { unsigned int i; float f; } x;
  x.i = u << 16;
  return x.f;
}

#if __has_builtin(__builtin_amdgcn_fdot2)
__device__ __forceinline__ float dot2(half2v a, half2v b, float c) {
  return __builtin_amdgcn_fdot2(a, b, c, false);
}
#else
__device__ __forceinline__ float dot2(half2v a, half2v b, float c) {
  return c + (float)a.x * (float)b.x + (float)a.y * (float)b.y;
}
#endif

__device__ __forceinline__ float wave_sum(float v) {
  #pragma unroll
  for (int m = 32; m > 0; m >>= 1) v += __shfl_xor(v, m, 64);
  return v;
}

__device__ __forceinline__ float wave_max(float v) {
  #pragma unroll
  for (int m = 32; m > 0; m >>= 1) v = fmaxf(v, __shfl_xor(v, m, 64));
  return v;
}

__device__ __forceinline__ unsigned short f2bf(float f) {
  union { float f; unsigned int u; } x; x.f = f;
  unsigned int r = x.u + 0x7fffu + ((x.u >> 16) & 1u);
  return (unsigned short)(r >> 16);
}

// -------- dtype detection: flags[0]=edges int64, flags[1]=floats fp32 --------

__global__ void detect_kernel(const int* __restrict__ ei, const unsigned int* __restrict__ w1,
                              int* __restrict__ flags, int E) {
  __shared__ int nz, sane;
  if (threadIdx.x == 0) { nz = 0; sane = 0; }
  __syncthreads();
  for (int i = threadIdx.x; i < 2048; i += blockDim.x) {
    if (i < E && ei[2 * i + 1] != 0) atomicAdd(&nz, 1);
    union { unsigned int u; float f; } c; c.u = w1[i];
    float af = fabsf(c.f);
    if (c.f == c.f && af > 1e-10f && af < 1e10f) atomicAdd(&sane, 1);
  }
  __syncthreads();
  if (threadIdx.x == 0) {
    flags[0] = (nz == 0) ? 1 : 0;
    flags[1] = (sane > 1024) ? 1 : 0;
  }
}

// ---------------- CSR build (by dst) with inline edge decode ----------------

__global__ void count_kernel(const int* __restrict__ ei, const int* __restrict__ flags,
                             int* __restrict__ cnt, int E, int N) {
  int e = blockIdx.x * blockDim.x + threadIdx.x;
  if (e >= E) return;
  int d = flags[0] ? ei[2 * (E + e)] : ei[E + e];
  d = ((unsigned)d < (unsigned)N) ? d : 0;
  atomicAdd(&cnt[d], 1);
}

__global__ void scan1_kernel(const int* __restrict__ cnt, int* __restrict__ off,
                             int* __restrict__ bsum, int n) {
  __shared__ int buf[1024];
  int t = threadIdx.x;
  int i = blockIdx.x * 1024 + t;
  int v = (i < n) ? cnt[i] : 0;
  buf[t] = v;
  __syncthreads();
  for (int o = 1; o < 1024; o <<= 1) {
    int a = (t >= o) ? buf[t - o] : 0;
    __syncthreads();
    buf[t] += a;
    __syncthreads();
  }
  if (i < n) off[i + 1] = buf[t];
  if (t == 1023) bsum[blockIdx.x] = buf[1023];
}

__global__ void scan2_kernel(int* __restrict__ bsum, int nb) {
  __shared__ int buf[1024];
  int t = threadIdx.x;
  int v = (t < nb) ? bsum[t] : 0;
  buf[t] = v;
  __syncthreads();
  for (int o = 1; o < 1024; o <<= 1) {
    int a = (t >= o) ? buf[t - o] : 0;
    __syncthreads();
    buf[t] += a;
    __syncthreads();
  }
  if (t < nb) bsum[t] = buf[t];
}

__global__ void scan3_kernel(int* __restrict__ off, const int* __restrict__ bsum, int n) {
  int i = blockIdx.x * blockDim.x + threadIdx.x;
  if (i == 0) off[0] = 0;
  if (i < n) {
    int b = i >> 10;
    if (b > 0) off[i + 1] += bsum[b - 1];
  }
}

__global__ void copy_kernel(const int* __restrict__ off, int* __restrict__ cur, int n) {
  int i = blockIdx.x * blockDim.x + threadIdx.x;
  if (i < n) cur[i] = off[i];
}

__global__ void fill_kernel(const int* __restrict__ ei, const int* __restrict__ flags,
                            int* __restrict__ cur, int* __restrict__ srcP,
                            int* __restrict__ dstP, int E, int N) {
  int e = blockIdx.x * blockDim.x + threadIdx.x;
  if (e >= E) return;
  int s, d;
  if (flags[0]) { s = ei[2 * e]; d = ei[2 * (E + e)]; }
  else          { s = ei[e];     d = ei[E + e]; }
  s = ((unsigned)s < (unsigned)N) ? s : 0;
  d = ((unsigned)d < (unsigned)N) ? d : 0;
  int pos = atomicAdd(&cur[d], 1);
  srcP[pos] = s;
  dstP[pos] = d;
}

// -------- layer-1 convert+norm (fp32 or bf16 input -> f16 rows + invn) --------

__global__ __launch_bounds__(256) void convert_norm_kernel(
    const float* __restrict__ xf, const unsigned short* __restrict__ xb,
    const int* __restrict__ flags, _Float16* __restrict__ xo,
    float* __restrict__ invn, int n) {
  int row = blockIdx.x * 4 + (threadIdx.x >> 6);
  int lane = threadIdx.x & 63;
  if (row >= n) return;
  float ss = 0.f;
  H8 o;
  if (flags[1]) {
    const float4* vp = reinterpret_cast<const float4*>(xf + (size_t)row * 512) + lane * 2;
    float4 a = vp[0], b = vp[1];
    ss = a.x*a.x + a.y*a.y + a.z*a.z + a.w*a.w + b.x*b.x + b.y*b.y + b.z*b.z + b.w*b.w;
    o.v[0] = (_Float16)a.x; o.v[1] = (_Float16)a.y;
    o.v[2] = (_Float16)a.z; o.v[3] = (_Float16)a.w;
    o.v[4] = (_Float16)b.x; o.v[5] = (_Float16)b.y;
    o.v[6] = (_Float16)b.z; o.v[7] = (_Float16)b.w;
  } else {
    uint4 v = *(reinterpret_cast<const uint4*>(xb + (size_t)row * 512) + lane);
    unsigned int a[4] = {v.x, v.y, v.z, v.w};
    #pragma unroll
    for (int i = 0; i < 4; i++) {
      float lo = bf2f(a[i] & 0xffffu), hi = bf2f(a[i] >> 16);
      ss += lo * lo + hi * hi;
      o.v[2 * i] = (_Float16)lo;
      o.v[2 * i + 1] = (_Float16)hi;
    }
  }
  *(reinterpret_cast<uint4*>(xo + (size_t)row * 512) + lane) = o.u;
  ss = wave_sum(ss);
  if (lane == 0) invn[row] = (ss == 0.f) ? 1.0f : rsqrtf(ss);
}

// fallback norm over raw x (no f16 copy available)
__global__ __launch_bounds__(256) void norm8_kernel(const unsigned short* __restrict__ hb,
                                                    const float* __restrict__ hf,
                                                    const int* __restrict__ flags,
                                                    float* __restrict__ invn, int n) {
  int wid = blockIdx.x * 4 + (threadIdx.x >> 6);
  int lane = threadIdx.x & 63;
  if (wid >= n) return;
  float s = 0.f;
  if (flags[1]) {
    const float4* vp = reinterpret_cast<const float4*>(hf + (size_t)wid * 512) + lane * 2;
    float4 a = vp[0], b = vp[1];
    s = a.x*a.x + a.y*a.y + a.z*a.z + a.w*a.w + b.x*b.x + b.y*b.y + b.z*b.z + b.w*b.w;
  } else {
    uint4 v = *(reinterpret_cast<const uint4*>(hb + (size_t)wid * 512) + lane);
    unsigned int a[4] = {v.x, v.y, v.z, v.w};
    #pragma unroll
    for (int i = 0; i < 4; i++) {
      float lo = bf2f(a[i] & 0xffffu), hi = bf2f(a[i] >> 16);
      s += lo * lo + hi * hi;
    }
  }
  s = wave_sum(s);
  if (lane == 0) invn[wid] = (s == 0.f) ? 1.0f : rsqrtf(s);
}

__global__ __launch_bounds__(256) void norm256_kernel(const _Float16* __restrict__ h,
                                                      float* __restrict__ invn, int n) {
  int wid = blockIdx.x * 4 + (threadIdx.x >> 6);
  int lane = threadIdx.x & 63;
  if (wid >= n) return;
  H4 a;
  a.u = *(reinterpret_cast<const uint2*>(h + (size_t)wid * 256) + lane);
  float s = 0.f;
  s = dot2(a.h[0], a.h[0], s);
  s = dot2(a.h[1], a.h[1], s);
  s = wave_sum(s);
  if (lane == 0) invn[wid] = (s == 0.f) ? 1.0f : rsqrtf(s);
}

__global__ __launch_bounds__(256) void norm64_kernel(const _Float16* __restrict__ h,
                                                     float* __restrict__ invn, int n) {
  int wid = blockIdx.x * 4 + (threadIdx.x >> 6);
  int lane = threadIdx.x & 63;
  if (wid >= n) return;
  float v0 = (float)h[(size_t)wid * 64 + lane];
  float s = wave_sum(v0 * v0);
  if (lane == 0) invn[wid] = (s == 0.f) ? 1.0f : rsqrtf(s);
}

// ---------------- per-edge cosine sim (dst-sorted order, f16 rows) ----------------

template<int DIM>
__global__ __launch_bounds__(256) void simb_kernel(const _Float16* __restrict__ h,
                                                   const int* __restrict__ srcP,
                                                   const int* __restrict__ dstP,
                                                   const float* __restrict__ invn,
                                                   float* __restrict__ w,
                                                   float* __restrict__ rowsum,
                                                   float* __restrict__ degcnt, int E) {
  int j = blockIdx.x * 4 + (threadIdx.x >> 6);
  int lane = threadIdx.x & 63;
  if (j >= E) return;
  int s = srcP[j], t = dstP[j];
  float acc = 0.f;
  if constexpr (DIM == 512) {
    H8 a, b;
    a.u = *(reinterpret_cast<const uint4*>(h + (size_t)s * 512) + lane);
    b.u = *(reinterpret_cast<const uint4*>(h + (size_t)t * 512) + lane);
    #pragma unroll
    for (int i = 0; i < 4; i++) acc = dot2(a.h[i], b.h[i], acc);
  } else if constexpr (DIM == 256) {
    H4 a, b;
    a.u = *(reinterpret_cast<const uint2*>(h + (size_t)s * 256) + lane);
    b.u = *(reinterpret_cast<const uint2*>(h + (size_t)t * 256) + lane);
    #pragma unroll
    for (int i = 0; i < 2; i++) acc = dot2(a.h[i], b.h[i], acc);
  } else {
    acc = (float)h[(size_t)s * 64 + lane] * (float)h[(size_t)t * 64 + lane];
  }
  acc = wave_sum(acc);
  if (lane == 0) {
    float simv = acc * invn[s] * invn[t];
    float wv = (s != t && simv > 0.f) ? simv : 0.f;
    w[j] = wv;
    if (wv > 0.f) {
      atomicAdd(&rowsum[s], wv);
      atomicAdd(&degcnt[s], 1.0f);
    }
  }
}

// fallback layer-1 sim on raw x
__global__ __launch_bounds__(256) void simf_kernel(const unsigned short* __restrict__ hb,
                                                   const float* __restrict__ hf,
                                                   const int* __restrict__ flags,
                                                   const int* __restrict__ srcP,
                                                   const int* __restrict__ dstP,
                                                   const float* __restrict__ invn,
                                                   float* __restrict__ w,
                                                   float* __restrict__ rowsum,
                                                   float* __restrict__ degcnt, int E) {
  int j = blockIdx.x * 4 + (threadIdx.x >> 6);
  int lane = threadIdx.x & 63;
  if (j >= E) return;
  int s = srcP[j], t = dstP[j];
  float acc = 0.f;
  if (flags[1]) {
    const float4* ap = reinterpret_cast<const float4*>(hf + (size_t)s * 512) + lane * 2;
    const float4* bp = reinterpret_cast<const float4*>(hf + (size_t)t * 512) + lane * 2;
    float4 a0 = ap[0], a1 = ap[1], b0 = bp[0], b1 = bp[1];
    acc = a0.x*b0.x + a0.y*b0.y + a0.z*b0.z + a0.w*b0.w
        + a1.x*b1.x + a1.y*b1.y + a1.z*b1.z + a1.w*b1.w;
  } else {
    uint4 a = *(reinterpret_cast<const uint4*>(hb + (size_t)s * 512) + lane);
    uint4 b = *(reinterpret_cast<const uint4*>(hb + (size_t)t * 512) + lane);
    unsigned int av[4] = {a.x, a.y, a.z, a.w};
    unsigned int bv[4] = {b.x, b.y, b.z, b.w};
    #pragma unroll
    for (int i = 0; i < 4; i++)
      acc += bf2f(av[i] & 0xffffu) * bf2f(bv[i] & 0xffffu)
           + bf2f(av[i] >> 16) * bf2f(bv[i] >> 16);
  }
  acc = wave_sum(acc);
  if (lane == 0) {
    float simv = acc * invn[s] * invn[t];
    float wv = (s != t && simv > 0.f) ? simv : 0.f;
    w[j] = wv;
    if (wv > 0.f) {
      atomicAdd(&rowsum[s], wv);
      atomicAdd(&degcnt[s], 1.0f);
    }
  }
}

// ---------------- node / edge scalar stages ----------------

__global__ void node_a_kernel(float* __restrict__ rowsum, const float* __restrict__ degcnt,
                              float* __restrict__ sw, float* __restrict__ deg2, int n) {
  int i = blockIdx.x * blockDim.x + threadIdx.x;
  if (i >= n) return;
  float rs = rowsum[i];
  rowsum[i] = (rs > 0.f) ? 1.0f / rs : 0.0f;
  float lam = 1.0f / (degcnt[i] + 1.0f);
  float s = expf(lam);
  sw[i] = s;
  deg2[i] = s;
}

__global__ void edge_b_kernel(float* __restrict__ w, const int* __restrict__ srcP,
                              const int* __restrict__ dstP, const float* __restrict__ invrs,
                              float* __restrict__ deg2, int E) {
  int j = blockIdx.x * blockDim.x + threadIdx.x;
  if (j >= E) return;
  float wv = w[j];
  if (wv > 0.f) {
    float ewv = expf(wv * invrs[srcP[j]]);
    w[j] = ewv;
    atomicAdd(&deg2[dstP[j]], ewv);
  }
}

__global__ void node_b_kernel(const float* __restrict__ deg2, float* __restrict__ dinv, int n) {
  int i = blockIdx.x * blockDim.x + threadIdx.x;
  if (i < n) dinv[i] = rsqrtf(deg2[i]);
}

// ---------------- GEMM (f16 MFMA) ----------------

__global__ void transpose_kernel(const unsigned short* __restrict__ Wb,
                                 const float* __restrict__ Wf,
                                 const int* __restrict__ flags,
                                 _Float16* __restrict__ WT,
                                 int K, int Nc, int Npad) {
  int idx = blockIdx.x * blockDim.x + threadIdx.x;
  if (idx >= Npad * K) return;
  int nn = idx / K, k = idx - nn * K;
  _Float16 v = (_Float16)0.f;
  if (nn < Nc) {
    if (flags[1]) v = (_Float16)Wf[(size_t)k * Nc + nn];
    else          v = (_Float16)bf2f((unsigned int)Wb[(size_t)k * Nc + nn]);
  }
  WT[idx] = v;
}

// wide GEMM: one wave owns a 16-row m-tile and all NT n-tiles; A read once.
template<int NT, int KSTEPS>
__global__ __launch_bounds__(256) void gemmw_kernel(const _Float16* __restrict__ Ah,
                                                    const float* __restrict__ Af,
                                                    const unsigned short* __restrict__ Abf,
                                                    const int* __restrict__ flags,
                                                    int useflags,
                                                    const _Float16* __restrict__ BT,
                                                    _Float16* __restrict__ C,
                                                    int M, int Npad) {
  constexpr int K = KSTEPS * 32;
  int mt = blockIdx.x * 4 + (threadIdx.x >> 6);
  if (mt * 16 >= M) return;
  int lane = threadIdx.x & 63;
  int r = lane & 15, quad = lane >> 4;
  int m0 = mt * 16;
  int mode = useflags ? (flags[1] ? 1 : 2) : 0;  // 0=f16, 1=fp32, 2=bf16
  floatx4 acc[NT];
  #pragma unroll
  for (int nt = 0; nt < NT; nt++) acc[nt] = floatx4{0.f, 0.f, 0.f, 0.f};
  const uint4* ap = reinterpret_cast<const uint4*>(Ah + (size_t)(m0 + r) * K);
  const float* af = Af + (size_t)(m0 + r) * K + quad * 8;
  const unsigned short* ab = Abf + (size_t)(m0 + r) * K + quad * 8;
  for (int kk = 0; kk < KSTEPS; kk++) {
    H8 a;
    if (mode == 1) {
      float4 x0 = *reinterpret_cast<const float4*>(af + kk * 32);
      float4 x1 = *reinterpret_cast<const float4*>(af + kk * 32 + 4);
      a.v[0] = (_Float16)x0.x; a.v[1] = (_Float16)x0.y;
      a.v[2] = (_Float16)x0.z; a.v[3] = (_Float16)x0.w;
      a.v[4] = (_Float16)x1.x; a.v[5] = (_Float16)x1.y;
      a.v[6] = (_Float16)x1.z; a.v[7] = (_Float16)x1.w;
    } else if (mode == 2) {
      uint4 u = *reinterpret_cast<const uint4*>(ab + kk * 32);
      unsigned int uu[4] = {u.x, u.y, u.z, u.w};
      #pragma unroll
      for (int i = 0; i < 4; i++) {
        a.v[2 * i] = (_Float16)bf2f(uu[i] & 0xffffu);
        a.v[2 * i + 1] = (_Float16)bf2f(uu[i] >> 16);
      }
    } else {
      a.u = ap[(kk << 2) + quad];
    }
    #pragma unroll
    for (int nt = 0; nt < NT; nt++) {
      H8 b;
      b.u = *reinterpret_cast<const uint4*>(BT + (size_t)(nt * 16 + r) * K + kk * 32 + quad * 8);
      acc[nt] = __builtin_amdgcn_mfma_f32_16x16x32_f16(a.v, b.v, acc[nt], 0, 0, 0);
    }
  }
  #pragma unroll
  for (int nt = 0; nt < NT; nt++) {
    #pragma unroll
    for (int i = 0; i < 4; i++)
      C[(size_t)(m0 + quad * 4 + i) * Npad + nt * 16 + r] = (_Float16)acc[nt][i];
  }
}

// ---------------- aggregation (dst-sorted contiguous edges) ----------------

template<int BLK, int NC, int STRIDE>
__global__ __launch_bounds__(BLK) void agg_relu_kernel(
    const _Float16* __restrict__ hp, const float* __restrict__ ew,
    const int* __restrict__ srcP, const int* __restrict__ off,
    const float* __restrict__ dinv, const float* __restrict__ sw,
    const unsigned short* __restrict__ biasb, const float* __restrict__ biasf,
    const int* __restrict__ flags, _Float16* __restrict__ out, int n) {
  int i = blockIdx.x;
  if (i >= n) return;
  int c = threadIdx.x;
  __shared__ float scoef[BLK];
  __shared__ int ssrc[BLK];
  float di = dinv[i];
  float acc = 0.f;
  if (c < NC) acc = sw[i] * di * di * (float)hp[(size_t)i * STRIDE + c];
  int e0 = off[i], e1 = off[i + 1];
  for (int base = e0; base < e1; base += BLK) {
    int j = base + c;
    if (j < e1) {
      int s = srcP[j];
      ssrc[c] = s;
      scoef[c] = ew[j] * dinv[s] * di;
    }
    __syncthreads();
    int m = min(BLK, e1 - base);
    for (int k = 0; k < m; k++) {
      float cf = scoef[k];
      if (cf != 0.f && c < NC)
        acc += cf * (float)hp[(size_t)ssrc[k] * STRIDE + c];
    }
    __syncthreads();
  }
  if (c < NC) {
    float bb = flags[1] ? biasf[c] : bf2f((unsigned int)biasb[c]);
    float v = acc + bb;
    out[(size_t)i * NC + c] = (_Float16)(v > 0.f ? v : 0.f);
  }
}

__global__ __launch_bounds__(64) void agg_lsm_kernel(
    const _Float16* __restrict__ hp, const float* __restrict__ ew,
    const int* __restrict__ srcP, const int* __restrict__ off,
    const float* __restrict__ dinv, const float* __restrict__ sw,
    const unsigned short* __restrict__ biasb, const float* __restrict__ biasf,
    const int* __restrict__ flags, void* __restrict__ outv, int n) {
  constexpr int BLK = 64, NC = 40, STRIDE = 48;
  int i = blockIdx.x;
  if (i >= n) return;
  int c = threadIdx.x;
  __shared__ float scoef[BLK];
  __shared__ int ssrc[BLK];
  float di = dinv[i];
  float acc = 0.f;
  if (c < NC) acc = sw[i] * di * di * (float)hp[(size_t)i * STRIDE + c];
  int e0 = off[i], e1 = off[i + 1];
  for (int base = e0; base < e1; base += BLK) {
    int j = base + c;
    if (j < e1) {
      int s = srcP[j];
      ssrc[c] = s;
      scoef[c] = ew[j] * dinv[s] * di;
    }
    __syncthreads();
    int m = min(BLK, e1 - base);
    for (int k = 0; k < m; k++) {
      float cf = scoef[k];
      if (cf != 0.f && c < NC)
        acc += cf * (float)hp[(size_t)ssrc[k] * STRIDE + c];
    }
    __syncthreads();
  }
  int f32 = flags[1];
  float bb = 0.f;
  if (c < NC) bb = f32 ? biasf[c] : bf2f((unsigned int)biasb[c]);
  float v = (c < NC) ? acc + bb : -3.0e38f;
  float vm = wave_max(v);
  float ex = (c < NC) ? expf(v - vm) : 0.f;
  float se = wave_sum(ex);
  float ls = logf(se);
  if (c < NC) {
    float r = v - vm - ls;
    if (f32) ((float*)outv)[(size_t)i * NC + c] = r;
    else ((unsigned short*)outv)[(size_t)i * NC + c] = f2bf(r);
  }
}

// ---------------- host ----------------

extern "C" void kernel_launch(void* const* d_in, const int* in_sizes, int n_in,
                              void* d_out, int out_size, void* d_ws, size_t ws_size,
                              hipStream_t stream) {
  const unsigned short* xb = (const unsigned short*)d_in[0];
  const float* xf          = (const float*)d_in[0];
  const int* ei            = (const int*)d_in[1];

  const int H  = in_sizes[3];            // 256
  const int F  = in_sizes[2] / H;        // 512
  const int D2 = in_sizes[5];            // 64
  const int C  = in_sizes[7];            // 40
  const int N  = in_sizes[0] / F;        // 50000
  const int E  = in_sizes[1] / 2;        // 1600000
  const int CP = 48;

  char* p = (char*)d_ws;
  auto alloc = [&](size_t bytes) -> char* {
    char* r = p;
    p += (bytes + 255) & ~(size_t)255;
    return r;
  };
  int*   srcP   = (int*)alloc((size_t)E * 4);
  int*   dstP   = (int*)alloc((size_t)E * 4);
  float* wbuf   = (float*)alloc((size_t)E * 4);
  int*   off    = (int*)alloc((size_t)(N + 1) * 4);
  int*   cur    = (int*)alloc((size_t)N * 4);
  float* invn   = (float*)alloc((size_t)N * 4);
  float* rowsum = (float*)alloc((size_t)N * 4);
  float* degcnt = (float*)alloc((size_t)N * 4);
  float* sw     = (float*)alloc((size_t)N * 4);
  float* deg2   = (float*)alloc((size_t)N * 4);
  float* dinv   = (float*)alloc((size_t)N * 4);
  int*   flags  = (int*)alloc(256);
  int*   bsum   = (int*)alloc(4096 * 4);
  _Float16* WT  = (_Float16*)alloc((size_t)256 * 512 * 2);
  _Float16* hp  = (_Float16*)alloc((size_t)N * 256 * 2);
  size_t used = (size_t)(p - (char*)d_ws);
  size_t xh_bytes = (size_t)N * 512 * 2;
  bool big = (used + xh_bytes + 256) <= ws_size;
  _Float16* xh = big ? (_Float16*)alloc(xh_bytes) : hp;

  _Float16* h1 = (_Float16*)d_in[0];     // x dead after layer-1 reads (25.6 MB < x buf)
  _Float16* h2 = hp + (size_t)N * 64;    // disjoint from later hp use

  const int TB = 256;
  int nblk = (N + TB - 1) / TB;
  int eblk = (E + TB - 1) / TB;
  int nwav = (N + 3) / 4;
  int ewav = (E + 3) / 4;
  int mt4  = (N / 16 + 3) / 4;
  int nb1024 = (N + 1023) / 1024;

  detect_kernel<<<1, 256, 0, stream>>>(ei, (const unsigned int*)d_in[2], flags, E);

  // CSR by dst -> permuted edge arrays
  hipMemsetAsync(cur, 0, (size_t)N * 4, stream);
  count_kernel<<<eblk, TB, 0, stream>>>(ei, flags, cur, E, N);
  scan1_kernel<<<nb1024, 1024, 0, stream>>>(cur, off, bsum, N);
  scan2_kernel<<<1, 1024, 0, stream>>>(bsum, nb1024);
  scan3_kernel<<<nblk, TB, 0, stream>>>(off, bsum, N);
  copy_kernel<<<nblk, TB, 0, stream>>>(off, cur, N);
  fill_kernel<<<eblk, TB, 0, stream>>>(ei, flags, cur, srcP, dstP, E, N);

  // ---------- layer 1: x(512) -> h1(256) ----------
  hipMemsetAsync(rowsum, 0, (size_t)N * 4, stream);
  hipMemsetAsync(degcnt, 0, (size_t)N * 4, stream);
  if (big) {
    convert_norm_kernel<<<nwav, TB, 0, stream>>>(xf, xb, flags, xh, invn, N);
    simb_kernel<512><<<ewav, TB, 0, stream>>>(xh, srcP, dstP, invn, wbuf, rowsum, degcnt, E);
  } else {
    norm8_kernel<<<nwav, TB, 0, stream>>>(xb, xf, flags, invn, N);
    simf_kernel<<<ewav, TB, 0, stream>>>(xb, xf, flags, srcP, dstP, invn, wbuf, rowsum, degcnt, E);
  }
  node_a_kernel<<<nblk, TB, 0, stream>>>(rowsum, degcnt, sw, deg2, N);
  edge_b_kernel<<<eblk, TB, 0, stream>>>(wbuf, srcP, dstP, rowsum, deg2, E);
  node_b_kernel<<<nblk, TB, 0, stream>>>(deg2, dinv, N);
  transpose_kernel<<<(H * F + TB - 1) / TB, TB, 0, stream>>>(
      (const unsigned short*)d_in[2], (const float*)d_in[2], flags, WT, F, H, H);
  gemmw_kernel<16, 16><<<mt4, TB, 0, stream>>>(
      xh, xf, xb, flags, big ? 0 : 1, WT, hp, N, H);
  agg_relu_kernel<256, 256, 256><<<N, 256, 0, stream>>>(
      hp, wbuf, srcP, off, dinv, sw,
      (const unsigned short*)d_in[3], (const float*)d_in[3], flags, h1, N);

  // ---------- layer 2: h1(256) -> h2(64) ----------
  hipMemsetAsync(rowsum, 0, (size_t)N * 4, stream);
  hipMemsetAsync(degcnt, 0, (size_t)N * 4, stream);
  norm256_kernel<<<nwav, TB, 0, stream>>>(h1, invn, N);
  simb_kernel<256><<<ewav, TB, 0, stream>>>(h1, srcP, dstP, invn, wbuf, rowsum, degcnt, E);
  node_a_kernel<<<nblk, TB, 0, stream>>>(rowsum, degcnt, sw, deg2, N);
  edge_b_kernel<<<eblk, TB, 0, stream>>>(wbuf, srcP, dstP, rowsum, deg2, E);
  node_b_kernel<<<nblk, TB, 0, stream>>>(deg2, dinv, N);
  transpose_kernel<<<(D2 * H + TB - 1) / TB, TB, 0, stream>>>(
      (const unsigned short*)d_in[4], (const float*)d_in[4], flags, WT, H, D2, D2);
  gemmw_kernel<4, 8><<<mt4, TB, 0, stream>>>(h1, xf, xb, flags, 0, WT, hp, N, D2);
  agg_relu_kernel<64, 64, 64><<<N, 64, 0, stream>>>(
      hp, wbuf, srcP, off, dinv, sw,
      (const unsigned short*)d_in[5], (const float*)d_in[5], flags, h2, N);

  // ---------- layer 3: h2(64) -> out(40), fused log_softmax ----------
  hipMemsetAsync(rowsum, 0, (size_t)N * 4, stream);
  hipMemsetAsync(degcnt, 0, (size_t)N * 4, stream);
  norm64_kernel<<<nwav, TB, 0, stream>>>(h2, invn, N);
  simb_kernel<64><<<ewav, TB, 0, stream>>>(h2, srcP, dstP, invn, wbuf, rowsum, degcnt, E);
  node_a_kernel<<<nblk, TB, 0, stream>>>(rowsum, degcnt, sw, deg2, N);
  edge_b_kernel<<<eblk, TB, 0, stream>>>(wbuf, srcP, dstP, rowsum, deg2, E);
  node_b_kernel<<<nblk, TB, 0, stream>>>(deg2, dinv, N);
  transpose_kernel<<<(CP * D2 + TB - 1) / TB, TB, 0, stream>>>(
      (const unsigned short*)d_in[6], (const float*)d_in[6], flags, WT, D2, C, CP);
  gemmw_kernel<3, 2><<<mt4, TB, 0, stream>>>(h2, xf, xb, flags, 0, WT, hp, N, CP);
  agg_lsm_kernel<<<N, 64, 0, stream>>>(
      hp, wbuf, srcP, off, dinv, sw,
      (const unsigned short*)d_in[7], (const float*)d_in[7], flags, d_out, N);
}

// Round 6
// 1837.553 us; speedup vs baseline: 1.6956x; 1.2816x over previous
//
#include <hip/hip_runtime.h>
#include <stdint.h>

typedef __attribute__((ext_vector_type(8))) _Float16 half8v;
typedef __attribute__((ext_vector_type(2))) _Float16 half2v;
typedef __attribute__((ext_vector_type(4))) float floatx4;

union H8 { uint4 u; half8v v; half2v h[4]; };
union H4 { uint2 u; half2v h[2]; };

__device__ __forceinline__ float bf2f(unsigned int u) {
  union { unsigned int i; float f; } x;
  x.i = u << 16;
  return x.f;
}

#if __has_builtin(__builtin_amdgcn_fdot2)
__device__ __forceinline__ float dot2(half2v a, half2v b, float c) {
  return __builtin_amdgcn_fdot2(a, b, c, false);
}
#else
__device__ __forceinline__ float dot2(half2v a, half2v b, float c) {
  return c + (float)a.x * (float)b.x + (float)a.y * (float)b.y;
}
#endif

__device__ __forceinline__ float wave_sum(float v) {
  #pragma unroll
  for (int m = 32; m > 0; m >>= 1) v += __shfl_xor(v, m, 64);
  return v;
}

__device__ __forceinline__ float wave_max(float v) {
  #pragma unroll
  for (int m = 32; m > 0; m >>= 1) v = fmaxf(v, __shfl_xor(v, m, 64));
  return v;
}

__device__ __forceinline__ unsigned short f2bf(float f) {
  union { float f; unsigned int u; } x; x.f = f;
  unsigned int r = x.u + 0x7fffu + ((x.u >> 16) & 1u);
  return (unsigned short)(r >> 16);
}

// -------- dtype detection: flags[0]=edges int64, flags[1]=floats fp32 --------

__global__ void detect_kernel(const int* __restrict__ ei, const unsigned int* __restrict__ w1,
                              int* __restrict__ flags, int E) {
  __shared__ int nz, sane;
  if (threadIdx.x == 0) { nz = 0; sane = 0; }
  __syncthreads();
  for (int i = threadIdx.x; i < 2048; i += blockDim.x) {
    if (i < E && ei[2 * i + 1] != 0) atomicAdd(&nz, 1);
    union { unsigned int u; float f; } c; c.u = w1[i];
    float af = fabsf(c.f);
    if (c.f == c.f && af > 1e-10f && af < 1e10f) atomicAdd(&sane, 1);
  }
  __syncthreads();
  if (threadIdx.x == 0) {
    flags[0] = (nz == 0) ? 1 : 0;
    flags[1] = (sane > 1024) ? 1 : 0;
  }
}

// ---------------- CSR build (by dst) with inline edge decode ----------------

__global__ void count_kernel(const int* __restrict__ ei, const int* __restrict__ flags,
                             int* __restrict__ cnt, int E, int N) {
  int e = blockIdx.x * blockDim.x + threadIdx.x;
  if (e >= E) return;
  int d = flags[0] ? ei[2 * (E + e)] : ei[E + e];
  d = ((unsigned)d < (unsigned)N) ? d : 0;
  atomicAdd(&cnt[d], 1);
}

__global__ void scan1_kernel(const int* __restrict__ cnt, int* __restrict__ off,
                             int* __restrict__ bsum, int n) {
  __shared__ int buf[1024];
  int t = threadIdx.x;
  int i = blockIdx.x * 1024 + t;
  int v = (i < n) ? cnt[i] : 0;
  buf[t] = v;
  __syncthreads();
  for (int o = 1; o < 1024; o <<= 1) {
    int a = (t >= o) ? buf[t - o] : 0;
    __syncthreads();
    buf[t] += a;
    __syncthreads();
  }
  if (i < n) off[i + 1] = buf[t];
  if (t == 1023) bsum[blockIdx.x] = buf[1023];
}

__global__ void scan2_kernel(int* __restrict__ bsum, int nb) {
  __shared__ int buf[1024];
  int t = threadIdx.x;
  int v = (t < nb) ? bsum[t] : 0;
  buf[t] = v;
  __syncthreads();
  for (int o = 1; o < 1024; o <<= 1) {
    int a = (t >= o) ? buf[t - o] : 0;
    __syncthreads();
    buf[t] += a;
    __syncthreads();
  }
  if (t < nb) bsum[t] = buf[t];
}

__global__ void scan3_kernel(int* __restrict__ off, const int* __restrict__ bsum, int n) {
  int i = blockIdx.x * blockDim.x + threadIdx.x;
  if (i == 0) off[0] = 0;
  if (i < n) {
    int b = i >> 10;
    if (b > 0) off[i + 1] += bsum[b - 1];
  }
}

__global__ void copy_kernel(const int* __restrict__ off, int* __restrict__ cur, int n) {
  int i = blockIdx.x * blockDim.x + threadIdx.x;
  if (i < n) cur[i] = off[i];
}

__global__ void fill_kernel(const int* __restrict__ ei, const int* __restrict__ flags,
                            int* __restrict__ cur, int* __restrict__ srcP,
                            int* __restrict__ dstP, int E, int N) {
  int e = blockIdx.x * blockDim.x + threadIdx.x;
  if (e >= E) return;
  int s, d;
  if (flags[0]) { s = ei[2 * e]; d = ei[2 * (E + e)]; }
  else          { s = ei[e];     d = ei[E + e]; }
  s = ((unsigned)s < (unsigned)N) ? s : 0;
  d = ((unsigned)d < (unsigned)N) ? d : 0;
  int pos = atomicAdd(&cur[d], 1);
  srcP[pos] = s;
  dstP[pos] = d;
}

// -------- layer-1 convert+norm (fp32 or bf16 input -> f16 rows + invn) --------

__global__ __launch_bounds__(256) void convert_norm_kernel(
    const float* __restrict__ xf, const unsigned short* __restrict__ xb,
    const int* __restrict__ flags, _Float16* __restrict__ xo,
    float* __restrict__ invn, int n) {
  int row = blockIdx.x * 4 + (threadIdx.x >> 6);
  int lane = threadIdx.x & 63;
  if (row >= n) return;
  float ss = 0.f;
  H8 o;
  if (flags[1]) {
    const float4* vp = reinterpret_cast<const float4*>(xf + (size_t)row * 512) + lane * 2;
    float4 a = vp[0], b = vp[1];
    ss = a.x*a.x + a.y*a.y + a.z*a.z + a.w*a.w + b.x*b.x + b.y*b.y + b.z*b.z + b.w*b.w;
    o.v[0] = (_Float16)a.x; o.v[1] = (_Float16)a.y;
    o.v[2] = (_Float16)a.z; o.v[3] = (_Float16)a.w;
    o.v[4] = (_Float16)b.x; o.v[5] = (_Float16)b.y;
    o.v[6] = (_Float16)b.z; o.v[7] = (_Float16)b.w;
  } else {
    uint4 v = *(reinterpret_cast<const uint4*>(xb + (size_t)row * 512) + lane);
    unsigned int a[4] = {v.x, v.y, v.z, v.w};
    #pragma unroll
    for (int i = 0; i < 4; i++) {
      float lo = bf2f(a[i] & 0xffffu), hi = bf2f(a[i] >> 16);
      ss += lo * lo + hi * hi;
      o.v[2 * i] = (_Float16)lo;
      o.v[2 * i + 1] = (_Float16)hi;
    }
  }
  *(reinterpret_cast<uint4*>(xo + (size_t)row * 512) + lane) = o.u;
  ss = wave_sum(ss);
  if (lane == 0) invn[row] = (ss == 0.f) ? 1.0f : rsqrtf(ss);
}

// fallback norm over raw x (no f16 copy available)
__global__ __launch_bounds__(256) void norm8_kernel(const unsigned short* __restrict__ hb,
                                                    const float* __restrict__ hf,
                                                    const int* __restrict__ flags,
                                                    float* __restrict__ invn, int n) {
  int wid = blockIdx.x * 4 + (threadIdx.x >> 6);
  int lane = threadIdx.x & 63;
  if (wid >= n) return;
  float s = 0.f;
  if (flags[1]) {
    const float4* vp = reinterpret_cast<const float4*>(hf + (size_t)wid * 512) + lane * 2;
    float4 a = vp[0], b = vp[1];
    s = a.x*a.x + a.y*a.y + a.z*a.z + a.w*a.w + b.x*b.x + b.y*b.y + b.z*b.z + b.w*b.w;
  } else {
    uint4 v = *(reinterpret_cast<const uint4*>(hb + (size_t)wid * 512) + lane);
    unsigned int a[4] = {v.x, v.y, v.z, v.w};
    #pragma unroll
    for (int i = 0; i < 4; i++) {
      float lo = bf2f(a[i] & 0xffffu), hi = bf2f(a[i] >> 16);
      s += lo * lo + hi * hi;
    }
  }
  s = wave_sum(s);
  if (lane == 0) invn[wid] = (s == 0.f) ? 1.0f : rsqrtf(s);
}

// ------- per-edge cosine sim: 4 edges/wave, XCD-swizzled edge mapping -------
// grid = chunk*8 blocks; block b covers edges [( (b&7)*chunk + (b>>3) )*16, +16)

template<int DIM>
__global__ __launch_bounds__(256) void simb_kernel(const _Float16* __restrict__ h,
                                                   const int* __restrict__ srcP,
                                                   const int* __restrict__ dstP,
                                                   const float* __restrict__ invn,
                                                   float* __restrict__ w,
                                                   float* __restrict__ rowsum,
                                                   float* __restrict__ degcnt,
                                                   int E, int chunk) {
  int nb = (blockIdx.x & 7) * chunk + (blockIdx.x >> 3);
  int lane = threadIdx.x & 63;
  int j0 = (nb * 4 + (threadIdx.x >> 6)) * 4;   // first of 4 edges for this wave
  if (j0 >= E) return;
  int4 s4 = *reinterpret_cast<const int4*>(srcP + j0);
  int4 t4 = *reinterpret_cast<const int4*>(dstP + j0);
  int ss[4] = {s4.x, s4.y, s4.z, s4.w};
  int tt[4] = {t4.x, t4.y, t4.z, t4.w};
  bool valid[4];
  #pragma unroll
  for (int e = 0; e < 4; e++) {
    valid[e] = (j0 + e) < E;
    if (!valid[e]) { ss[e] = 0; tt[e] = 0; }
  }
  float acc[4];
  if constexpr (DIM == 512) {
    H8 a[4], b[4];
    #pragma unroll
    for (int e = 0; e < 4; e++) {
      a[e].u = *(reinterpret_cast<const uint4*>(h + (size_t)ss[e] * 512) + lane);
      b[e].u = *(reinterpret_cast<const uint4*>(h + (size_t)tt[e] * 512) + lane);
    }
    #pragma unroll
    for (int e = 0; e < 4; e++) {
      acc[e] = 0.f;
      #pragma unroll
      for (int i = 0; i < 4; i++) acc[e] = dot2(a[e].h[i], b[e].h[i], acc[e]);
    }
  } else if constexpr (DIM == 256) {
    H4 a[4], b[4];
    #pragma unroll
    for (int e = 0; e < 4; e++) {
      a[e].u = *(reinterpret_cast<const uint2*>(h + (size_t)ss[e] * 256) + lane);
      b[e].u = *(reinterpret_cast<const uint2*>(h + (size_t)tt[e] * 256) + lane);
    }
    #pragma unroll
    for (int e = 0; e < 4; e++) {
      acc[e] = 0.f;
      #pragma unroll
      for (int i = 0; i < 2; i++) acc[e] = dot2(a[e].h[i], b[e].h[i], acc[e]);
    }
  } else {
    _Float16 a[4], b[4];
    #pragma unroll
    for (int e = 0; e < 4; e++) {
      a[e] = h[(size_t)ss[e] * 64 + lane];
      b[e] = h[(size_t)tt[e] * 64 + lane];
    }
    #pragma unroll
    for (int e = 0; e < 4; e++) acc[e] = (float)a[e] * (float)b[e];
  }
  // 4 independent butterfly reductions, interleaved for ILP
  #pragma unroll
  for (int m = 32; m > 0; m >>= 1) {
    #pragma unroll
    for (int e = 0; e < 4; e++) acc[e] += __shfl_xor(acc[e], m, 64);
  }
  // distribute tail across lanes 0..3
  float myacc = acc[0];
  int myS = ss[0], myT = tt[0];
  bool myV = valid[0];
  #pragma unroll
  for (int e = 1; e < 4; e++) {
    if (lane == e) { myacc = acc[e]; myS = ss[e]; myT = tt[e]; myV = valid[e]; }
  }
  if (lane < 4 && myV) {
    float simv = myacc * invn[myS] * invn[myT];
    float wv = (myS != myT && simv > 0.f) ? simv : 0.f;
    w[j0 + lane] = wv;
    if (wv > 0.f) {
      atomicAdd(&rowsum[myS], wv);
      atomicAdd(&degcnt[myS], 1.0f);
    }
  }
}

// fallback layer-1 sim on raw x (one edge/wave; rare path)
__global__ __launch_bounds__(256) void simf_kernel(const unsigned short* __restrict__ hb,
                                                   const float* __restrict__ hf,
                                                   const int* __restrict__ flags,
                                                   const int* __restrict__ srcP,
                                                   const int* __restrict__ dstP,
                                                   const float* __restrict__ invn,
                                                   float* __restrict__ w,
                                                   float* __restrict__ rowsum,
                                                   float* __restrict__ degcnt, int E) {
  int j = blockIdx.x * 4 + (threadIdx.x >> 6);
  int lane = threadIdx.x & 63;
  if (j >= E) return;
  int s = srcP[j], t = dstP[j];
  float acc = 0.f;
  if (flags[1]) {
    const float4* ap = reinterpret_cast<const float4*>(hf + (size_t)s * 512) + lane * 2;
    const float4* bp = reinterpret_cast<const float4*>(hf + (size_t)t * 512) + lane * 2;
    float4 a0 = ap[0], a1 = ap[1], b0 = bp[0], b1 = bp[1];
    acc = a0.x*b0.x + a0.y*b0.y + a0.z*b0.z + a0.w*b0.w
        + a1.x*b1.x + a1.y*b1.y + a1.z*b1.z + a1.w*b1.w;
  } else {
    uint4 a = *(reinterpret_cast<const uint4*>(hb + (size_t)s * 512) + lane);
    uint4 b = *(reinterpret_cast<const uint4*>(hb + (size_t)t * 512) + lane);
    unsigned int av[4] = {a.x, a.y, a.z, a.w};
    unsigned int bv[4] = {b.x, b.y, b.z, b.w};
    #pragma unroll
    for (int i = 0; i < 4; i++)
      acc += bf2f(av[i] & 0xffffu) * bf2f(bv[i] & 0xffffu)
           + bf2f(av[i] >> 16) * bf2f(bv[i] >> 16);
  }
  acc = wave_sum(acc);
  if (lane == 0) {
    float simv = acc * invn[s] * invn[t];
    float wv = (s != t && simv > 0.f) ? simv : 0.f;
    w[j] = wv;
    if (wv > 0.f) {
      atomicAdd(&rowsum[s], wv);
      atomicAdd(&degcnt[s], 1.0f);
    }
  }
}

// ---------------- node / edge scalar stages ----------------

__global__ void node_a_kernel(float* __restrict__ rowsum, const float* __restrict__ degcnt,
                              float* __restrict__ sw, float* __restrict__ deg2, int n) {
  int i = blockIdx.x * blockDim.x + threadIdx.x;
  if (i >= n) return;
  float rs = rowsum[i];
  rowsum[i] = (rs > 0.f) ? 1.0f / rs : 0.0f;
  float lam = 1.0f / (degcnt[i] + 1.0f);
  float s = expf(lam);
  sw[i] = s;
  deg2[i] = s;
}

__global__ void edge_b_kernel(float* __restrict__ w, const int* __restrict__ srcP,
                              const int* __restrict__ dstP, const float* __restrict__ invrs,
                              float* __restrict__ deg2, int E) {
  int j = blockIdx.x * blockDim.x + threadIdx.x;
  if (j >= E) return;
  float wv = w[j];
  if (wv > 0.f) {
    float ewv = expf(wv * invrs[srcP[j]]);
    w[j] = ewv;
    atomicAdd(&deg2[dstP[j]], ewv);
  }
}

__global__ void node_b_kernel(const float* __restrict__ deg2, float* __restrict__ dinv, int n) {
  int i = blockIdx.x * blockDim.x + threadIdx.x;
  if (i < n) dinv[i] = rsqrtf(deg2[i]);
}

// ---------------- GEMM (f16 MFMA) ----------------

__global__ void transpose_kernel(const unsigned short* __restrict__ Wb,
                                 const float* __restrict__ Wf,
                                 const int* __restrict__ flags,
                                 _Float16* __restrict__ WT,
                                 int K, int Nc, int Npad) {
  int idx = blockIdx.x * blockDim.x + threadIdx.x;
  if (idx >= Npad * K) return;
  int nn = idx / K, k = idx - nn * K;
  _Float16 v = (_Float16)0.f;
  if (nn < Nc) {
    if (flags[1]) v = (_Float16)Wf[(size_t)k * Nc + nn];
    else          v = (_Float16)bf2f((unsigned int)Wb[(size_t)k * Nc + nn]);
  }
  WT[idx] = v;
}

// wide GEMM: one wave owns a 16-row m-tile and all NT n-tiles; A read once.
template<int NT, int KSTEPS>
__global__ __launch_bounds__(256) void gemmw_kernel(const _Float16* __restrict__ Ah,
                                                    const float* __restrict__ Af,
                                                    const unsigned short* __restrict__ Abf,
                                                    const int* __restrict__ flags,
                                                    int useflags,
                                                    const _Float16* __restrict__ BT,
                                                    _Float16* __restrict__ C,
                                                    int M, int Npad) {
  constexpr int K = KSTEPS * 32;
  int mt = blockIdx.x * 4 + (threadIdx.x >> 6);
  if (mt * 16 >= M) return;
  int lane = threadIdx.x & 63;
  int r = lane & 15, quad = lane >> 4;
  int m0 = mt * 16;
  int mode = useflags ? (flags[1] ? 1 : 2) : 0;  // 0=f16, 1=fp32, 2=bf16
  floatx4 acc[NT];
  #pragma unroll
  for (int nt = 0; nt < NT; nt++) acc[nt] = floatx4{0.f, 0.f, 0.f, 0.f};
  const uint4* ap = reinterpret_cast<const uint4*>(Ah + (size_t)(m0 + r) * K);
  const float* af = Af + (size_t)(m0 + r) * K + quad * 8;
  const unsigned short* ab = Abf + (size_t)(m0 + r) * K + quad * 8;
  for (int kk = 0; kk < KSTEPS; kk++) {
    H8 a;
    if (mode == 1) {
      float4 x0 = *reinterpret_cast<const float4*>(af + kk * 32);
      float4 x1 = *reinterpret_cast<const float4*>(af + kk * 32 + 4);
      a.v[0] = (_Float16)x0.x; a.v[1] = (_Float16)x0.y;
      a.v[2] = (_Float16)x0.z; a.v[3] = (_Float16)x0.w;
      a.v[4] = (_Float16)x1.x; a.v[5] = (_Float16)x1.y;
      a.v[6] = (_Float16)x1.z; a.v[7] = (_Float16)x1.w;
    } else if (mode == 2) {
      uint4 u = *reinterpret_cast<const uint4*>(ab + kk * 32);
      unsigned int uu[4] = {u.x, u.y, u.z, u.w};
      #pragma unroll
      for (int i = 0; i < 4; i++) {
        a.v[2 * i] = (_Float16)bf2f(uu[i] & 0xffffu);
        a.v[2 * i + 1] = (_Float16)bf2f(uu[i] >> 16);
      }
    } else {
      a.u = ap[(kk << 2) + quad];
    }
    #pragma unroll
    for (int nt = 0; nt < NT; nt++) {
      H8 b;
      b.u = *reinterpret_cast<const uint4*>(BT + (size_t)(nt * 16 + r) * K + kk * 32 + quad * 8);
      acc[nt] = __builtin_amdgcn_mfma_f32_16x16x32_f16(a.v, b.v, acc[nt], 0, 0, 0);
    }
  }
  #pragma unroll
  for (int nt = 0; nt < NT; nt++) {
    #pragma unroll
    for (int i = 0; i < 4; i++)
      C[(size_t)(m0 + quad * 4 + i) * Npad + nt * 16 + r] = (_Float16)acc[nt][i];
  }
}

// ---------------- aggregation (dst-sorted contiguous edges) ----------------
// Fused: also writes invn (L2-norm of output row) for the next layer's sim.

template<int BLK, int NC, int STRIDE>
__global__ __launch_bounds__(BLK) void agg_relu_kernel(
    const _Float16* __restrict__ hp, const float* __restrict__ ew,
    const int* __restrict__ srcP, const int* __restrict__ off,
    const float* __restrict__ dinv, const float* __restrict__ sw,
    const unsigned short* __restrict__ biasb, const float* __restrict__ biasf,
    const int* __restrict__ flags, _Float16* __restrict__ out,
    float* __restrict__ invn, int n) {
  int i = blockIdx.x;
  if (i >= n) return;
  int c = threadIdx.x;
  __shared__ float scoef[BLK];
  __shared__ int ssrc[BLK];
  __shared__ float wpart[BLK / 64];
  float di = dinv[i];
  float acc = 0.f;
  if (c < NC) acc = sw[i] * di * di * (float)hp[(size_t)i * STRIDE + c];
  int e0 = off[i], e1 = off[i + 1];
  for (int base = e0; base < e1; base += BLK) {
    int j = base + c;
    if (j < e1) {
      int s = srcP[j];
      ssrc[c] = s;
      scoef[c] = ew[j] * dinv[s] * di;
    }
    __syncthreads();
    int m = min(BLK, e1 - base);
    for (int k = 0; k < m; k++) {
      float cf = scoef[k];
      if (cf != 0.f && c < NC)
        acc += cf * (float)hp[(size_t)ssrc[k] * STRIDE + c];
    }
    __syncthreads();
  }
  float val = 0.f;
  if (c < NC) {
    float bb = flags[1] ? biasf[c] : bf2f((unsigned int)biasb[c]);
    float v = acc + bb;
    val = v > 0.f ? v : 0.f;
    out[(size_t)i * NC + c] = (_Float16)val;
  }
  // fused row-norm of the relu output
  float ws = wave_sum(val * val);
  if constexpr (BLK == 64) {
    if (c == 0) invn[i] = (ws == 0.f) ? 1.0f : rsqrtf(ws);
  } else {
    if ((c & 63) == 0) wpart[c >> 6] = ws;
    __syncthreads();
    if (c == 0) {
      float tot = 0.f;
      #pragma unroll
      for (int k = 0; k < BLK / 64; k++) tot += wpart[k];
      invn[i] = (tot == 0.f) ? 1.0f : rsqrtf(tot);
    }
  }
}

__global__ __launch_bounds__(64) void agg_lsm_kernel(
    const _Float16* __restrict__ hp, const float* __restrict__ ew,
    const int* __restrict__ srcP, const int* __restrict__ off,
    const float* __restrict__ dinv, const float* __restrict__ sw,
    const unsigned short* __restrict__ biasb, const float* __restrict__ biasf,
    const int* __restrict__ flags, void* __restrict__ outv, int n) {
  constexpr int BLK = 64, NC = 40, STRIDE = 48;
  int i = blockIdx.x;
  if (i >= n) return;
  int c = threadIdx.x;
  __shared__ float scoef[BLK];
  __shared__ int ssrc[BLK];
  float di = dinv[i];
  float acc = 0.f;
  if (c < NC) acc = sw[i] * di * di * (float)hp[(size_t)i * STRIDE + c];
  int e0 = off[i], e1 = off[i + 1];
  for (int base = e0; base < e1; base += BLK) {
    int j = base + c;
    if (j < e1) {
      int s = srcP[j];
      ssrc[c] = s;
      scoef[c] = ew[j] * dinv[s] * di;
    }
    __syncthreads();
    int m = min(BLK, e1 - base);
    for (int k = 0; k < m; k++) {
      float cf = scoef[k];
      if (cf != 0.f && c < NC)
        acc += cf * (float)hp[(size_t)ssrc[k] * STRIDE + c];
    }
    __syncthreads();
  }
  int f32 = flags[1];
  float bb = 0.f;
  if (c < NC) bb = f32 ? biasf[c] : bf2f((unsigned int)biasb[c]);
  float v = (c < NC) ? acc + bb : -3.0e38f;
  float vm = wave_max(v);
  float ex = (c < NC) ? expf(v - vm) : 0.f;
  float se = wave_sum(ex);
  float ls = logf(se);
  if (c < NC) {
    float r = v - vm - ls;
    if (f32) ((float*)outv)[(size_t)i * NC + c] = r;
    else ((unsigned short*)outv)[(size_t)i * NC + c] = f2bf(r);
  }
}

// ---------------- host ----------------

extern "C" void kernel_launch(void* const* d_in, const int* in_sizes, int n_in,
                              void* d_out, int out_size, void* d_ws, size_t ws_size,
                              hipStream_t stream) {
  const unsigned short* xb = (const unsigned short*)d_in[0];
  const float* xf          = (const float*)d_in[0];
  const int* ei            = (const int*)d_in[1];

  const int H  = in_sizes[3];            // 256
  const int F  = in_sizes[2] / H;        // 512
  const int D2 = in_sizes[5];            // 64
  const int C  = in_sizes[7];            // 40
  const int N  = in_sizes[0] / F;        // 50000
  const int E  = in_sizes[1] / 2;        // 1600000
  const int CP = 48;

  char* p = (char*)d_ws;
  auto alloc = [&](size_t bytes) -> char* {
    char* r = p;
    p += (bytes + 255) & ~(size_t)255;
    return r;
  };
  int*   srcP   = (int*)alloc((size_t)E * 4 + 16);   // +16: int4 tail slack
  int*   dstP   = (int*)alloc((size_t)E * 4 + 16);
  float* wbuf   = (float*)alloc((size_t)E * 4);
  int*   off    = (int*)alloc((size_t)(N + 1) * 4);
  int*   cur    = (int*)alloc((size_t)N * 4);
  float* invn   = (float*)alloc((size_t)N * 4);
  float* rowsum = (float*)alloc((size_t)N * 4);
  float* degcnt = (float*)alloc((size_t)N * 4);
  float* sw     = (float*)alloc((size_t)N * 4);
  float* deg2   = (float*)alloc((size_t)N * 4);
  float* dinv   = (float*)alloc((size_t)N * 4);
  int*   flags  = (int*)alloc(256);
  int*   bsum   = (int*)alloc(4096 * 4);
  _Float16* WT  = (_Float16*)alloc((size_t)256 * 512 * 2);
  _Float16* hp  = (_Float16*)alloc((size_t)N * 256 * 2);
  size_t used = (size_t)(p - (char*)d_ws);
  size_t xh_bytes = (size_t)N * 512 * 2;
  bool big = (used + xh_bytes + 256) <= ws_size;
  _Float16* xh = big ? (_Float16*)alloc(xh_bytes) : hp;

  _Float16* h1 = (_Float16*)d_in[0];     // x dead after layer-1 reads
  _Float16* h2 = hp + (size_t)N * 64;    // disjoint from later hp use
  size_t rd_span = (size_t)((char*)degcnt - (char*)rowsum) + (size_t)N * 4;

  const int TB = 256;
  int nblk = (N + TB - 1) / TB;
  int eblk = (E + TB - 1) / TB;
  int nwav = (N + 3) / 4;
  int ewav = (E + 3) / 4;
  int mt4  = (N / 16 + 3) / 4;
  int nb1024 = (N + 1023) / 1024;
  // simb grid: 16 edges/block, XCD-swizzled
  int sblocks = (E + 15) / 16;
  int schunk = (sblocks + 7) / 8;
  int sgrid = schunk * 8;

  detect_kernel<<<1, 256, 0, stream>>>(ei, (const unsigned int*)d_in[2], flags, E);

  // CSR by dst -> permuted edge arrays
  hipMemsetAsync(cur, 0, (size_t)N * 4, stream);
  count_kernel<<<eblk, TB, 0, stream>>>(ei, flags, cur, E, N);
  scan1_kernel<<<nb1024, 1024, 0, stream>>>(cur, off, bsum, N);
  scan2_kernel<<<1, 1024, 0, stream>>>(bsum, nb1024);
  scan3_kernel<<<nblk, TB, 0, stream>>>(off, bsum, N);
  copy_kernel<<<nblk, TB, 0, stream>>>(off, cur, N);
  fill_kernel<<<eblk, TB, 0, stream>>>(ei, flags, cur, srcP, dstP, E, N);

  // ---------- layer 1: x(512) -> h1(256) ----------
  hipMemsetAsync(rowsum, 0, rd_span, stream);
  if (big) {
    convert_norm_kernel<<<nwav, TB, 0, stream>>>(xf, xb, flags, xh, invn, N);
    simb_kernel<512><<<sgrid, TB, 0, stream>>>(xh, srcP, dstP, invn, wbuf, rowsum, degcnt, E, schunk);
  } else {
    norm8_kernel<<<nwav, TB, 0, stream>>>(xb, xf, flags, invn, N);
    simf_kernel<<<ewav, TB, 0, stream>>>(xb, xf, flags, srcP, dstP, invn, wbuf, rowsum, degcnt, E);
  }
  node_a_kernel<<<nblk, TB, 0, stream>>>(rowsum, degcnt, sw, deg2, N);
  edge_b_kernel<<<eblk, TB, 0, stream>>>(wbuf, srcP, dstP, rowsum, deg2, E);
  node_b_kernel<<<nblk, TB, 0, stream>>>(deg2, dinv, N);
  transpose_kernel<<<(H * F + TB - 1) / TB, TB, 0, stream>>>(
      (const unsigned short*)d_in[2], (const float*)d_in[2], flags, WT, F, H, H);
  gemmw_kernel<16, 16><<<mt4, TB, 0, stream>>>(
      xh, xf, xb, flags, big ? 0 : 1, WT, hp, N, H);
  agg_relu_kernel<256, 256, 256><<<N, 256, 0, stream>>>(
      hp, wbuf, srcP, off, dinv, sw,
      (const unsigned short*)d_in[3], (const float*)d_in[3], flags, h1, invn, N);

  // ---------- layer 2: h1(256) -> h2(64) ----------
  hipMemsetAsync(rowsum, 0, rd_span, stream);
  simb_kernel<256><<<sgrid, TB, 0, stream>>>(h1, srcP, dstP, invn, wbuf, rowsum, degcnt, E, schunk);
  node_a_kernel<<<nblk, TB, 0, stream>>>(rowsum, degcnt, sw, deg2, N);
  edge_b_kernel<<<eblk, TB, 0, stream>>>(wbuf, srcP, dstP, rowsum, deg2, E);
  node_b_kernel<<<nblk, TB, 0, stream>>>(deg2, dinv, N);
  transpose_kernel<<<(D2 * H + TB - 1) / TB, TB, 0, stream>>>(
      (const unsigned short*)d_in[4], (const float*)d_in[4], flags, WT, H, D2, D2);
  gemmw_kernel<4, 8><<<mt4, TB, 0, stream>>>(h1, xf, xb, flags, 0, WT, hp, N, D2);
  agg_relu_kernel<64, 64, 64><<<N, 64, 0, stream>>>(
      hp, wbuf, srcP, off, dinv, sw,
      (const unsigned short*)d_in[5], (const float*)d_in[5], flags, h2, invn, N);

  // ---------- layer 3: h2(64) -> out(40), fused log_softmax ----------
  hipMemsetAsync(rowsum, 0, rd_span, stream);
  simb_kernel<64><<<sgrid, TB, 0, stream>>>(h2, srcP, dstP, invn, wbuf, rowsum, degcnt, E, schunk);
  node_a_kernel<<<nblk, TB, 0, stream>>>(rowsum, degcnt, sw, deg2, N);
  edge_b_kernel<<<eblk, TB, 0, stream>>>(wbuf, srcP, dstP, rowsum, deg2, E);
  node_b_kernel<<<nblk, TB, 0, stream>>>(deg2, dinv, N);
  transpose_kernel<<<(CP * D2 + TB - 1) / TB, TB, 0, stream>>>(
      (const unsigned short*)d_in[6], (const float*)d_in[6], flags, WT, D2, C, CP);
  gemmw_kernel<3, 2><<<mt4, TB, 0, stream>>>(h2, xf, xb, flags, 0, WT, hp, N, CP);
  agg_lsm_kernel<<<N, 64, 0, stream>>>(
      hp, wbuf, srcP, off, dinv, sw,
      (const unsigned short*)d_in[7], (const float*)d_in[7], flags, d_out, N);
}

// Round 7
// 1698.045 us; speedup vs baseline: 1.8349x; 1.0822x over previous
//
#include <hip/hip_runtime.h>
#include <stdint.h>

typedef __attribute__((ext_vector_type(8))) _Float16 half8v;
typedef __attribute__((ext_vector_type(2))) _Float16 half2v;
typedef __attribute__((ext_vector_type(4))) float floatx4;

union H8 { uint4 u; half8v v; half2v h[4]; _Float16 e[8]; };
union H4 { uint2 u; half2v h[2]; _Float16 e[4]; };

__device__ __forceinline__ float bf2f(unsigned int u) {
  union { unsigned int i; float f; } x;
  x.i = u << 16;
  return x.f;
}

#if __has_builtin(__builtin_amdgcn_fdot2)
__device__ __forceinline__ float dot2(half2v a, half2v b, float c) {
  return __builtin_amdgcn_fdot2(a, b, c, false);
}
#else
__device__ __forceinline__ float dot2(half2v a, half2v b, float c) {
  return c + (float)a.x * (float)b.x + (float)a.y * (float)b.y;
}
#endif

#if __has_builtin(__builtin_amdgcn_readlane)
__device__ __forceinline__ int rl(int v, int l) { return __builtin_amdgcn_readlane(v, l); }
#else
__device__ __forceinline__ int rl(int v, int l) { return __shfl(v, l, 64); }
#endif
__device__ __forceinline__ float rlf(float v, int l) {
  union { float f; int i; } x; x.f = v;
  x.i = rl(x.i, l);
  return x.f;
}

__device__ __forceinline__ float wave_sum(float v) {
  #pragma unroll
  for (int m = 32; m > 0; m >>= 1) v += __shfl_xor(v, m, 64);
  return v;
}

__device__ __forceinline__ float wave_max(float v) {
  #pragma unroll
  for (int m = 32; m > 0; m >>= 1) v = fmaxf(v, __shfl_xor(v, m, 64));
  return v;
}

__device__ __forceinline__ unsigned short f2bf(float f) {
  union { float f; unsigned int u; } x; x.f = f;
  unsigned int r = x.u + 0x7fffu + ((x.u >> 16) & 1u);
  return (unsigned short)(r >> 16);
}

// -------- dtype detection: flags[0]=edges int64, flags[1]=floats fp32 --------

__global__ void detect_kernel(const int* __restrict__ ei, const unsigned int* __restrict__ w1,
                              int* __restrict__ flags, int E) {
  __shared__ int nz, sane;
  if (threadIdx.x == 0) { nz = 0; sane = 0; }
  __syncthreads();
  for (int i = threadIdx.x; i < 2048; i += blockDim.x) {
    if (i < E && ei[2 * i + 1] != 0) atomicAdd(&nz, 1);
    union { unsigned int u; float f; } c; c.u = w1[i];
    float af = fabsf(c.f);
    if (c.f == c.f && af > 1e-10f && af < 1e10f) atomicAdd(&sane, 1);
  }
  __syncthreads();
  if (threadIdx.x == 0) {
    flags[0] = (nz == 0) ? 1 : 0;
    flags[1] = (sane > 1024) ? 1 : 0;
  }
}

// ---------------- CSR build (by dst) with inline edge decode ----------------

__global__ void count_kernel(const int* __restrict__ ei, const int* __restrict__ flags,
                             int* __restrict__ cnt, int E, int N) {
  int e = blockIdx.x * blockDim.x + threadIdx.x;
  if (e >= E) return;
  int d = flags[0] ? ei[2 * (E + e)] : ei[E + e];
  d = ((unsigned)d < (unsigned)N) ? d : 0;
  atomicAdd(&cnt[d], 1);
}

__global__ void scan1_kernel(const int* __restrict__ cnt, int* __restrict__ off,
                             int* __restrict__ bsum, int n) {
  __shared__ int buf[1024];
  int t = threadIdx.x;
  int i = blockIdx.x * 1024 + t;
  int v = (i < n) ? cnt[i] : 0;
  buf[t] = v;
  __syncthreads();
  for (int o = 1; o < 1024; o <<= 1) {
    int a = (t >= o) ? buf[t - o] : 0;
    __syncthreads();
    buf[t] += a;
    __syncthreads();
  }
  if (i < n) off[i + 1] = buf[t];
  if (t == 1023) bsum[blockIdx.x] = buf[1023];
}

__global__ void scan2_kernel(int* __restrict__ bsum, int nb) {
  __shared__ int buf[1024];
  int t = threadIdx.x;
  int v = (t < nb) ? bsum[t] : 0;
  buf[t] = v;
  __syncthreads();
  for (int o = 1; o < 1024; o <<= 1) {
    int a = (t >= o) ? buf[t - o] : 0;
    __syncthreads();
    buf[t] += a;
    __syncthreads();
  }
  if (t < nb) bsum[t] = buf[t];
}

__global__ void scan3_kernel(int* __restrict__ off, const int* __restrict__ bsum, int n) {
  int i = blockIdx.x * blockDim.x + threadIdx.x;
  if (i == 0) off[0] = 0;
  if (i < n) {
    int b = i >> 10;
    if (b > 0) off[i + 1] += bsum[b - 1];
  }
}

__global__ void copy_kernel(const int* __restrict__ off, int* __restrict__ cur, int n) {
  int i = blockIdx.x * blockDim.x + threadIdx.x;
  if (i < n) cur[i] = off[i];
}

__global__ void fill_kernel(const int* __restrict__ ei, const int* __restrict__ flags,
                            int* __restrict__ cur, int* __restrict__ srcP,
                            int* __restrict__ dstP, int E, int N) {
  int e = blockIdx.x * blockDim.x + threadIdx.x;
  if (e >= E) return;
  int s, d;
  if (flags[0]) { s = ei[2 * e]; d = ei[2 * (E + e)]; }
  else          { s = ei[e];     d = ei[E + e]; }
  s = ((unsigned)s < (unsigned)N) ? s : 0;
  d = ((unsigned)d < (unsigned)N) ? d : 0;
  int pos = atomicAdd(&cur[d], 1);
  srcP[pos] = s;
  dstP[pos] = d;
}

// -------- layer-1 convert+norm (fp32 or bf16 input -> f16 rows + invn) --------

__global__ __launch_bounds__(256) void convert_norm_kernel(
    const float* __restrict__ xf, const unsigned short* __restrict__ xb,
    const int* __restrict__ flags, _Float16* __restrict__ xo,
    float* __restrict__ invn, int n) {
  int row = blockIdx.x * 4 + (threadIdx.x >> 6);
  int lane = threadIdx.x & 63;
  if (row >= n) return;
  float ss = 0.f;
  H8 o;
  if (flags[1]) {
    const float4* vp = reinterpret_cast<const float4*>(xf + (size_t)row * 512) + lane * 2;
    float4 a = vp[0], b = vp[1];
    ss = a.x*a.x + a.y*a.y + a.z*a.z + a.w*a.w + b.x*b.x + b.y*b.y + b.z*b.z + b.w*b.w;
    o.v[0] = (_Float16)a.x; o.v[1] = (_Float16)a.y;
    o.v[2] = (_Float16)a.z; o.v[3] = (_Float16)a.w;
    o.v[4] = (_Float16)b.x; o.v[5] = (_Float16)b.y;
    o.v[6] = (_Float16)b.z; o.v[7] = (_Float16)b.w;
  } else {
    uint4 v = *(reinterpret_cast<const uint4*>(xb + (size_t)row * 512) + lane);
    unsigned int a[4] = {v.x, v.y, v.z, v.w};
    #pragma unroll
    for (int i = 0; i < 4; i++) {
      float lo = bf2f(a[i] & 0xffffu), hi = bf2f(a[i] >> 16);
      ss += lo * lo + hi * hi;
      o.v[2 * i] = (_Float16)lo;
      o.v[2 * i + 1] = (_Float16)hi;
    }
  }
  *(reinterpret_cast<uint4*>(xo + (size_t)row * 512) + lane) = o.u;
  ss = wave_sum(ss);
  if (lane == 0) invn[row] = (ss == 0.f) ? 1.0f : rsqrtf(ss);
}

// fallback norm over raw x (no f16 copy available)
__global__ __launch_bounds__(256) void norm8_kernel(const unsigned short* __restrict__ hb,
                                                    const float* __restrict__ hf,
                                                    const int* __restrict__ flags,
                                                    float* __restrict__ invn, int n) {
  int wid = blockIdx.x * 4 + (threadIdx.x >> 6);
  int lane = threadIdx.x & 63;
  if (wid >= n) return;
  float s = 0.f;
  if (flags[1]) {
    const float4* vp = reinterpret_cast<const float4*>(hf + (size_t)wid * 512) + lane * 2;
    float4 a = vp[0], b = vp[1];
    s = a.x*a.x + a.y*a.y + a.z*a.z + a.w*a.w + b.x*b.x + b.y*b.y + b.z*b.z + b.w*b.w;
  } else {
    uint4 v = *(reinterpret_cast<const uint4*>(hb + (size_t)wid * 512) + lane);
    unsigned int a[4] = {v.x, v.y, v.z, v.w};
    #pragma unroll
    for (int i = 0; i < 4; i++) {
      float lo = bf2f(a[i] & 0xffffu), hi = bf2f(a[i] >> 16);
      s += lo * lo + hi * hi;
    }
  }
  s = wave_sum(s);
  if (lane == 0) invn[wid] = (s == 0.f) ? 1.0f : rsqrtf(s);
}

// ------- per-edge cosine sim: 4 edges/wave, XCD-swizzled edge mapping -------

template<int DIM>
__global__ __launch_bounds__(256) void simb_kernel(const _Float16* __restrict__ h,
                                                   const int* __restrict__ srcP,
                                                   const int* __restrict__ dstP,
                                                   const float* __restrict__ invn,
                                                   float* __restrict__ w,
                                                   float* __restrict__ rowsum,
                                                   float* __restrict__ degcnt,
                                                   int E, int chunk) {
  int nb = (blockIdx.x & 7) * chunk + (blockIdx.x >> 3);
  int lane = threadIdx.x & 63;
  int j0 = (nb * 4 + (threadIdx.x >> 6)) * 4;
  if (j0 >= E) return;
  int4 s4 = *reinterpret_cast<const int4*>(srcP + j0);
  int4 t4 = *reinterpret_cast<const int4*>(dstP + j0);
  int ss[4] = {s4.x, s4.y, s4.z, s4.w};
  int tt[4] = {t4.x, t4.y, t4.z, t4.w};
  bool valid[4];
  #pragma unroll
  for (int e = 0; e < 4; e++) {
    valid[e] = (j0 + e) < E;
    if (!valid[e]) { ss[e] = 0; tt[e] = 0; }
  }
  float acc[4];
  if constexpr (DIM == 512) {
    H8 a[4], b[4];
    #pragma unroll
    for (int e = 0; e < 4; e++) {
      a[e].u = *(reinterpret_cast<const uint4*>(h + (size_t)ss[e] * 512) + lane);
      b[e].u = *(reinterpret_cast<const uint4*>(h + (size_t)tt[e] * 512) + lane);
    }
    #pragma unroll
    for (int e = 0; e < 4; e++) {
      acc[e] = 0.f;
      #pragma unroll
      for (int i = 0; i < 4; i++) acc[e] = dot2(a[e].h[i], b[e].h[i], acc[e]);
    }
  } else if constexpr (DIM == 256) {
    H4 a[4], b[4];
    #pragma unroll
    for (int e = 0; e < 4; e++) {
      a[e].u = *(reinterpret_cast<const uint2*>(h + (size_t)ss[e] * 256) + lane);
      b[e].u = *(reinterpret_cast<const uint2*>(h + (size_t)tt[e] * 256) + lane);
    }
    #pragma unroll
    for (int e = 0; e < 4; e++) {
      acc[e] = 0.f;
      #pragma unroll
      for (int i = 0; i < 2; i++) acc[e] = dot2(a[e].h[i], b[e].h[i], acc[e]);
    }
  } else {
    _Float16 a[4], b[4];
    #pragma unroll
    for (int e = 0; e < 4; e++) {
      a[e] = h[(size_t)ss[e] * 64 + lane];
      b[e] = h[(size_t)tt[e] * 64 + lane];
    }
    #pragma unroll
    for (int e = 0; e < 4; e++) acc[e] = (float)a[e] * (float)b[e];
  }
  #pragma unroll
  for (int m = 32; m > 0; m >>= 1) {
    #pragma unroll
    for (int e = 0; e < 4; e++) acc[e] += __shfl_xor(acc[e], m, 64);
  }
  float myacc = acc[0];
  int myS = ss[0], myT = tt[0];
  bool myV = valid[0];
  #pragma unroll
  for (int e = 1; e < 4; e++) {
    if (lane == e) { myacc = acc[e]; myS = ss[e]; myT = tt[e]; myV = valid[e]; }
  }
  if (lane < 4 && myV) {
    float simv = myacc * invn[myS] * invn[myT];
    float wv = (myS != myT && simv > 0.f) ? simv : 0.f;
    w[j0 + lane] = wv;
    if (wv > 0.f) {
      atomicAdd(&rowsum[myS], wv);
      atomicAdd(&degcnt[myS], 1.0f);
    }
  }
}

// fallback layer-1 sim on raw x
__global__ __launch_bounds__(256) void simf_kernel(const unsigned short* __restrict__ hb,
                                                   const float* __restrict__ hf,
                                                   const int* __restrict__ flags,
                                                   const int* __restrict__ srcP,
                                                   const int* __restrict__ dstP,
                                                   const float* __restrict__ invn,
                                                   float* __restrict__ w,
                                                   float* __restrict__ rowsum,
                                                   float* __restrict__ degcnt, int E) {
  int j = blockIdx.x * 4 + (threadIdx.x >> 6);
  int lane = threadIdx.x & 63;
  if (j >= E) return;
  int s = srcP[j], t = dstP[j];
  float acc = 0.f;
  if (flags[1]) {
    const float4* ap = reinterpret_cast<const float4*>(hf + (size_t)s * 512) + lane * 2;
    const float4* bp = reinterpret_cast<const float4*>(hf + (size_t)t * 512) + lane * 2;
    float4 a0 = ap[0], a1 = ap[1], b0 = bp[0], b1 = bp[1];
    acc = a0.x*b0.x + a0.y*b0.y + a0.z*b0.z + a0.w*b0.w
        + a1.x*b1.x + a1.y*b1.y + a1.z*b1.z + a1.w*b1.w;
  } else {
    uint4 a = *(reinterpret_cast<const uint4*>(hb + (size_t)s * 512) + lane);
    uint4 b = *(reinterpret_cast<const uint4*>(hb + (size_t)t * 512) + lane);
    unsigned int av[4] = {a.x, a.y, a.z, a.w};
    unsigned int bv[4] = {b.x, b.y, b.z, b.w};
    #pragma unroll
    for (int i = 0; i < 4; i++)
      acc += bf2f(av[i] & 0xffffu) * bf2f(bv[i] & 0xffffu)
           + bf2f(av[i] >> 16) * bf2f(bv[i] >> 16);
  }
  acc = wave_sum(acc);
  if (lane == 0) {
    float simv = acc * invn[s] * invn[t];
    float wv = (s != t && simv > 0.f) ? simv : 0.f;
    w[j] = wv;
    if (wv > 0.f) {
      atomicAdd(&rowsum[s], wv);
      atomicAdd(&degcnt[s], 1.0f);
    }
  }
}

// ---------------- node / edge scalar stages ----------------

__global__ void node_a_kernel(float* __restrict__ rowsum, const float* __restrict__ degcnt,
                              float* __restrict__ sw, float* __restrict__ deg2, int n) {
  int i = blockIdx.x * blockDim.x + threadIdx.x;
  if (i >= n) return;
  float rs = rowsum[i];
  rowsum[i] = (rs > 0.f) ? 1.0f / rs : 0.0f;
  float lam = 1.0f / (degcnt[i] + 1.0f);
  float s = expf(lam);
  sw[i] = s;
  deg2[i] = s;
}

__global__ void edge_b_kernel(float* __restrict__ w, const int* __restrict__ srcP,
                              const int* __restrict__ dstP, const float* __restrict__ invrs,
                              float* __restrict__ deg2, int E) {
  int j = blockIdx.x * blockDim.x + threadIdx.x;
  if (j >= E) return;
  float wv = w[j];
  if (wv > 0.f) {
    float ewv = expf(wv * invrs[srcP[j]]);
    w[j] = ewv;
    atomicAdd(&deg2[dstP[j]], ewv);
  }
}

__global__ void node_b_kernel(const float* __restrict__ deg2, float* __restrict__ dinv, int n) {
  int i = blockIdx.x * blockDim.x + threadIdx.x;
  if (i < n) dinv[i] = rsqrtf(deg2[i]);
}

// ---------------- GEMM (f16 MFMA) ----------------

__global__ void transpose_kernel(const unsigned short* __restrict__ Wb,
                                 const float* __restrict__ Wf,
                                 const int* __restrict__ flags,
                                 _Float16* __restrict__ WT,
                                 int K, int Nc, int Npad) {
  int idx = blockIdx.x * blockDim.x + threadIdx.x;
  if (idx >= Npad * K) return;
  int nn = idx / K, k = idx - nn * K;
  _Float16 v = (_Float16)0.f;
  if (nn < Nc) {
    if (flags[1]) v = (_Float16)Wf[(size_t)k * Nc + nn];
    else          v = (_Float16)bf2f((unsigned int)Wb[(size_t)k * Nc + nn]);
  }
  WT[idx] = v;
}

template<int NT, int KSTEPS>
__global__ __launch_bounds__(256) void gemmw_kernel(const _Float16* __restrict__ Ah,
                                                    const float* __restrict__ Af,
                                                    const unsigned short* __restrict__ Abf,
                                                    const int* __restrict__ flags,
                                                    int useflags,
                                                    const _Float16* __restrict__ BT,
                                                    _Float16* __restrict__ C,
                                                    int M, int Npad) {
  constexpr int K = KSTEPS * 32;
  int mt = blockIdx.x * 4 + (threadIdx.x >> 6);
  if (mt * 16 >= M) return;
  int lane = threadIdx.x & 63;
  int r = lane & 15, quad = lane >> 4;
  int m0 = mt * 16;
  int mode = useflags ? (flags[1] ? 1 : 2) : 0;
  floatx4 acc[NT];
  #pragma unroll
  for (int nt = 0; nt < NT; nt++) acc[nt] = floatx4{0.f, 0.f, 0.f, 0.f};
  const uint4* ap = reinterpret_cast<const uint4*>(Ah + (size_t)(m0 + r) * K);
  const float* af = Af + (size_t)(m0 + r) * K + quad * 8;
  const unsigned short* ab = Abf + (size_t)(m0 + r) * K + quad * 8;
  for (int kk = 0; kk < KSTEPS; kk++) {
    H8 a;
    if (mode == 1) {
      float4 x0 = *reinterpret_cast<const float4*>(af + kk * 32);
      float4 x1 = *reinterpret_cast<const float4*>(af + kk * 32 + 4);
      a.v[0] = (_Float16)x0.x; a.v[1] = (_Float16)x0.y;
      a.v[2] = (_Float16)x0.z; a.v[3] = (_Float16)x0.w;
      a.v[4] = (_Float16)x1.x; a.v[5] = (_Float16)x1.y;
      a.v[6] = (_Float16)x1.z; a.v[7] = (_Float16)x1.w;
    } else if (mode == 2) {
      uint4 u = *reinterpret_cast<const uint4*>(ab + kk * 32);
      unsigned int uu[4] = {u.x, u.y, u.z, u.w};
      #pragma unroll
      for (int i = 0; i < 4; i++) {
        a.v[2 * i] = (_Float16)bf2f(uu[i] & 0xffffu);
        a.v[2 * i + 1] = (_Float16)bf2f(uu[i] >> 16);
      }
    } else {
      a.u = ap[(kk << 2) + quad];
    }
    #pragma unroll
    for (int nt = 0; nt < NT; nt++) {
      H8 b;
      b.u = *reinterpret_cast<const uint4*>(BT + (size_t)(nt * 16 + r) * K + kk * 32 + quad * 8);
      acc[nt] = __builtin_amdgcn_mfma_f32_16x16x32_f16(a.v, b.v, acc[nt], 0, 0, 0);
    }
  }
  #pragma unroll
  for (int nt = 0; nt < NT; nt++) {
    #pragma unroll
    for (int i = 0; i < 4; i++)
      C[(size_t)(m0 + quad * 4 + i) * Npad + nt * 16 + r] = (_Float16)acc[nt][i];
  }
}

// ------- aggregation: wave-per-node, scalar broadcast, no LDS/barriers -------
// VEC channels per lane; active lanes = NC/VEC. Fuses bias+relu+next-layer norm.

template<int NC, int STRIDE, int VEC>
__global__ __launch_bounds__(256) void aggw_relu_kernel(
    const _Float16* __restrict__ hp, const float* __restrict__ ew,
    const int* __restrict__ srcP, const int* __restrict__ off,
    const float* __restrict__ dinv, const float* __restrict__ sw,
    const unsigned short* __restrict__ biasb, const float* __restrict__ biasf,
    const int* __restrict__ flags, _Float16* __restrict__ out,
    float* __restrict__ invn, int n) {
  constexpr int ACT = NC / VEC;
  int i = blockIdx.x * 4 + (threadIdx.x >> 6);
  if (i >= n) return;
  int lane = threadIdx.x & 63;
  float di = dinv[i];
  float sii = sw[i] * di * di;
  float acc[VEC];
  #pragma unroll
  for (int v = 0; v < VEC; v++) acc[v] = 0.f;
  if (lane < ACT) {
    if constexpr (VEC == 4) {
      H4 hv;
      hv.u = *reinterpret_cast<const uint2*>(hp + (size_t)i * STRIDE + lane * 4);
      #pragma unroll
      for (int v = 0; v < 4; v++) acc[v] = sii * (float)hv.e[v];
    } else {
      acc[0] = sii * (float)hp[(size_t)i * STRIDE + lane];
    }
  }
  int e0 = off[i], e1 = off[i + 1];
  for (int base = e0; base < e1; base += 64) {
    int j = base + lane;
    int sreg = 0;
    float creg = 0.f;
    if (j < e1) {
      sreg = srcP[j];
      float e = ew[j];
      if (e != 0.f) creg = e * dinv[sreg] * di;
    }
    int m = min(64, e1 - base);
    for (int k = 0; k < m; k++) {
      float cfk = rlf(creg, k);
      if (cfk != 0.f) {
        int sk = rl(sreg, k);
        if (lane < ACT) {
          if constexpr (VEC == 4) {
            H4 hv;
            hv.u = *reinterpret_cast<const uint2*>(hp + (size_t)sk * STRIDE + lane * 4);
            #pragma unroll
            for (int v = 0; v < 4; v++) acc[v] += cfk * (float)hv.e[v];
          } else {
            acc[0] += cfk * (float)hp[(size_t)sk * STRIDE + lane];
          }
        }
      }
    }
  }
  float nrm = 0.f;
  if (lane < ACT) {
    if constexpr (VEC == 4) {
      H4 ov;
      #pragma unroll
      for (int v = 0; v < 4; v++) {
        int c = lane * 4 + v;
        float bb = flags[1] ? biasf[c] : bf2f((unsigned int)biasb[c]);
        float x = acc[v] + bb;
        x = x > 0.f ? x : 0.f;
        ov.e[v] = (_Float16)x;
        nrm += x * x;
      }
      *reinterpret_cast<uint2*>(out + (size_t)i * NC + lane * 4) = ov.u;
    } else {
      float bb = flags[1] ? biasf[lane] : bf2f((unsigned int)biasb[lane]);
      float x = acc[0] + bb;
      x = x > 0.f ? x : 0.f;
      out[(size_t)i * NC + lane] = (_Float16)x;
      nrm = x * x;
    }
  }
  nrm = wave_sum(nrm);
  if (lane == 0) invn[i] = (nrm == 0.f) ? 1.0f : rsqrtf(nrm);
}

__global__ __launch_bounds__(256) void aggw_lsm_kernel(
    const _Float16* __restrict__ hp, const float* __restrict__ ew,
    const int* __restrict__ srcP, const int* __restrict__ off,
    const float* __restrict__ dinv, const float* __restrict__ sw,
    const unsigned short* __restrict__ biasb, const float* __restrict__ biasf,
    const int* __restrict__ flags, void* __restrict__ outv, int n) {
  constexpr int NC = 40, STRIDE = 48;
  int i = blockIdx.x * 4 + (threadIdx.x >> 6);
  if (i >= n) return;
  int lane = threadIdx.x & 63;
  float di = dinv[i];
  float acc = 0.f;
  if (lane < NC) acc = sw[i] * di * di * (float)hp[(size_t)i * STRIDE + lane];
  int e0 = off[i], e1 = off[i + 1];
  for (int base = e0; base < e1; base += 64) {
    int j = base + lane;
    int sreg = 0;
    float creg = 0.f;
    if (j < e1) {
      sreg = srcP[j];
      float e = ew[j];
      if (e != 0.f) creg = e * dinv[sreg] * di;
    }
    int m = min(64, e1 - base);
    for (int k = 0; k < m; k++) {
      float cfk = rlf(creg, k);
      if (cfk != 0.f) {
        int sk = rl(sreg, k);
        if (lane < NC) acc += cfk * (float)hp[(size_t)sk * STRIDE + lane];
      }
    }
  }
  int f32 = flags[1];
  float bb = 0.f;
  if (lane < NC) bb = f32 ? biasf[lane] : bf2f((unsigned int)biasb[lane]);
  float v = (lane < NC) ? acc + bb : -3.0e38f;
  float vm = wave_max(v);
  float ex = (lane < NC) ? expf(v - vm) : 0.f;
  float se = wave_sum(ex);
  float ls = logf(se);
  if (lane < NC) {
    float r = v - vm - ls;
    if (f32) ((float*)outv)[(size_t)i * NC + lane] = r;
    else ((unsigned short*)outv)[(size_t)i * NC + lane] = f2bf(r);
  }
}

// ---------------- host ----------------

extern "C" void kernel_launch(void* const* d_in, const int* in_sizes, int n_in,
                              void* d_out, int out_size, void* d_ws, size_t ws_size,
                              hipStream_t stream) {
  const unsigned short* xb = (const unsigned short*)d_in[0];
  const float* xf          = (const float*)d_in[0];
  const int* ei            = (const int*)d_in[1];

  const int H  = in_sizes[3];            // 256
  const int F  = in_sizes[2] / H;        // 512
  const int D2 = in_sizes[5];            // 64
  const int C  = in_sizes[7];            // 40
  const int N  = in_sizes[0] / F;        // 50000
  const int E  = in_sizes[1] / 2;        // 1600000
  const int CP = 48;

  char* p = (char*)d_ws;
  auto alloc = [&](size_t bytes) -> char* {
    char* r = p;
    p += (bytes + 255) & ~(size_t)255;
    return r;
  };
  int*   srcP   = (int*)alloc((size_t)E * 4 + 16);
  int*   dstP   = (int*)alloc((size_t)E * 4 + 16);
  float* wbuf   = (float*)alloc((size_t)E * 4);
  int*   off    = (int*)alloc((size_t)(N + 1) * 4);
  int*   cur    = (int*)alloc((size_t)N * 4);
  float* invn   = (float*)alloc((size_t)N * 4);
  float* rowsum = (float*)alloc((size_t)N * 4);
  float* degcnt = (float*)alloc((size_t)N * 4);
  float* sw     = (float*)alloc((size_t)N * 4);
  float* deg2   = (float*)alloc((size_t)N * 4);
  float* dinv   = (float*)alloc((size_t)N * 4);
  int*   flags  = (int*)alloc(256);
  int*   bsum   = (int*)alloc(4096 * 4);
  _Float16* WT  = (_Float16*)alloc((size_t)256 * 512 * 2);
  _Float16* hp  = (_Float16*)alloc((size_t)N * 256 * 2);
  size_t used = (size_t)(p - (char*)d_ws);
  size_t xh_bytes = (size_t)N * 512 * 2;
  bool big = (used + xh_bytes + 256) <= ws_size;
  _Float16* xh = big ? (_Float16*)alloc(xh_bytes) : hp;

  _Float16* h1 = (_Float16*)d_in[0];
  _Float16* h2 = hp + (size_t)N * 64;
  size_t rd_span = (size_t)((char*)degcnt - (char*)rowsum) + (size_t)N * 4;

  const int TB = 256;
  int nblk = (N + TB - 1) / TB;
  int eblk = (E + TB - 1) / TB;
  int nwav = (N + 3) / 4;
  int ewav = (E + 3) / 4;
  int mt4  = (N / 16 + 3) / 4;
  int nb1024 = (N + 1023) / 1024;
  int sblocks = (E + 15) / 16;
  int schunk = (sblocks + 7) / 8;
  int sgrid = schunk * 8;

  detect_kernel<<<1, 256, 0, stream>>>(ei, (const unsigned int*)d_in[2], flags, E);

  hipMemsetAsync(cur, 0, (size_t)N * 4, stream);
  count_kernel<<<eblk, TB, 0, stream>>>(ei, flags, cur, E, N);
  scan1_kernel<<<nb1024, 1024, 0, stream>>>(cur, off, bsum, N);
  scan2_kernel<<<1, 1024, 0, stream>>>(bsum, nb1024);
  scan3_kernel<<<nblk, TB, 0, stream>>>(off, bsum, N);
  copy_kernel<<<nblk, TB, 0, stream>>>(off, cur, N);
  fill_kernel<<<eblk, TB, 0, stream>>>(ei, flags, cur, srcP, dstP, E, N);

  // ---------- layer 1: x(512) -> h1(256) ----------
  hipMemsetAsync(rowsum, 0, rd_span, stream);
  if (big) {
    convert_norm_kernel<<<nwav, TB, 0, stream>>>(xf, xb, flags, xh, invn, N);
    simb_kernel<512><<<sgrid, TB, 0, stream>>>(xh, srcP, dstP, invn, wbuf, rowsum, degcnt, E, schunk);
  } else {
    norm8_kernel<<<nwav, TB, 0, stream>>>(xb, xf, flags, invn, N);
    simf_kernel<<<ewav, TB, 0, stream>>>(xb, xf, flags, srcP, dstP, invn, wbuf, rowsum, degcnt, E);
  }
  node_a_kernel<<<nblk, TB, 0, stream>>>(rowsum, degcnt, sw, deg2, N);
  edge_b_kernel<<<eblk, TB, 0, stream>>>(wbuf, srcP, dstP, rowsum, deg2, E);
  node_b_kernel<<<nblk, TB, 0, stream>>>(deg2, dinv, N);
  transpose_kernel<<<(H * F + TB - 1) / TB, TB, 0, stream>>>(
      (const unsigned short*)d_in[2], (const float*)d_in[2], flags, WT, F, H, H);
  gemmw_kernel<16, 16><<<mt4, TB, 0, stream>>>(
      xh, xf, xb, flags, big ? 0 : 1, WT, hp, N, H);
  aggw_relu_kernel<256, 256, 4><<<nwav, TB, 0, stream>>>(
      hp, wbuf, srcP, off, dinv, sw,
      (const unsigned short*)d_in[3], (const float*)d_in[3], flags, h1, invn, N);

  // ---------- layer 2: h1(256) -> h2(64) ----------
  hipMemsetAsync(rowsum, 0, rd_span, stream);
  simb_kernel<256><<<sgrid, TB, 0, stream>>>(h1, srcP, dstP, invn, wbuf, rowsum, degcnt, E, schunk);
  node_a_kernel<<<nblk, TB, 0, stream>>>(rowsum, degcnt, sw, deg2, N);
  edge_b_kernel<<<eblk, TB, 0, stream>>>(wbuf, srcP, dstP, rowsum, deg2, E);
  node_b_kernel<<<nblk, TB, 0, stream>>>(deg2, dinv, N);
  transpose_kernel<<<(D2 * H + TB - 1) / TB, TB, 0, stream>>>(
      (const unsigned short*)d_in[4], (const float*)d_in[4], flags, WT, H, D2, D2);
  gemmw_kernel<4, 8><<<mt4, TB, 0, stream>>>(h1, xf, xb, flags, 0, WT, hp, N, D2);
  aggw_relu_kernel<64, 64, 1><<<nwav, TB, 0, stream>>>(
      hp, wbuf, srcP, off, dinv, sw,
      (const unsigned short*)d_in[5], (const float*)d_in[5], flags, h2, invn, N);

  // ---------- layer 3: h2(64) -> out(40), fused log_softmax ----------
  hipMemsetAsync(rowsum, 0, rd_span, stream);
  simb_kernel<64><<<sgrid, TB, 0, stream>>>(h2, srcP, dstP, invn, wbuf, rowsum, degcnt, E, schunk);
  node_a_kernel<<<nblk, TB, 0, stream>>>(rowsum, degcnt, sw, deg2, N);
  edge_b_kernel<<<eblk, TB, 0, stream>>>(wbuf, srcP, dstP, rowsum, deg2, E);
  node_b_kernel<<<nblk, TB, 0, stream>>>(deg2, dinv, N);
  transpose_kernel<<<(CP * D2 + TB - 1) / TB, TB, 0, stream>>>(
      (const unsigned short*)d_in[6], (const float*)d_in[6], flags, WT, D2, C, CP);
  gemmw_kernel<3, 2><<<mt4, TB, 0, stream>>>(h2, xf, xb, flags, 0, WT, hp, N, CP);
  aggw_lsm_kernel<<<nwav, TB, 0, stream>>>(
      hp, wbuf, srcP, off, dinv, sw,
      (const unsigned short*)d_in[7], (const float*)d_in[7], flags, d_out, N);
}

// Round 8
// 1612.047 us; speedup vs baseline: 1.9328x; 1.0533x over previous
//
#include <hip/hip_runtime.h>
#include <stdint.h>

typedef __attribute__((ext_vector_type(8))) _Float16 half8v;
typedef __attribute__((ext_vector_type(2))) _Float16 half2v;
typedef __attribute__((ext_vector_type(4))) float floatx4;

union H8 { uint4 u; half8v v; half2v h[4]; _Float16 e[8]; };
union H4 { uint2 u; half2v h[2]; _Float16 e[4]; };

__device__ __forceinline__ float bf2f(unsigned int u) {
  union { unsigned int i; float f; } x;
  x.i = u << 16;
  return x.f;
}

#if __has_builtin(__builtin_amdgcn_fdot2)
__device__ __forceinline__ float dot2(half2v a, half2v b, float c) {
  return __builtin_amdgcn_fdot2(a, b, c, false);
}
#else
__device__ __forceinline__ float dot2(half2v a, half2v b, float c) {
  return c + (float)a.x * (float)b.x + (float)a.y * (float)b.y;
}
#endif

#if __has_builtin(__builtin_amdgcn_sdot4)
__device__ __forceinline__ int dot4i(int a, int b, int c) {
  return __builtin_amdgcn_sdot4(a, b, c, false);
}
#else
__device__ __forceinline__ int dot4i(int a, int b, int c) {
  #pragma unroll
  for (int i = 0; i < 4; i++)
    c += (int)(signed char)(a >> (8 * i)) * (int)(signed char)(b >> (8 * i));
  return c;
}
#endif

#if __has_builtin(__builtin_amdgcn_readlane)
__device__ __forceinline__ int rl(int v, int l) { return __builtin_amdgcn_readlane(v, l); }
#else
__device__ __forceinline__ int rl(int v, int l) { return __shfl(v, l, 64); }
#endif
__device__ __forceinline__ float rlf(float v, int l) {
  union { float f; int i; } x; x.f = v;
  x.i = rl(x.i, l);
  return x.f;
}

__device__ __forceinline__ float wave_sum(float v) {
  #pragma unroll
  for (int m = 32; m > 0; m >>= 1) v += __shfl_xor(v, m, 64);
  return v;
}

__device__ __forceinline__ float wave_max(float v) {
  #pragma unroll
  for (int m = 32; m > 0; m >>= 1) v = fmaxf(v, __shfl_xor(v, m, 64));
  return v;
}

__device__ __forceinline__ unsigned short f2bf(float f) {
  union { float f; unsigned int u; } x; x.f = f;
  unsigned int r = x.u + 0x7fffu + ((x.u >> 16) & 1u);
  return (unsigned short)(r >> 16);
}

// -------- dtype detection: flags[0]=edges int64, flags[1]=floats fp32 --------

__global__ void detect_kernel(const int* __restrict__ ei, const unsigned int* __restrict__ w1,
                              int* __restrict__ flags, int E) {
  __shared__ int nz, sane;
  if (threadIdx.x == 0) { nz = 0; sane = 0; }
  __syncthreads();
  for (int i = threadIdx.x; i < 2048; i += blockDim.x) {
    if (i < E && ei[2 * i + 1] != 0) atomicAdd(&nz, 1);
    union { unsigned int u; float f; } c; c.u = w1[i];
    float af = fabsf(c.f);
    if (c.f == c.f && af > 1e-10f && af < 1e10f) atomicAdd(&sane, 1);
  }
  __syncthreads();
  if (threadIdx.x == 0) {
    flags[0] = (nz == 0) ? 1 : 0;
    flags[1] = (sane > 1024) ? 1 : 0;
  }
}

// ---------------- CSR build (by dst) with inline edge decode ----------------

__global__ void count_kernel(const int* __restrict__ ei, const int* __restrict__ flags,
                             int* __restrict__ cnt, int E, int N) {
  int e = blockIdx.x * blockDim.x + threadIdx.x;
  if (e >= E) return;
  int d = flags[0] ? ei[2 * (E + e)] : ei[E + e];
  d = ((unsigned)d < (unsigned)N) ? d : 0;
  atomicAdd(&cnt[d], 1);
}

__global__ void scan1_kernel(const int* __restrict__ cnt, int* __restrict__ off,
                             int* __restrict__ bsum, int n) {
  __shared__ int buf[1024];
  int t = threadIdx.x;
  int i = blockIdx.x * 1024 + t;
  int v = (i < n) ? cnt[i] : 0;
  buf[t] = v;
  __syncthreads();
  for (int o = 1; o < 1024; o <<= 1) {
    int a = (t >= o) ? buf[t - o] : 0;
    __syncthreads();
    buf[t] += a;
    __syncthreads();
  }
  if (i < n) off[i + 1] = buf[t];
  if (t == 1023) bsum[blockIdx.x] = buf[1023];
}

__global__ void scan2_kernel(int* __restrict__ bsum, int nb) {
  __shared__ int buf[1024];
  int t = threadIdx.x;
  int v = (t < nb) ? bsum[t] : 0;
  buf[t] = v;
  __syncthreads();
  for (int o = 1; o < 1024; o <<= 1) {
    int a = (t >= o) ? buf[t - o] : 0;
    __syncthreads();
    buf[t] += a;
    __syncthreads();
  }
  if (t < nb) bsum[t] = buf[t];
}

__global__ void scan3_kernel(int* __restrict__ off, const int* __restrict__ bsum, int n) {
  int i = blockIdx.x * blockDim.x + threadIdx.x;
  if (i == 0) off[0] = 0;
  if (i < n) {
    int b = i >> 10;
    if (b > 0) off[i + 1] += bsum[b - 1];
  }
}

__global__ void copy_kernel(const int* __restrict__ off, int* __restrict__ cur, int n) {
  int i = blockIdx.x * blockDim.x + threadIdx.x;
  if (i < n) cur[i] = off[i];
}

__global__ void fill_kernel(const int* __restrict__ ei, const int* __restrict__ flags,
                            int* __restrict__ cur, int* __restrict__ srcP,
                            int* __restrict__ dstP, int E, int N) {
  int e = blockIdx.x * blockDim.x + threadIdx.x;
  if (e >= E) return;
  int s, d;
  if (flags[0]) { s = ei[2 * e]; d = ei[2 * (E + e)]; }
  else          { s = ei[e];     d = ei[E + e]; }
  s = ((unsigned)s < (unsigned)N) ? s : 0;
  d = ((unsigned)d < (unsigned)N) ? d : 0;
  int pos = atomicAdd(&cur[d], 1);
  srcP[pos] = s;
  dstP[pos] = d;
}

// -- layer-1 convert+norm: fp32/bf16 x -> f16 rows + int8 rows + invq --------

__global__ __launch_bounds__(256) void convert_norm_kernel(
    const float* __restrict__ xf, const unsigned short* __restrict__ xb,
    const int* __restrict__ flags, _Float16* __restrict__ xo,
    unsigned char* __restrict__ xq, float* __restrict__ invq, int n) {
  int row = blockIdx.x * 4 + (threadIdx.x >> 6);
  int lane = threadIdx.x & 63;
  if (row >= n) return;
  float ss = 0.f, mx = 0.f;
  float vals[8];
  H8 o;
  if (flags[1]) {
    const float4* vp = reinterpret_cast<const float4*>(xf + (size_t)row * 512) + lane * 2;
    float4 a = vp[0], b = vp[1];
    vals[0] = a.x; vals[1] = a.y; vals[2] = a.z; vals[3] = a.w;
    vals[4] = b.x; vals[5] = b.y; vals[6] = b.z; vals[7] = b.w;
  } else {
    uint4 v = *(reinterpret_cast<const uint4*>(xb + (size_t)row * 512) + lane);
    unsigned int a[4] = {v.x, v.y, v.z, v.w};
    #pragma unroll
    for (int i = 0; i < 4; i++) {
      vals[2 * i] = bf2f(a[i] & 0xffffu);
      vals[2 * i + 1] = bf2f(a[i] >> 16);
    }
  }
  #pragma unroll
  for (int i = 0; i < 8; i++) {
    ss += vals[i] * vals[i];
    mx = fmaxf(mx, fabsf(vals[i]));
    o.v[i] = (_Float16)vals[i];
  }
  *(reinterpret_cast<uint4*>(xo + (size_t)row * 512) + lane) = o.u;
  ss = wave_sum(ss);
  mx = wave_max(mx);
  float scale = (mx > 0.f) ? 127.0f / mx : 0.f;
  uint2 qo;
  unsigned int q0 = 0, q1 = 0;
  #pragma unroll
  for (int i = 0; i < 4; i++) {
    int q = (int)rintf(vals[i] * scale);
    q0 |= ((unsigned int)(q & 0xff)) << (8 * i);
  }
  #pragma unroll
  for (int i = 0; i < 4; i++) {
    int q = (int)rintf(vals[4 + i] * scale);
    q1 |= ((unsigned int)(q & 0xff)) << (8 * i);
  }
  qo.x = q0; qo.y = q1;
  *(reinterpret_cast<uint2*>(xq + (size_t)row * 512) + lane) = qo;
  if (lane == 0)
    invq[row] = (mx > 0.f && ss > 0.f) ? (mx / 127.0f) * rsqrtf(ss) : 0.f;
}

// fallback norm over raw x (no f16/int8 copy available)
__global__ __launch_bounds__(256) void norm8_kernel(const unsigned short* __restrict__ hb,
                                                    const float* __restrict__ hf,
                                                    const int* __restrict__ flags,
                                                    float* __restrict__ invn, int n) {
  int wid = blockIdx.x * 4 + (threadIdx.x >> 6);
  int lane = threadIdx.x & 63;
  if (wid >= n) return;
  float s = 0.f;
  if (flags[1]) {
    const float4* vp = reinterpret_cast<const float4*>(hf + (size_t)wid * 512) + lane * 2;
    float4 a = vp[0], b = vp[1];
    s = a.x*a.x + a.y*a.y + a.z*a.z + a.w*a.w + b.x*b.x + b.y*b.y + b.z*b.z + b.w*b.w;
  } else {
    uint4 v = *(reinterpret_cast<const uint4*>(hb + (size_t)wid * 512) + lane);
    unsigned int a[4] = {v.x, v.y, v.z, v.w};
    #pragma unroll
    for (int i = 0; i < 4; i++) {
      float lo = bf2f(a[i] & 0xffffu), hi = bf2f(a[i] >> 16);
      s += lo * lo + hi * hi;
    }
  }
  s = wave_sum(s);
  if (lane == 0) invn[wid] = (s == 0.f) ? 1.0f : rsqrtf(s);
}

// ------ int8 cosine sim: 8 edges/wave, sdot4, XCD-swizzled edge blocks ------
// grid: blocks of 32 edges; block b -> nb = (b&7)*chunk + (b>>3)

template<int DIM>
__global__ __launch_bounds__(256) void simq_kernel(const unsigned char* __restrict__ q,
                                                   const int* __restrict__ srcP,
                                                   const int* __restrict__ dstP,
                                                   const float* __restrict__ invq,
                                                   float* __restrict__ w,
                                                   float* __restrict__ rowsum,
                                                   float* __restrict__ degcnt,
                                                   int E, int chunk) {
  int nb = (blockIdx.x & 7) * chunk + (blockIdx.x >> 3);
  int lane = threadIdx.x & 63;
  int j0 = (nb * 4 + (threadIdx.x >> 6)) * 8;
  if (j0 >= E) return;
  int4 sa = *reinterpret_cast<const int4*>(srcP + j0);
  int4 sb = *reinterpret_cast<const int4*>(srcP + j0 + 4);
  int4 ta = *reinterpret_cast<const int4*>(dstP + j0);
  int4 tb = *reinterpret_cast<const int4*>(dstP + j0 + 4);
  int ss[8] = {sa.x, sa.y, sa.z, sa.w, sb.x, sb.y, sb.z, sb.w};
  int tt[8] = {ta.x, ta.y, ta.z, ta.w, tb.x, tb.y, tb.z, tb.w};
  bool valid[8];
  #pragma unroll
  for (int e = 0; e < 8; e++) {
    valid[e] = (j0 + e) < E;
    if (!valid[e]) { ss[e] = 0; tt[e] = 0; }
  }
  int acc[8];
  if constexpr (DIM == 512) {
    uint2 a[8], b[8];
    #pragma unroll
    for (int e = 0; e < 8; e++) {
      a[e] = *(reinterpret_cast<const uint2*>(q + (size_t)ss[e] * 512) + lane);
      b[e] = *(reinterpret_cast<const uint2*>(q + (size_t)tt[e] * 512) + lane);
    }
    #pragma unroll
    for (int e = 0; e < 8; e++)
      acc[e] = dot4i((int)a[e].y, (int)b[e].y, dot4i((int)a[e].x, (int)b[e].x, 0));
  } else {
    unsigned int a[8], b[8];
    #pragma unroll
    for (int e = 0; e < 8; e++) {
      a[e] = *(reinterpret_cast<const unsigned int*>(q + (size_t)ss[e] * 256) + lane);
      b[e] = *(reinterpret_cast<const unsigned int*>(q + (size_t)tt[e] * 256) + lane);
    }
    #pragma unroll
    for (int e = 0; e < 8; e++)
      acc[e] = dot4i((int)a[e], (int)b[e], 0);
  }
  #pragma unroll
  for (int m = 32; m > 0; m >>= 1) {
    #pragma unroll
    for (int e = 0; e < 8; e++) acc[e] += __shfl_xor(acc[e], m, 64);
  }
  int myacc = acc[0];
  int myS = ss[0], myT = tt[0];
  bool myV = valid[0];
  #pragma unroll
  for (int e = 1; e < 8; e++) {
    if (lane == e) { myacc = acc[e]; myS = ss[e]; myT = tt[e]; myV = valid[e]; }
  }
  if (lane < 8 && myV) {
    float simv = (float)myacc * invq[myS] * invq[myT];
    float wv = (myS != myT && simv > 0.f) ? simv : 0.f;
    w[j0 + lane] = wv;
    if (wv > 0.f) {
      atomicAdd(&rowsum[myS], wv);
      atomicAdd(&degcnt[myS], 1.0f);
    }
  }
}

// f16 sim for 64-dim layer (4 edges/wave)
__global__ __launch_bounds__(256) void simb64_kernel(const _Float16* __restrict__ h,
                                                     const int* __restrict__ srcP,
                                                     const int* __restrict__ dstP,
                                                     const float* __restrict__ invn,
                                                     float* __restrict__ w,
                                                     float* __restrict__ rowsum,
                                                     float* __restrict__ degcnt,
                                                     int E, int chunk) {
  int nb = (blockIdx.x & 7) * chunk + (blockIdx.x >> 3);
  int lane = threadIdx.x & 63;
  int j0 = (nb * 4 + (threadIdx.x >> 6)) * 4;
  if (j0 >= E) return;
  int4 s4 = *reinterpret_cast<const int4*>(srcP + j0);
  int4 t4 = *reinterpret_cast<const int4*>(dstP + j0);
  int ss[4] = {s4.x, s4.y, s4.z, s4.w};
  int tt[4] = {t4.x, t4.y, t4.z, t4.w};
  bool valid[4];
  #pragma unroll
  for (int e = 0; e < 4; e++) {
    valid[e] = (j0 + e) < E;
    if (!valid[e]) { ss[e] = 0; tt[e] = 0; }
  }
  float acc[4];
  _Float16 a[4], b[4];
  #pragma unroll
  for (int e = 0; e < 4; e++) {
    a[e] = h[(size_t)ss[e] * 64 + lane];
    b[e] = h[(size_t)tt[e] * 64 + lane];
  }
  #pragma unroll
  for (int e = 0; e < 4; e++) acc[e] = (float)a[e] * (float)b[e];
  #pragma unroll
  for (int m = 32; m > 0; m >>= 1) {
    #pragma unroll
    for (int e = 0; e < 4; e++) acc[e] += __shfl_xor(acc[e], m, 64);
  }
  float myacc = acc[0];
  int myS = ss[0], myT = tt[0];
  bool myV = valid[0];
  #pragma unroll
  for (int e = 1; e < 4; e++) {
    if (lane == e) { myacc = acc[e]; myS = ss[e]; myT = tt[e]; myV = valid[e]; }
  }
  if (lane < 4 && myV) {
    float simv = myacc * invn[myS] * invn[myT];
    float wv = (myS != myT && simv > 0.f) ? simv : 0.f;
    w[j0 + lane] = wv;
    if (wv > 0.f) {
      atomicAdd(&rowsum[myS], wv);
      atomicAdd(&degcnt[myS], 1.0f);
    }
  }
}

// fallback layer-1 sim on raw x
__global__ __launch_bounds__(256) void simf_kernel(const unsigned short* __restrict__ hb,
                                                   const float* __restrict__ hf,
                                                   const int* __restrict__ flags,
                                                   const int* __restrict__ srcP,
                                                   const int* __restrict__ dstP,
                                                   const float* __restrict__ invn,
                                                   float* __restrict__ w,
                                                   float* __restrict__ rowsum,
                                                   float* __restrict__ degcnt, int E) {
  int j = blockIdx.x * 4 + (threadIdx.x >> 6);
  int lane = threadIdx.x & 63;
  if (j >= E) return;
  int s = srcP[j], t = dstP[j];
  float acc = 0.f;
  if (flags[1]) {
    const float4* ap = reinterpret_cast<const float4*>(hf + (size_t)s * 512) + lane * 2;
    const float4* bp = reinterpret_cast<const float4*>(hf + (size_t)t * 512) + lane * 2;
    float4 a0 = ap[0], a1 = ap[1], b0 = bp[0], b1 = bp[1];
    acc = a0.x*b0.x + a0.y*b0.y + a0.z*b0.z + a0.w*b0.w
        + a1.x*b1.x + a1.y*b1.y + a1.z*b1.z + a1.w*b1.w;
  } else {
    uint4 a = *(reinterpret_cast<const uint4*>(hb + (size_t)s * 512) + lane);
    uint4 b = *(reinterpret_cast<const uint4*>(hb + (size_t)t * 512) + lane);
    unsigned int av[4] = {a.x, a.y, a.z, a.w};
    unsigned int bv[4] = {b.x, b.y, b.z, b.w};
    #pragma unroll
    for (int i = 0; i < 4; i++)
      acc += bf2f(av[i] & 0xffffu) * bf2f(bv[i] & 0xffffu)
           + bf2f(av[i] >> 16) * bf2f(bv[i] >> 16);
  }
  acc = wave_sum(acc);
  if (lane == 0) {
    float simv = acc * invn[s] * invn[t];
    float wv = (s != t && simv > 0.f) ? simv : 0.f;
    w[j] = wv;
    if (wv > 0.f) {
      atomicAdd(&rowsum[s], wv);
      atomicAdd(&degcnt[s], 1.0f);
    }
  }
}

// ---------------- node / edge scalar stages ----------------

__global__ void node_a_kernel(float* __restrict__ rowsum, const float* __restrict__ degcnt,
                              float* __restrict__ sw, float* __restrict__ deg2, int n) {
  int i = blockIdx.x * blockDim.x + threadIdx.x;
  if (i >= n) return;
  float rs = rowsum[i];
  rowsum[i] = (rs > 0.f) ? 1.0f / rs : 0.0f;
  float lam = 1.0f / (degcnt[i] + 1.0f);
  float s = expf(lam);
  sw[i] = s;
  deg2[i] = s;
}

__global__ void edge_b_kernel(float* __restrict__ w, const int* __restrict__ srcP,
                              const int* __restrict__ dstP, const float* __restrict__ invrs,
                              float* __restrict__ deg2, int E) {
  int j = blockIdx.x * blockDim.x + threadIdx.x;
  if (j >= E) return;
  float wv = w[j];
  if (wv > 0.f) {
    float ewv = expf(wv * invrs[srcP[j]]);
    w[j] = ewv;
    atomicAdd(&deg2[dstP[j]], ewv);
  }
}

__global__ void node_b_kernel(const float* __restrict__ deg2, float* __restrict__ dinv, int n) {
  int i = blockIdx.x * blockDim.x + threadIdx.x;
  if (i < n) dinv[i] = rsqrtf(deg2[i]);
}

// ---------------- GEMM (f16 MFMA) ----------------

__global__ void transpose_kernel(const unsigned short* __restrict__ Wb,
                                 const float* __restrict__ Wf,
                                 const int* __restrict__ flags,
                                 _Float16* __restrict__ WT,
                                 int K, int Nc, int Npad) {
  int idx = blockIdx.x * blockDim.x + threadIdx.x;
  if (idx >= Npad * K) return;
  int nn = idx / K, k = idx - nn * K;
  _Float16 v = (_Float16)0.f;
  if (nn < Nc) {
    if (flags[1]) v = (_Float16)Wf[(size_t)k * Nc + nn];
    else          v = (_Float16)bf2f((unsigned int)Wb[(size_t)k * Nc + nn]);
  }
  WT[idx] = v;
}

template<int NT, int KSTEPS>
__global__ __launch_bounds__(256) void gemmw_kernel(const _Float16* __restrict__ Ah,
                                                    const float* __restrict__ Af,
                                                    const unsigned short* __restrict__ Abf,
                                                    const int* __restrict__ flags,
                                                    int useflags,
                                                    const _Float16* __restrict__ BT,
                                                    _Float16* __restrict__ C,
                                                    int M, int Npad) {
  constexpr int K = KSTEPS * 32;
  int mt = blockIdx.x * 4 + (threadIdx.x >> 6);
  if (mt * 16 >= M) return;
  int lane = threadIdx.x & 63;
  int r = lane & 15, quad = lane >> 4;
  int m0 = mt * 16;
  int mode = useflags ? (flags[1] ? 1 : 2) : 0;
  floatx4 acc[NT];
  #pragma unroll
  for (int nt = 0; nt < NT; nt++) acc[nt] = floatx4{0.f, 0.f, 0.f, 0.f};
  const uint4* ap = reinterpret_cast<const uint4*>(Ah + (size_t)(m0 + r) * K);
  const float* af = Af + (size_t)(m0 + r) * K + quad * 8;
  const unsigned short* ab = Abf + (size_t)(m0 + r) * K + quad * 8;
  for (int kk = 0; kk < KSTEPS; kk++) {
    H8 a;
    if (mode == 1) {
      float4 x0 = *reinterpret_cast<const float4*>(af + kk * 32);
      float4 x1 = *reinterpret_cast<const float4*>(af + kk * 32 + 4);
      a.v[0] = (_Float16)x0.x; a.v[1] = (_Float16)x0.y;
      a.v[2] = (_Float16)x0.z; a.v[3] = (_Float16)x0.w;
      a.v[4] = (_Float16)x1.x; a.v[5] = (_Float16)x1.y;
      a.v[6] = (_Float16)x1.z; a.v[7] = (_Float16)x1.w;
    } else if (mode == 2) {
      uint4 u = *reinterpret_cast<const uint4*>(ab + kk * 32);
      unsigned int uu[4] = {u.x, u.y, u.z, u.w};
      #pragma unroll
      for (int i = 0; i < 4; i++) {
        a.v[2 * i] = (_Float16)bf2f(uu[i] & 0xffffu);
        a.v[2 * i + 1] = (_Float16)bf2f(uu[i] >> 16);
      }
    } else {
      a.u = ap[(kk << 2) + quad];
    }
    #pragma unroll
    for (int nt = 0; nt < NT; nt++) {
      H8 b;
      b.u = *reinterpret_cast<const uint4*>(BT + (size_t)(nt * 16 + r) * K + kk * 32 + quad * 8);
      acc[nt] = __builtin_amdgcn_mfma_f32_16x16x32_f16(a.v, b.v, acc[nt], 0, 0, 0);
    }
  }
  #pragma unroll
  for (int nt = 0; nt < NT; nt++) {
    #pragma unroll
    for (int i = 0; i < 4; i++)
      C[(size_t)(m0 + quad * 4 + i) * Npad + nt * 16 + r] = (_Float16)acc[nt][i];
  }
}

// ------- aggregation: wave-per-node, scalar broadcast, no LDS/barriers -------
// DOQ: additionally emit int8-quantized row + invq (for next layer's int8 sim);
// else emit invn = 1/||row||.

template<int NC, int STRIDE, int VEC, bool DOQ>
__global__ __launch_bounds__(256) void aggw_relu_kernel(
    const _Float16* __restrict__ hp, const float* __restrict__ ew,
    const int* __restrict__ srcP, const int* __restrict__ off,
    const float* __restrict__ dinv, const float* __restrict__ sw,
    const unsigned short* __restrict__ biasb, const float* __restrict__ biasf,
    const int* __restrict__ flags, _Float16* __restrict__ out,
    unsigned char* __restrict__ qout, float* __restrict__ invn, int n) {
  constexpr int ACT = NC / VEC;
  int i = blockIdx.x * 4 + (threadIdx.x >> 6);
  if (i >= n) return;
  int lane = threadIdx.x & 63;
  float di = dinv[i];
  float sii = sw[i] * di * di;
  float acc[VEC];
  #pragma unroll
  for (int v = 0; v < VEC; v++) acc[v] = 0.f;
  if (lane < ACT) {
    if constexpr (VEC == 4) {
      H4 hv;
      hv.u = *reinterpret_cast<const uint2*>(hp + (size_t)i * STRIDE + lane * 4);
      #pragma unroll
      for (int v = 0; v < 4; v++) acc[v] = sii * (float)hv.e[v];
    } else {
      acc[0] = sii * (float)hp[(size_t)i * STRIDE + lane];
    }
  }
  int e0 = off[i], e1 = off[i + 1];
  for (int base = e0; base < e1; base += 64) {
    int j = base + lane;
    int sreg = 0;
    float creg = 0.f;
    if (j < e1) {
      sreg = srcP[j];
      float e = ew[j];
      if (e != 0.f) creg = e * dinv[sreg] * di;
    }
    int m = min(64, e1 - base);
    for (int k = 0; k < m; k++) {
      float cfk = rlf(creg, k);
      if (cfk != 0.f) {
        int sk = rl(sreg, k);
        if (lane < ACT) {
          if constexpr (VEC == 4) {
            H4 hv;
            hv.u = *reinterpret_cast<const uint2*>(hp + (size_t)sk * STRIDE + lane * 4);
            #pragma unroll
            for (int v = 0; v < 4; v++) acc[v] += cfk * (float)hv.e[v];
          } else {
            acc[0] += cfk * (float)hp[(size_t)sk * STRIDE + lane];
          }
        }
      }
    }
  }
  float nrm = 0.f, lmax = 0.f;
  float xv[VEC];
  if (lane < ACT) {
    if constexpr (VEC == 4) {
      H4 ov;
      #pragma unroll
      for (int v = 0; v < 4; v++) {
        int c = lane * 4 + v;
        float bb = flags[1] ? biasf[c] : bf2f((unsigned int)biasb[c]);
        float x = acc[v] + bb;
        x = x > 0.f ? x : 0.f;
        xv[v] = x;
        ov.e[v] = (_Float16)x;
        nrm += x * x;
        lmax = fmaxf(lmax, x);
      }
      *reinterpret_cast<uint2*>(out + (size_t)i * NC + lane * 4) = ov.u;
    } else {
      float bb = flags[1] ? biasf[lane] : bf2f((unsigned int)biasb[lane]);
      float x = acc[0] + bb;
      x = x > 0.f ? x : 0.f;
      xv[0] = x;
      out[(size_t)i * NC + lane] = (_Float16)x;
      nrm = x * x;
      lmax = x;
    }
  }
  nrm = wave_sum(nrm);
  if constexpr (DOQ) {
    float mx = wave_max(lmax);
    float scale = (mx > 0.f) ? 127.0f / mx : 0.f;
    if (lane < ACT) {
      if constexpr (VEC == 4) {
        unsigned int qw = 0;
        #pragma unroll
        for (int v = 0; v < 4; v++) {
          int qq = (int)(xv[v] * scale + 0.5f);
          qw |= ((unsigned int)(qq & 0xff)) << (8 * v);
        }
        *reinterpret_cast<unsigned int*>(qout + (size_t)i * NC + lane * 4) = qw;
      } else {
        qout[(size_t)i * NC + lane] = (unsigned char)(int)(xv[0] * scale + 0.5f);
      }
    }
    if (lane == 0)
      invn[i] = (mx > 0.f && nrm > 0.f) ? (mx / 127.0f) * rsqrtf(nrm) : 0.f;
  } else {
    if (lane == 0) invn[i] = (nrm == 0.f) ? 1.0f : rsqrtf(nrm);
  }
}

__global__ __launch_bounds__(256) void aggw_lsm_kernel(
    const _Float16* __restrict__ hp, const float* __restrict__ ew,
    const int* __restrict__ srcP, const int* __restrict__ off,
    const float* __restrict__ dinv, const float* __restrict__ sw,
    const unsigned short* __restrict__ biasb, const float* __restrict__ biasf,
    const int* __restrict__ flags, void* __restrict__ outv, int n) {
  constexpr int NC = 40, STRIDE = 48;
  int i = blockIdx.x * 4 + (threadIdx.x >> 6);
  if (i >= n) return;
  int lane = threadIdx.x & 63;
  float di = dinv[i];
  float acc = 0.f;
  if (lane < NC) acc = sw[i] * di * di * (float)hp[(size_t)i * STRIDE + lane];
  int e0 = off[i], e1 = off[i + 1];
  for (int base = e0; base < e1; base += 64) {
    int j = base + lane;
    int sreg = 0;
    float creg = 0.f;
    if (j < e1) {
      sreg = srcP[j];
      float e = ew[j];
      if (e != 0.f) creg = e * dinv[sreg] * di;
    }
    int m = min(64, e1 - base);
    for (int k = 0; k < m; k++) {
      float cfk = rlf(creg, k);
      if (cfk != 0.f) {
        int sk = rl(sreg, k);
        if (lane < NC) acc += cfk * (float)hp[(size_t)sk * STRIDE + lane];
      }
    }
  }
  int f32 = flags[1];
  float bb = 0.f;
  if (lane < NC) bb = f32 ? biasf[lane] : bf2f((unsigned int)biasb[lane]);
  float v = (lane < NC) ? acc + bb : -3.0e38f;
  float vm = wave_max(v);
  float ex = (lane < NC) ? expf(v - vm) : 0.f;
  float se = wave_sum(ex);
  float ls = logf(se);
  if (lane < NC) {
    float r = v - vm - ls;
    if (f32) ((float*)outv)[(size_t)i * NC + lane] = r;
    else ((unsigned short*)outv)[(size_t)i * NC + lane] = f2bf(r);
  }
}

// ---------------- host ----------------

extern "C" void kernel_launch(void* const* d_in, const int* in_sizes, int n_in,
                              void* d_out, int out_size, void* d_ws, size_t ws_size,
                              hipStream_t stream) {
  const unsigned short* xb = (const unsigned short*)d_in[0];
  const float* xf          = (const float*)d_in[0];
  const int* ei            = (const int*)d_in[1];

  const int H  = in_sizes[3];            // 256
  const int F  = in_sizes[2] / H;        // 512
  const int D2 = in_sizes[5];            // 64
  const int C  = in_sizes[7];            // 40
  const int N  = in_sizes[0] / F;        // 50000
  const int E  = in_sizes[1] / 2;        // 1600000
  const int CP = 48;

  char* p = (char*)d_ws;
  auto alloc = [&](size_t bytes) -> char* {
    char* r = p;
    p += (bytes + 255) & ~(size_t)255;
    return r;
  };
  int*   srcP   = (int*)alloc((size_t)E * 4 + 32);
  int*   dstP   = (int*)alloc((size_t)E * 4 + 32);
  float* wbuf   = (float*)alloc((size_t)E * 4);
  int*   off    = (int*)alloc((size_t)(N + 1) * 4);
  int*   cur    = (int*)alloc((size_t)N * 4);
  float* invn   = (float*)alloc((size_t)N * 4);
  float* rowsum = (float*)alloc((size_t)N * 4);
  float* degcnt = (float*)alloc((size_t)N * 4);
  float* sw     = (float*)alloc((size_t)N * 4);
  float* deg2   = (float*)alloc((size_t)N * 4);
  float* dinv   = (float*)alloc((size_t)N * 4);
  int*   flags  = (int*)alloc(256);
  int*   bsum   = (int*)alloc(4096 * 4);
  _Float16* WT  = (_Float16*)alloc((size_t)256 * 512 * 2);
  _Float16* hp  = (_Float16*)alloc((size_t)N * 256 * 2);
  size_t used = (size_t)(p - (char*)d_ws);
  size_t xh_bytes = (size_t)N * 512 * 2;
  bool big = (used + xh_bytes + 256) <= ws_size;
  _Float16* xh = big ? (_Float16*)alloc(xh_bytes) : hp;

  // int8 x rows alias hp (dead until gemm1, which runs after the layer-1 sim)
  unsigned char* xq = (unsigned char*)hp;          // N*512 = 25.6MB == sizeof(hp)
  _Float16* h1 = (_Float16*)d_in[0];               // N*256 f16 = 25.6MB
  unsigned char* h1q = (unsigned char*)d_in[0] + (size_t)N * 512; // N*256 int8, fits x buf
  _Float16* h2 = hp + (size_t)N * 64;
  size_t rd_span = (size_t)((char*)degcnt - (char*)rowsum) + (size_t)N * 4;

  const int TB = 256;
  int nblk = (N + TB - 1) / TB;
  int eblk = (E + TB - 1) / TB;
  int nwav = (N + 3) / 4;
  int ewav = (E + 3) / 4;
  int mt4  = (N / 16 + 3) / 4;
  int nb1024 = (N + 1023) / 1024;
  // 4-edge/wave grid (16 edges/block) for f16 64-dim sim
  int sblocks4 = (E + 15) / 16;
  int schunk4 = (sblocks4 + 7) / 8;
  int sgrid4 = schunk4 * 8;
  // 8-edge/wave grid (32 edges/block) for int8 sims
  int sblocks8 = (E + 31) / 32;
  int schunk8 = (sblocks8 + 7) / 8;
  int sgrid8 = schunk8 * 8;

  detect_kernel<<<1, 256, 0, stream>>>(ei, (const unsigned int*)d_in[2], flags, E);

  hipMemsetAsync(cur, 0, (size_t)N * 4, stream);
  count_kernel<<<eblk, TB, 0, stream>>>(ei, flags, cur, E, N);
  scan1_kernel<<<nb1024, 1024, 0, stream>>>(cur, off, bsum, N);
  scan2_kernel<<<1, 1024, 0, stream>>>(bsum, nb1024);
  scan3_kernel<<<nblk, TB, 0, stream>>>(off, bsum, N);
  copy_kernel<<<nblk, TB, 0, stream>>>(off, cur, N);
  fill_kernel<<<eblk, TB, 0, stream>>>(ei, flags, cur, srcP, dstP, E, N);

  // ---------- layer 1: x(512) -> h1(256) ----------
  hipMemsetAsync(rowsum, 0, rd_span, stream);
  if (big) {
    convert_norm_kernel<<<nwav, TB, 0, stream>>>(xf, xb, flags, xh, xq, invn, N);
    simq_kernel<512><<<sgrid8, TB, 0, stream>>>(xq, srcP, dstP, invn, wbuf, rowsum, degcnt, E, schunk8);
  } else {
    norm8_kernel<<<nwav, TB, 0, stream>>>(xb, xf, flags, invn, N);
    simf_kernel<<<ewav, TB, 0, stream>>>(xb, xf, flags, srcP, dstP, invn, wbuf, rowsum, degcnt, E);
  }
  node_a_kernel<<<nblk, TB, 0, stream>>>(rowsum, degcnt, sw, deg2, N);
  edge_b_kernel<<<eblk, TB, 0, stream>>>(wbuf, srcP, dstP, rowsum, deg2, E);
  node_b_kernel<<<nblk, TB, 0, stream>>>(deg2, dinv, N);
  transpose_kernel<<<(H * F + TB - 1) / TB, TB, 0, stream>>>(
      (const unsigned short*)d_in[2], (const float*)d_in[2], flags, WT, F, H, H);
  gemmw_kernel<16, 16><<<mt4, TB, 0, stream>>>(
      xh, xf, xb, flags, big ? 0 : 1, WT, hp, N, H);
  aggw_relu_kernel<256, 256, 4, true><<<nwav, TB, 0, stream>>>(
      hp, wbuf, srcP, off, dinv, sw,
      (const unsigned short*)d_in[3], (const float*)d_in[3], flags, h1, h1q, invn, N);

  // ---------- layer 2: h1(256) -> h2(64) ----------
  hipMemsetAsync(rowsum, 0, rd_span, stream);
  simq_kernel<256><<<sgrid8, TB, 0, stream>>>(h1q, srcP, dstP, invn, wbuf, rowsum, degcnt, E, schunk8);
  node_a_kernel<<<nblk, TB, 0, stream>>>(rowsum, degcnt, sw, deg2, N);
  edge_b_kernel<<<eblk, TB, 0, stream>>>(wbuf, srcP, dstP, rowsum, deg2, E);
  node_b_kernel<<<nblk, TB, 0, stream>>>(deg2, dinv, N);
  transpose_kernel<<<(D2 * H + TB - 1) / TB, TB, 0, stream>>>(
      (const unsigned short*)d_in[4], (const float*)d_in[4], flags, WT, H, D2, D2);
  gemmw_kernel<4, 8><<<mt4, TB, 0, stream>>>(h1, xf, xb, flags, 0, WT, hp, N, D2);
  aggw_relu_kernel<64, 64, 1, false><<<nwav, TB, 0, stream>>>(
      hp, wbuf, srcP, off, dinv, sw,
      (const unsigned short*)d_in[5], (const float*)d_in[5], flags, h2, nullptr, invn, N);

  // ---------- layer 3: h2(64) -> out(40), fused log_softmax ----------
  hipMemsetAsync(rowsum, 0, rd_span, stream);
  simb64_kernel<<<sgrid4, TB, 0, stream>>>(h2, srcP, dstP, invn, wbuf, rowsum, degcnt, E, schunk4);
  node_a_kernel<<<nblk, TB, 0, stream>>>(rowsum, degcnt, sw, deg2, N);
  edge_b_kernel<<<eblk, TB, 0, stream>>>(wbuf, srcP, dstP, rowsum, deg2, E);
  node_b_kernel<<<nblk, TB, 0, stream>>>(deg2, dinv, N);
  transpose_kernel<<<(CP * D2 + TB - 1) / TB, TB, 0, stream>>>(
      (const unsigned short*)d_in[6], (const float*)d_in[6], flags, WT, D2, C, CP);
  gemmw_kernel<3, 2><<<mt4, TB, 0, stream>>>(h2, xf, xb, flags, 0, WT, hp, N, CP);
  aggw_lsm_kernel<<<nwav, TB, 0, stream>>>(
      hp, wbuf, srcP, off, dinv, sw,
      (const unsigned short*)d_in[7], (const float*)d_in[7], flags, d_out, N);
}

// Round 9
// 1576.217 us; speedup vs baseline: 1.9768x; 1.0227x over previous
//
#include <hip/hip_runtime.h>
#include <stdint.h>

typedef __attribute__((ext_vector_type(8))) _Float16 half8v;
typedef __attribute__((ext_vector_type(2))) _Float16 half2v;
typedef __attribute__((ext_vector_type(4))) float floatx4;

union H8 { uint4 u; half8v v; half2v h[4]; _Float16 e[8]; };
union H4 { uint2 u; half2v h[2]; _Float16 e[4]; };

__device__ __forceinline__ float bf2f(unsigned int u) {
  union { unsigned int i; float f; } x;
  x.i = u << 16;
  return x.f;
}

#if __has_builtin(__builtin_amdgcn_sdot4)
__device__ __forceinline__ int dot4i(int a, int b, int c) {
  return __builtin_amdgcn_sdot4(a, b, c, false);
}
#else
__device__ __forceinline__ int dot4i(int a, int b, int c) {
  #pragma unroll
  for (int i = 0; i < 4; i++)
    c += (int)(signed char)(a >> (8 * i)) * (int)(signed char)(b >> (8 * i));
  return c;
}
#endif

#if __has_builtin(__builtin_amdgcn_readlane)
__device__ __forceinline__ int rl(int v, int l) { return __builtin_amdgcn_readlane(v, l); }
#else
__device__ __forceinline__ int rl(int v, int l) { return __shfl(v, l, 64); }
#endif
__device__ __forceinline__ float rlf(float v, int l) {
  union { float f; int i; } x; x.f = v;
  x.i = rl(x.i, l);
  return x.f;
}

__device__ __forceinline__ float wave_sum(float v) {
  #pragma unroll
  for (int m = 32; m > 0; m >>= 1) v += __shfl_xor(v, m, 64);
  return v;
}

__device__ __forceinline__ float wave_max(float v) {
  #pragma unroll
  for (int m = 32; m > 0; m >>= 1) v = fmaxf(v, __shfl_xor(v, m, 64));
  return v;
}

__device__ __forceinline__ unsigned short f2bf(float f) {
  union { float f; unsigned int u; } x; x.f = f;
  unsigned int r = x.u + 0x7fffu + ((x.u >> 16) & 1u);
  return (unsigned short)(r >> 16);
}

// -------- dtype detection: flags[0]=edges int64, flags[1]=floats fp32 --------

__global__ void detect_kernel(const int* __restrict__ ei, const unsigned int* __restrict__ w1,
                              int* __restrict__ flags, int E) {
  __shared__ int nz, sane;
  if (threadIdx.x == 0) { nz = 0; sane = 0; }
  __syncthreads();
  for (int i = threadIdx.x; i < 2048; i += blockDim.x) {
    if (i < E && ei[2 * i + 1] != 0) atomicAdd(&nz, 1);
    union { unsigned int u; float f; } c; c.u = w1[i];
    float af = fabsf(c.f);
    if (c.f == c.f && af > 1e-10f && af < 1e10f) atomicAdd(&sane, 1);
  }
  __syncthreads();
  if (threadIdx.x == 0) {
    flags[0] = (nz == 0) ? 1 : 0;
    flags[1] = (sane > 1024) ? 1 : 0;
  }
}

// ---------------- CSR build (by dst) with inline edge decode ----------------

__global__ void count_kernel(const int* __restrict__ ei, const int* __restrict__ flags,
                             int* __restrict__ cnt, int E, int N) {
  int e = blockIdx.x * blockDim.x + threadIdx.x;
  if (e >= E) return;
  int d = flags[0] ? ei[2 * (E + e)] : ei[E + e];
  d = ((unsigned)d < (unsigned)N) ? d : 0;
  atomicAdd(&cnt[d], 1);
}

__global__ void scan1_kernel(const int* __restrict__ cnt, int* __restrict__ off,
                             int* __restrict__ bsum, int n) {
  __shared__ int buf[1024];
  int t = threadIdx.x;
  int i = blockIdx.x * 1024 + t;
  int v = (i < n) ? cnt[i] : 0;
  buf[t] = v;
  __syncthreads();
  for (int o = 1; o < 1024; o <<= 1) {
    int a = (t >= o) ? buf[t - o] : 0;
    __syncthreads();
    buf[t] += a;
    __syncthreads();
  }
  if (i < n) off[i + 1] = buf[t];
  if (t == 1023) bsum[blockIdx.x] = buf[1023];
}

__global__ void scan2_kernel(int* __restrict__ bsum, int nb) {
  __shared__ int buf[1024];
  int t = threadIdx.x;
  int v = (t < nb) ? bsum[t] : 0;
  buf[t] = v;
  __syncthreads();
  for (int o = 1; o < 1024; o <<= 1) {
    int a = (t >= o) ? buf[t - o] : 0;
    __syncthreads();
    buf[t] += a;
    __syncthreads();
  }
  if (t < nb) bsum[t] = buf[t];
}

// finalize off and seed cur (= final off) in one pass
__global__ void scan3_kernel(int* __restrict__ off, int* __restrict__ cur,
                             const int* __restrict__ bsum, int n) {
  int i = blockIdx.x * blockDim.x + threadIdx.x;
  if (i == 0) { off[0] = 0; cur[0] = 0; }
  if (i < n) {
    int b = i >> 10;
    int v = off[i + 1] + ((b > 0) ? bsum[b - 1] : 0);
    off[i + 1] = v;
    if (i + 1 < n) cur[i + 1] = v;
  }
}

__global__ void fill_kernel(const int* __restrict__ ei, const int* __restrict__ flags,
                            int* __restrict__ cur, int* __restrict__ srcP,
                            int* __restrict__ dstP, int E, int N) {
  int e = blockIdx.x * blockDim.x + threadIdx.x;
  if (e >= E) return;
  int s, d;
  if (flags[0]) { s = ei[2 * e]; d = ei[2 * (E + e)]; }
  else          { s = ei[e];     d = ei[E + e]; }
  s = ((unsigned)s < (unsigned)N) ? s : 0;
  d = ((unsigned)d < (unsigned)N) ? d : 0;
  int pos = atomicAdd(&cur[d], 1);
  srcP[pos] = s;
  dstP[pos] = d;
}

// -- layer-1 convert+norm: fp32/bf16 x -> f16 rows + int8 rows + invq --------

__global__ __launch_bounds__(256) void convert_norm_kernel(
    const float* __restrict__ xf, const unsigned short* __restrict__ xb,
    const int* __restrict__ flags, _Float16* __restrict__ xo,
    unsigned char* __restrict__ xq, float* __restrict__ invq, int n) {
  int row = blockIdx.x * 4 + (threadIdx.x >> 6);
  int lane = threadIdx.x & 63;
  if (row >= n) return;
  float ss = 0.f, mx = 0.f;
  float vals[8];
  H8 o;
  if (flags[1]) {
    const float4* vp = reinterpret_cast<const float4*>(xf + (size_t)row * 512) + lane * 2;
    float4 a = vp[0], b = vp[1];
    vals[0] = a.x; vals[1] = a.y; vals[2] = a.z; vals[3] = a.w;
    vals[4] = b.x; vals[5] = b.y; vals[6] = b.z; vals[7] = b.w;
  } else {
    uint4 v = *(reinterpret_cast<const uint4*>(xb + (size_t)row * 512) + lane);
    unsigned int a[4] = {v.x, v.y, v.z, v.w};
    #pragma unroll
    for (int i = 0; i < 4; i++) {
      vals[2 * i] = bf2f(a[i] & 0xffffu);
      vals[2 * i + 1] = bf2f(a[i] >> 16);
    }
  }
  #pragma unroll
  for (int i = 0; i < 8; i++) {
    ss += vals[i] * vals[i];
    mx = fmaxf(mx, fabsf(vals[i]));
    o.v[i] = (_Float16)vals[i];
  }
  *(reinterpret_cast<uint4*>(xo + (size_t)row * 512) + lane) = o.u;
  ss = wave_sum(ss);
  mx = wave_max(mx);
  float scale = (mx > 0.f) ? 127.0f / mx : 0.f;
  uint2 qo;
  unsigned int q0 = 0, q1 = 0;
  #pragma unroll
  for (int i = 0; i < 4; i++) {
    int q = (int)rintf(vals[i] * scale);
    q0 |= ((unsigned int)(q & 0xff)) << (8 * i);
  }
  #pragma unroll
  for (int i = 0; i < 4; i++) {
    int q = (int)rintf(vals[4 + i] * scale);
    q1 |= ((unsigned int)(q & 0xff)) << (8 * i);
  }
  qo.x = q0; qo.y = q1;
  *(reinterpret_cast<uint2*>(xq + (size_t)row * 512) + lane) = qo;
  if (lane == 0)
    invq[row] = (mx > 0.f && ss > 0.f) ? (mx / 127.0f) * rsqrtf(ss) : 0.f;
}

// fallback norm over raw x (no int8 copy available)
__global__ __launch_bounds__(256) void norm8_kernel(const unsigned short* __restrict__ hb,
                                                    const float* __restrict__ hf,
                                                    const int* __restrict__ flags,
                                                    float* __restrict__ invn, int n) {
  int wid = blockIdx.x * 4 + (threadIdx.x >> 6);
  int lane = threadIdx.x & 63;
  if (wid >= n) return;
  float s = 0.f;
  if (flags[1]) {
    const float4* vp = reinterpret_cast<const float4*>(hf + (size_t)wid * 512) + lane * 2;
    float4 a = vp[0], b = vp[1];
    s = a.x*a.x + a.y*a.y + a.z*a.z + a.w*a.w + b.x*b.x + b.y*b.y + b.z*b.z + b.w*b.w;
  } else {
    uint4 v = *(reinterpret_cast<const uint4*>(hb + (size_t)wid * 512) + lane);
    unsigned int a[4] = {v.x, v.y, v.z, v.w};
    #pragma unroll
    for (int i = 0; i < 4; i++) {
      float lo = bf2f(a[i] & 0xffffu), hi = bf2f(a[i] >> 16);
      s += lo * lo + hi * hi;
    }
  }
  s = wave_sum(s);
  if (lane == 0) invn[wid] = (s == 0.f) ? 1.0f : rsqrtf(s);
}

// --- int8 cosine sim: 16-lane groups, 4 edges/wave x 2 batches, sdot4 ------
// RB = row bytes (512 / 256 / 64). Reduction = 4 stages within the group.

template<int RB>
__global__ __launch_bounds__(256) void simq2_kernel(const unsigned char* __restrict__ q,
                                                    const int* __restrict__ srcP,
                                                    const int* __restrict__ dstP,
                                                    const float* __restrict__ invq,
                                                    float* __restrict__ w,
                                                    float* __restrict__ rowsum,
                                                    float* __restrict__ degcnt,
                                                    int E, int chunk) {
  int nb = (blockIdx.x & 7) * chunk + (blockIdx.x >> 3);
  int lane = threadIdx.x & 63;
  int l = lane & 15, g = lane >> 4;
  int j0 = (nb * 4 + (threadIdx.x >> 6)) * 8;   // 8 edges per wave
  if (j0 >= E) return;
  int sj[2], tj[2];
  bool val[2];
  #pragma unroll
  for (int b = 0; b < 2; b++) {
    int j = j0 + b * 4 + g;
    val[b] = j < E;
    int jj = val[b] ? j : 0;
    sj[b] = srcP[jj];                 // same addr across 16 lanes -> broadcast
    tj[b] = dstP[jj];
  }
  int acc[2];
  if constexpr (RB == 512) {
    uint4 sa[2][2], ta[2][2];
    #pragma unroll
    for (int b = 0; b < 2; b++) {
      const unsigned char* sp = q + (size_t)sj[b] * 512 + l * 16;
      const unsigned char* tp = q + (size_t)tj[b] * 512 + l * 16;
      sa[b][0] = *reinterpret_cast<const uint4*>(sp);
      sa[b][1] = *reinterpret_cast<const uint4*>(sp + 256);
      ta[b][0] = *reinterpret_cast<const uint4*>(tp);
      ta[b][1] = *reinterpret_cast<const uint4*>(tp + 256);
    }
    #pragma unroll
    for (int b = 0; b < 2; b++) {
      int a = 0;
      a = dot4i((int)sa[b][0].x, (int)ta[b][0].x, a);
      a = dot4i((int)sa[b][0].y, (int)ta[b][0].y, a);
      a = dot4i((int)sa[b][0].z, (int)ta[b][0].z, a);
      a = dot4i((int)sa[b][0].w, (int)ta[b][0].w, a);
      a = dot4i((int)sa[b][1].x, (int)ta[b][1].x, a);
      a = dot4i((int)sa[b][1].y, (int)ta[b][1].y, a);
      a = dot4i((int)sa[b][1].z, (int)ta[b][1].z, a);
      a = dot4i((int)sa[b][1].w, (int)ta[b][1].w, a);
      acc[b] = a;
    }
  } else if constexpr (RB == 256) {
    uint4 sa[2], ta[2];
    #pragma unroll
    for (int b = 0; b < 2; b++) {
      sa[b] = *reinterpret_cast<const uint4*>(q + (size_t)sj[b] * 256 + l * 16);
      ta[b] = *reinterpret_cast<const uint4*>(q + (size_t)tj[b] * 256 + l * 16);
    }
    #pragma unroll
    for (int b = 0; b < 2; b++) {
      int a = 0;
      a = dot4i((int)sa[b].x, (int)ta[b].x, a);
      a = dot4i((int)sa[b].y, (int)ta[b].y, a);
      a = dot4i((int)sa[b].z, (int)ta[b].z, a);
      a = dot4i((int)sa[b].w, (int)ta[b].w, a);
      acc[b] = a;
    }
  } else {  // RB == 64
    unsigned int sa[2], ta[2];
    #pragma unroll
    for (int b = 0; b < 2; b++) {
      sa[b] = *reinterpret_cast<const unsigned int*>(q + (size_t)sj[b] * 64 + l * 4);
      ta[b] = *reinterpret_cast<const unsigned int*>(q + (size_t)tj[b] * 64 + l * 4);
    }
    #pragma unroll
    for (int b = 0; b < 2; b++) acc[b] = dot4i((int)sa[b], (int)ta[b], 0);
  }
  // 4-stage reduction within the 16-lane group
  #pragma unroll
  for (int m = 1; m < 16; m <<= 1) {
    acc[0] += __shfl_xor(acc[0], m, 64);
    acc[1] += __shfl_xor(acc[1], m, 64);
  }
  if (l == 0) {
    #pragma unroll
    for (int b = 0; b < 2; b++) {
      if (val[b]) {
        int j = j0 + b * 4 + g;
        float simv = (float)acc[b] * invq[sj[b]] * invq[tj[b]];
        float wv = (sj[b] != tj[b] && simv > 0.f) ? simv : 0.f;
        w[j] = wv;
        if (wv > 0.f) {
          atomicAdd(&rowsum[sj[b]], wv);
          atomicAdd(&degcnt[sj[b]], 1.0f);
        }
      }
    }
  }
}

// fallback layer-1 sim on raw x
__global__ __launch_bounds__(256) void simf_kernel(const unsigned short* __restrict__ hb,
                                                   const float* __restrict__ hf,
                                                   const int* __restrict__ flags,
                                                   const int* __restrict__ srcP,
                                                   const int* __restrict__ dstP,
                                                   const float* __restrict__ invn,
                                                   float* __restrict__ w,
                                                   float* __restrict__ rowsum,
                                                   float* __restrict__ degcnt, int E) {
  int j = blockIdx.x * 4 + (threadIdx.x >> 6);
  int lane = threadIdx.x & 63;
  if (j >= E) return;
  int s = srcP[j], t = dstP[j];
  float acc = 0.f;
  if (flags[1]) {
    const float4* ap = reinterpret_cast<const float4*>(hf + (size_t)s * 512) + lane * 2;
    const float4* bp = reinterpret_cast<const float4*>(hf + (size_t)t * 512) + lane * 2;
    float4 a0 = ap[0], a1 = ap[1], b0 = bp[0], b1 = bp[1];
    acc = a0.x*b0.x + a0.y*b0.y + a0.z*b0.z + a0.w*b0.w
        + a1.x*b1.x + a1.y*b1.y + a1.z*b1.z + a1.w*b1.w;
  } else {
    uint4 a = *(reinterpret_cast<const uint4*>(hb + (size_t)s * 512) + lane);
    uint4 b = *(reinterpret_cast<const uint4*>(hb + (size_t)t * 512) + lane);
    unsigned int av[4] = {a.x, a.y, a.z, a.w};
    unsigned int bv[4] = {b.x, b.y, b.z, b.w};
    #pragma unroll
    for (int i = 0; i < 4; i++)
      acc += bf2f(av[i] & 0xffffu) * bf2f(bv[i] & 0xffffu)
           + bf2f(av[i] >> 16) * bf2f(bv[i] >> 16);
  }
  acc = wave_sum(acc);
  if (lane == 0) {
    float simv = acc * invn[s] * invn[t];
    float wv = (s != t && simv > 0.f) ? simv : 0.f;
    w[j] = wv;
    if (wv > 0.f) {
      atomicAdd(&rowsum[s], wv);
      atomicAdd(&degcnt[s], 1.0f);
    }
  }
}

// ---------------- node / edge scalar stages ----------------

__global__ void node_a_kernel(float* __restrict__ rowsum, const float* __restrict__ degcnt,
                              float* __restrict__ sw, float* __restrict__ deg2, int n) {
  int i = blockIdx.x * blockDim.x + threadIdx.x;
  if (i >= n) return;
  float rs = rowsum[i];
  rowsum[i] = (rs > 0.f) ? 1.0f / rs : 0.0f;
  float lam = 1.0f / (degcnt[i] + 1.0f);
  float s = expf(lam);
  sw[i] = s;
  deg2[i] = s;
}

__global__ void edge_b_kernel(float* __restrict__ w, const int* __restrict__ srcP,
                              const int* __restrict__ dstP, const float* __restrict__ invrs,
                              float* __restrict__ deg2, int E) {
  int j = blockIdx.x * blockDim.x + threadIdx.x;
  if (j >= E) return;
  float wv = w[j];
  if (wv > 0.f) {
    float ewv = expf(wv * invrs[srcP[j]]);
    w[j] = ewv;
    atomicAdd(&deg2[dstP[j]], ewv);
  }
}

__global__ void node_b_kernel(const float* __restrict__ deg2, float* __restrict__ dinv, int n) {
  int i = blockIdx.x * blockDim.x + threadIdx.x;
  if (i < n) dinv[i] = rsqrtf(deg2[i]);
}

// ---------------- GEMM (f16 MFMA) ----------------

__global__ void transpose_kernel(const unsigned short* __restrict__ Wb,
                                 const float* __restrict__ Wf,
                                 const int* __restrict__ flags,
                                 _Float16* __restrict__ WT,
                                 int K, int Nc, int Npad) {
  int idx = blockIdx.x * blockDim.x + threadIdx.x;
  if (idx >= Npad * K) return;
  int nn = idx / K, k = idx - nn * K;
  _Float16 v = (_Float16)0.f;
  if (nn < Nc) {
    if (flags[1]) v = (_Float16)Wf[(size_t)k * Nc + nn];
    else          v = (_Float16)bf2f((unsigned int)Wb[(size_t)k * Nc + nn]);
  }
  WT[idx] = v;
}

template<int NT, int KSTEPS>
__global__ __launch_bounds__(256) void gemmw_kernel(const _Float16* __restrict__ Ah,
                                                    const float* __restrict__ Af,
                                                    const unsigned short* __restrict__ Abf,
                                                    const int* __restrict__ flags,
                                                    int useflags,
                                                    const _Float16* __restrict__ BT,
                                                    _Float16* __restrict__ C,
                                                    int M, int Npad) {
  constexpr int K = KSTEPS * 32;
  int mt = blockIdx.x * 4 + (threadIdx.x >> 6);
  if (mt * 16 >= M) return;
  int lane = threadIdx.x & 63;
  int r = lane & 15, quad = lane >> 4;
  int m0 = mt * 16;
  int mode = useflags ? (flags[1] ? 1 : 2) : 0;
  floatx4 acc[NT];
  #pragma unroll
  for (int nt = 0; nt < NT; nt++) acc[nt] = floatx4{0.f, 0.f, 0.f, 0.f};
  const uint4* ap = reinterpret_cast<const uint4*>(Ah + (size_t)(m0 + r) * K);
  const float* af = Af + (size_t)(m0 + r) * K + quad * 8;
  const unsigned short* ab = Abf + (size_t)(m0 + r) * K + quad * 8;
  for (int kk = 0; kk < KSTEPS; kk++) {
    H8 a;
    if (mode == 1) {
      float4 x0 = *reinterpret_cast<const float4*>(af + kk * 32);
      float4 x1 = *reinterpret_cast<const float4*>(af + kk * 32 + 4);
      a.v[0] = (_Float16)x0.x; a.v[1] = (_Float16)x0.y;
      a.v[2] = (_Float16)x0.z; a.v[3] = (_Float16)x0.w;
      a.v[4] = (_Float16)x1.x; a.v[5] = (_Float16)x1.y;
      a.v[6] = (_Float16)x1.z; a.v[7] = (_Float16)x1.w;
    } else if (mode == 2) {
      uint4 u = *reinterpret_cast<const uint4*>(ab + kk * 32);
      unsigned int uu[4] = {u.x, u.y, u.z, u.w};
      #pragma unroll
      for (int i = 0; i < 4; i++) {
        a.v[2 * i] = (_Float16)bf2f(uu[i] & 0xffffu);
        a.v[2 * i + 1] = (_Float16)bf2f(uu[i] >> 16);
      }
    } else {
      a.u = ap[(kk << 2) + quad];
    }
    #pragma unroll
    for (int nt = 0; nt < NT; nt++) {
      H8 b;
      b.u = *reinterpret_cast<const uint4*>(BT + (size_t)(nt * 16 + r) * K + kk * 32 + quad * 8);
      acc[nt] = __builtin_amdgcn_mfma_f32_16x16x32_f16(a.v, b.v, acc[nt], 0, 0, 0);
    }
  }
  #pragma unroll
  for (int nt = 0; nt < NT; nt++) {
    #pragma unroll
    for (int i = 0; i < 4; i++)
      C[(size_t)(m0 + quad * 4 + i) * Npad + nt * 16 + r] = (_Float16)acc[nt][i];
  }
}

// ------- aggregation: wave-per-node, scalar broadcast, no LDS/barriers -------
// DOQ: also emit int8 row + scaled invq for the next layer's int8 sim.

template<int NC, int STRIDE, int VEC, bool DOQ>
__global__ __launch_bounds__(256) void aggw_relu_kernel(
    const _Float16* __restrict__ hp, const float* __restrict__ ew,
    const int* __restrict__ srcP, const int* __restrict__ off,
    const float* __restrict__ dinv, const float* __restrict__ sw,
    const unsigned short* __restrict__ biasb, const float* __restrict__ biasf,
    const int* __restrict__ flags, _Float16* __restrict__ out,
    unsigned char* __restrict__ qout, float* __restrict__ invn, int n) {
  constexpr int ACT = NC / VEC;
  int i = blockIdx.x * 4 + (threadIdx.x >> 6);
  if (i >= n) return;
  int lane = threadIdx.x & 63;
  float di = dinv[i];
  float sii = sw[i] * di * di;
  float acc[VEC];
  #pragma unroll
  for (int v = 0; v < VEC; v++) acc[v] = 0.f;
  if (lane < ACT) {
    if constexpr (VEC == 4) {
      H4 hv;
      hv.u = *reinterpret_cast<const uint2*>(hp + (size_t)i * STRIDE + lane * 4);
      #pragma unroll
      for (int v = 0; v < 4; v++) acc[v] = sii * (float)hv.e[v];
    } else {
      acc[0] = sii * (float)hp[(size_t)i * STRIDE + lane];
    }
  }
  int e0 = off[i], e1 = off[i + 1];
  for (int base = e0; base < e1; base += 64) {
    int j = base + lane;
    int sreg = 0;
    float creg = 0.f;
    if (j < e1) {
      sreg = srcP[j];
      float e = ew[j];
      if (e != 0.f) creg = e * dinv[sreg] * di;
    }
    int m = min(64, e1 - base);
    for (int k = 0; k < m; k++) {
      float cfk = rlf(creg, k);
      if (cfk != 0.f) {
        int sk = rl(sreg, k);
        if (lane < ACT) {
          if constexpr (VEC == 4) {
            H4 hv;
            hv.u = *reinterpret_cast<const uint2*>(hp + (size_t)sk * STRIDE + lane * 4);
            #pragma unroll
            for (int v = 0; v < 4; v++) acc[v] += cfk * (float)hv.e[v];
          } else {
            acc[0] += cfk * (float)hp[(size_t)sk * STRIDE + lane];
          }
        }
      }
    }
  }
  float nrm = 0.f, lmax = 0.f;
  float xv[VEC];
  if (lane < ACT) {
    if constexpr (VEC == 4) {
      H4 ov;
      #pragma unroll
      for (int v = 0; v < 4; v++) {
        int c = lane * 4 + v;
        float bb = flags[1] ? biasf[c] : bf2f((unsigned int)biasb[c]);
        float x = acc[v] + bb;
        x = x > 0.f ? x : 0.f;
        xv[v] = x;
        ov.e[v] = (_Float16)x;
        nrm += x * x;
        lmax = fmaxf(lmax, x);
      }
      *reinterpret_cast<uint2*>(out + (size_t)i * NC + lane * 4) = ov.u;
    } else {
      float bb = flags[1] ? biasf[lane] : bf2f((unsigned int)biasb[lane]);
      float x = acc[0] + bb;
      x = x > 0.f ? x : 0.f;
      xv[0] = x;
      out[(size_t)i * NC + lane] = (_Float16)x;
      nrm = x * x;
      lmax = x;
    }
  }
  nrm = wave_sum(nrm);
  if constexpr (DOQ) {
    float mx = wave_max(lmax);
    float scale = (mx > 0.f) ? 127.0f / mx : 0.f;
    if (lane < ACT) {
      if constexpr (VEC == 4) {
        unsigned int qw = 0;
        #pragma unroll
        for (int v = 0; v < 4; v++) {
          int qq = (int)(xv[v] * scale + 0.5f);
          qw |= ((unsigned int)(qq & 0xff)) << (8 * v);
        }
        *reinterpret_cast<unsigned int*>(qout + (size_t)i * NC + lane * 4) = qw;
      } else {
        qout[(size_t)i * NC + lane] = (unsigned char)(int)(xv[0] * scale + 0.5f);
      }
    }
    if (lane == 0)
      invn[i] = (mx > 0.f && nrm > 0.f) ? (mx / 127.0f) * rsqrtf(nrm) : 0.f;
  } else {
    if (lane == 0) invn[i] = (nrm == 0.f) ? 1.0f : rsqrtf(nrm);
  }
}

__global__ __launch_bounds__(256) void aggw_lsm_kernel(
    const _Float16* __restrict__ hp, const float* __restrict__ ew,
    const int* __restrict__ srcP, const int* __restrict__ off,
    const float* __restrict__ dinv, const float* __restrict__ sw,
    const unsigned short* __restrict__ biasb, const float* __restrict__ biasf,
    const int* __restrict__ flags, void* __restrict__ outv, int n) {
  constexpr int NC = 40, STRIDE = 48;
  int i = blockIdx.x * 4 + (threadIdx.x >> 6);
  if (i >= n) return;
  int lane = threadIdx.x & 63;
  float di = dinv[i];
  float acc = 0.f;
  if (lane < NC) acc = sw[i] * di * di * (float)hp[(size_t)i * STRIDE + lane];
  int e0 = off[i], e1 = off[i + 1];
  for (int base = e0; base < e1; base += 64) {
    int j = base + lane;
    int sreg = 0;
    float creg = 0.f;
    if (j < e1) {
      sreg = srcP[j];
      float e = ew[j];
      if (e != 0.f) creg = e * dinv[sreg] * di;
    }
    int m = min(64, e1 - base);
    for (int k = 0; k < m; k++) {
      float cfk = rlf(creg, k);
      if (cfk != 0.f) {
        int sk = rl(sreg, k);
        if (lane < NC) acc += cfk * (float)hp[(size_t)sk * STRIDE + lane];
      }
    }
  }
  int f32 = flags[1];
  float bb = 0.f;
  if (lane < NC) bb = f32 ? biasf[lane] : bf2f((unsigned int)biasb[lane]);
  float v = (lane < NC) ? acc + bb : -3.0e38f;
  float vm = wave_max(v);
  float ex = (lane < NC) ? expf(v - vm) : 0.f;
  float se = wave_sum(ex);
  float ls = logf(se);
  if (lane < NC) {
    float r = v - vm - ls;
    if (f32) ((float*)outv)[(size_t)i * NC + lane] = r;
    else ((unsigned short*)outv)[(size_t)i * NC + lane] = f2bf(r);
  }
}

// ---------------- host ----------------

extern "C" void kernel_launch(void* const* d_in, const int* in_sizes, int n_in,
                              void* d_out, int out_size, void* d_ws, size_t ws_size,
                              hipStream_t stream) {
  const unsigned short* xb = (const unsigned short*)d_in[0];
  const float* xf          = (const float*)d_in[0];
  const int* ei            = (const int*)d_in[1];

  const int H  = in_sizes[3];            // 256
  const int F  = in_sizes[2] / H;        // 512
  const int D2 = in_sizes[5];            // 64
  const int C  = in_sizes[7];            // 40
  const int N  = in_sizes[0] / F;        // 50000
  const int E  = in_sizes[1] / 2;        // 1600000
  const int CP = 48;

  char* p = (char*)d_ws;
  auto alloc = [&](size_t bytes) -> char* {
    char* r = p;
    p += (bytes + 255) & ~(size_t)255;
    return r;
  };
  int*   srcP   = (int*)alloc((size_t)E * 4 + 32);
  int*   dstP   = (int*)alloc((size_t)E * 4 + 32);
  float* wbuf   = (float*)alloc((size_t)E * 4);
  int*   off    = (int*)alloc((size_t)(N + 1) * 4);
  int*   cur    = (int*)alloc((size_t)N * 4);
  float* invn   = (float*)alloc((size_t)N * 4);
  float* rowsum = (float*)alloc((size_t)N * 4);
  float* degcnt = (float*)alloc((size_t)N * 4);
  float* sw     = (float*)alloc((size_t)N * 4);
  float* deg2   = (float*)alloc((size_t)N * 4);
  float* dinv   = (float*)alloc((size_t)N * 4);
  int*   flags  = (int*)alloc(256);
  int*   bsum   = (int*)alloc(4096 * 4);
  _Float16* WT  = (_Float16*)alloc((size_t)256 * 512 * 2);
  _Float16* hp  = (_Float16*)alloc((size_t)N * 256 * 2);
  size_t used = (size_t)(p - (char*)d_ws);
  size_t xh_bytes = (size_t)N * 512 * 2;
  bool big = (used + xh_bytes + 256) <= ws_size;
  _Float16* xh = big ? (_Float16*)alloc(xh_bytes) : hp;

  // int8 x rows alias hp (dead until gemm1, which runs after the layer-1 sim)
  unsigned char* xq = (unsigned char*)hp;                         // N*512 B
  _Float16* h1 = (_Float16*)d_in[0];                              // N*512 B (f16)
  unsigned char* h1q = (unsigned char*)d_in[0] + (size_t)N * 512; // N*256 B
  unsigned char* h2q = (unsigned char*)d_in[0] + (size_t)N * 768; // N*64 B
  _Float16* h2 = hp + (size_t)N * 64;
  size_t rd_span = (size_t)((char*)degcnt - (char*)rowsum) + (size_t)N * 4;

  const int TB = 256;
  int nblk = (N + TB - 1) / TB;
  int eblk = (E + TB - 1) / TB;
  int nwav = (N + 3) / 4;
  int ewav = (E + 3) / 4;
  int mt4  = (N / 16 + 3) / 4;
  int nb1024 = (N + 1023) / 1024;
  // 8-edge/wave grid (32 edges/block), XCD-swizzled
  int sblocks8 = (E + 31) / 32;
  int schunk8 = (sblocks8 + 7) / 8;
  int sgrid8 = schunk8 * 8;

  detect_kernel<<<1, 256, 0, stream>>>(ei, (const unsigned int*)d_in[2], flags, E);

  hipMemsetAsync(cur, 0, (size_t)N * 4, stream);
  count_kernel<<<eblk, TB, 0, stream>>>(ei, flags, cur, E, N);
  scan1_kernel<<<nb1024, 1024, 0, stream>>>(cur, off, bsum, N);
  scan2_kernel<<<1, 1024, 0, stream>>>(bsum, nb1024);
  scan3_kernel<<<nblk, TB, 0, stream>>>(off, cur, bsum, N);
  fill_kernel<<<eblk, TB, 0, stream>>>(ei, flags, cur, srcP, dstP, E, N);

  // ---------- layer 1: x(512) -> h1(256) ----------
  hipMemsetAsync(rowsum, 0, rd_span, stream);
  if (big) {
    convert_norm_kernel<<<nwav, TB, 0, stream>>>(xf, xb, flags, xh, xq, invn, N);
    simq2_kernel<512><<<sgrid8, TB, 0, stream>>>(xq, srcP, dstP, invn, wbuf, rowsum, degcnt, E, schunk8);
  } else {
    norm8_kernel<<<nwav, TB, 0, stream>>>(xb, xf, flags, invn, N);
    simf_kernel<<<ewav, TB, 0, stream>>>(xb, xf, flags, srcP, dstP, invn, wbuf, rowsum, degcnt, E);
  }
  node_a_kernel<<<nblk, TB, 0, stream>>>(rowsum, degcnt, sw, deg2, N);
  edge_b_kernel<<<eblk, TB, 0, stream>>>(wbuf, srcP, dstP, rowsum, deg2, E);
  node_b_kernel<<<nblk, TB, 0, stream>>>(deg2, dinv, N);
  transpose_kernel<<<(H * F + TB - 1) / TB, TB, 0, stream>>>(
      (const unsigned short*)d_in[2], (const float*)d_in[2], flags, WT, F, H, H);
  gemmw_kernel<16, 16><<<mt4, TB, 0, stream>>>(
      xh, xf, xb, flags, big ? 0 : 1, WT, hp, N, H);
  aggw_relu_kernel<256, 256, 4, true><<<nwav, TB, 0, stream>>>(
      hp, wbuf, srcP, off, dinv, sw,
      (const unsigned short*)d_in[3], (const float*)d_in[3], flags, h1, h1q, invn, N);

  // ---------- layer 2: h1(256) -> h2(64) ----------
  hipMemsetAsync(rowsum, 0, rd_span, stream);
  simq2_kernel<256><<<sgrid8, TB, 0, stream>>>(h1q, srcP, dstP, invn, wbuf, rowsum, degcnt, E, schunk8);
  node_a_kernel<<<nblk, TB, 0, stream>>>(rowsum, degcnt, sw, deg2, N);
  edge_b_kernel<<<eblk, TB, 0, stream>>>(wbuf, srcP, dstP, rowsum, deg2, E);
  node_b_kernel<<<nblk, TB, 0, stream>>>(deg2, dinv, N);
  transpose_kernel<<<(D2 * H + TB - 1) / TB, TB, 0, stream>>>(
      (const unsigned short*)d_in[4], (const float*)d_in[4], flags, WT, H, D2, D2);
  gemmw_kernel<4, 8><<<mt4, TB, 0, stream>>>(h1, xf, xb, flags, 0, WT, hp, N, D2);
  aggw_relu_kernel<64, 64, 1, true><<<nwav, TB, 0, stream>>>(
      hp, wbuf, srcP, off, dinv, sw,
      (const unsigned short*)d_in[5], (const float*)d_in[5], flags, h2, h2q, invn, N);

  // ---------- layer 3: h2(64) -> out(40), fused log_softmax ----------
  hipMemsetAsync(rowsum, 0, rd_span, stream);
  simq2_kernel<64><<<sgrid8, TB, 0, stream>>>(h2q, srcP, dstP, invn, wbuf, rowsum, degcnt, E, schunk8);
  node_a_kernel<<<nblk, TB, 0, stream>>>(rowsum, degcnt, sw, deg2, N);
  edge_b_kernel<<<eblk, TB, 0, stream>>>(wbuf, srcP, dstP, rowsum, deg2, E);
  node_b_kernel<<<nblk, TB, 0, stream>>>(deg2, dinv, N);
  transpose_kernel<<<(CP * D2 + TB - 1) / TB, TB, 0, stream>>>(
      (const unsigned short*)d_in[6], (const float*)d_in[6], flags, WT, D2, C, CP);
  gemmw_kernel<3, 2><<<mt4, TB, 0, stream>>>(h2, xf, xb, flags, 0, WT, hp, N, CP);
  aggw_lsm_kernel<<<nwav, TB, 0, stream>>>(
      hp, wbuf, srcP, off, dinv, sw,
      (const unsigned short*)d_in[7], (const float*)d_in[7], flags, d_out, N);
}

// Round 10
// 1240.955 us; speedup vs baseline: 2.5108x; 1.2702x over previous
//
#include <hip/hip_runtime.h>
#include <stdint.h>

typedef __attribute__((ext_vector_type(8))) _Float16 half8v;
typedef __attribute__((ext_vector_type(2))) _Float16 half2v;
typedef __attribute__((ext_vector_type(4))) float floatx4;

union H8 { uint4 u; half8v v; half2v h[4]; _Float16 e[8]; };
union H4 { uint2 u; half2v h[2]; _Float16 e[4]; };

__device__ __forceinline__ float bf2f(unsigned int u) {
  union { unsigned int i; float f; } x;
  x.i = u << 16;
  return x.f;
}

#if __has_builtin(__builtin_amdgcn_sdot4)
__device__ __forceinline__ int dot4i(int a, int b, int c) {
  return __builtin_amdgcn_sdot4(a, b, c, false);
}
#else
__device__ __forceinline__ int dot4i(int a, int b, int c) {
  #pragma unroll
  for (int i = 0; i < 4; i++)
    c += (int)(signed char)(a >> (8 * i)) * (int)(signed char)(b >> (8 * i));
  return c;
}
#endif

#if __has_builtin(__builtin_amdgcn_readlane)
__device__ __forceinline__ int rl(int v, int l) { return __builtin_amdgcn_readlane(v, l); }
#else
__device__ __forceinline__ int rl(int v, int l) { return __shfl(v, l, 64); }
#endif
__device__ __forceinline__ float rlf(float v, int l) {
  union { float f; int i; } x; x.f = v;
  x.i = rl(x.i, l);
  return x.f;
}

__device__ __forceinline__ float wave_sum(float v) {
  #pragma unroll
  for (int m = 32; m > 0; m >>= 1) v += __shfl_xor(v, m, 64);
  return v;
}

__device__ __forceinline__ float wave_max(float v) {
  #pragma unroll
  for (int m = 32; m > 0; m >>= 1) v = fmaxf(v, __shfl_xor(v, m, 64));
  return v;
}

__device__ __forceinline__ unsigned short f2bf(float f) {
  union { float f; unsigned int u; } x; x.f = f;
  unsigned int r = x.u + 0x7fffu + ((x.u >> 16) & 1u);
  return (unsigned short)(r >> 16);
}

// -------- dtype detection: flags[0]=edges int64, flags[1]=floats fp32 --------

__global__ void detect_kernel(const int* __restrict__ ei, const unsigned int* __restrict__ w1,
                              int* __restrict__ flags, int E) {
  __shared__ int nz, sane;
  if (threadIdx.x == 0) { nz = 0; sane = 0; }
  __syncthreads();
  for (int i = threadIdx.x; i < 2048; i += blockDim.x) {
    if (i < E && ei[2 * i + 1] != 0) atomicAdd(&nz, 1);
    union { unsigned int u; float f; } c; c.u = w1[i];
    float af = fabsf(c.f);
    if (c.f == c.f && af > 1e-10f && af < 1e10f) atomicAdd(&sane, 1);
  }
  __syncthreads();
  if (threadIdx.x == 0) {
    flags[0] = (nz == 0) ? 1 : 0;
    flags[1] = (sane > 1024) ? 1 : 0;
  }
}

// ---------------- CSR build (by dst) with inline edge decode ----------------

__global__ void count_kernel(const int* __restrict__ ei, const int* __restrict__ flags,
                             int* __restrict__ cnt, int E, int N) {
  int e = blockIdx.x * blockDim.x + threadIdx.x;
  if (e >= E) return;
  int d = flags[0] ? ei[2 * (E + e)] : ei[E + e];
  d = ((unsigned)d < (unsigned)N) ? d : 0;
  atomicAdd(&cnt[d], 1);
}

__global__ void scan1_kernel(const int* __restrict__ cnt, int* __restrict__ off,
                             int* __restrict__ bsum, int n) {
  __shared__ int buf[1024];
  int t = threadIdx.x;
  int i = blockIdx.x * 1024 + t;
  int v = (i < n) ? cnt[i] : 0;
  buf[t] = v;
  __syncthreads();
  for (int o = 1; o < 1024; o <<= 1) {
    int a = (t >= o) ? buf[t - o] : 0;
    __syncthreads();
    buf[t] += a;
    __syncthreads();
  }
  if (i < n) off[i + 1] = buf[t];
  if (t == 1023) bsum[blockIdx.x] = buf[1023];
}

__global__ void scan2_kernel(int* __restrict__ bsum, int nb) {
  __shared__ int buf[1024];
  int t = threadIdx.x;
  int v = (t < nb) ? bsum[t] : 0;
  buf[t] = v;
  __syncthreads();
  for (int o = 1; o < 1024; o <<= 1) {
    int a = (t >= o) ? buf[t - o] : 0;
    __syncthreads();
    buf[t] += a;
    __syncthreads();
  }
  if (t < nb) bsum[t] = buf[t];
}

// finalize off and seed cur (= final off) in one pass
__global__ void scan3_kernel(int* __restrict__ off, int* __restrict__ cur,
                             const int* __restrict__ bsum, int n) {
  int i = blockIdx.x * blockDim.x + threadIdx.x;
  if (i == 0) { off[0] = 0; cur[0] = 0; }
  if (i < n) {
    int b = i >> 10;
    int v = off[i + 1] + ((b > 0) ? bsum[b - 1] : 0);
    off[i + 1] = v;
    if (i + 1 < n) cur[i + 1] = v;
  }
}

__global__ void fill_kernel(const int* __restrict__ ei, const int* __restrict__ flags,
                            int* __restrict__ cur, int* __restrict__ srcP,
                            int* __restrict__ dstP, int E, int N) {
  int e = blockIdx.x * blockDim.x + threadIdx.x;
  if (e >= E) return;
  int s, d;
  if (flags[0]) { s = ei[2 * e]; d = ei[2 * (E + e)]; }
  else          { s = ei[e];     d = ei[E + e]; }
  s = ((unsigned)s < (unsigned)N) ? s : 0;
  d = ((unsigned)d < (unsigned)N) ? d : 0;
  int pos = atomicAdd(&cur[d], 1);
  srcP[pos] = s;
  dstP[pos] = d;
}

// -- layer-1 convert+norm: fp32/bf16 x -> f16 rows + int8 rows + invq --------

__global__ __launch_bounds__(256) void convert_norm_kernel(
    const float* __restrict__ xf, const unsigned short* __restrict__ xb,
    const int* __restrict__ flags, _Float16* __restrict__ xo,
    unsigned char* __restrict__ xq, float* __restrict__ invq, int n) {
  int row = blockIdx.x * 4 + (threadIdx.x >> 6);
  int lane = threadIdx.x & 63;
  if (row >= n) return;
  float ss = 0.f, mx = 0.f;
  float vals[8];
  H8 o;
  if (flags[1]) {
    const float4* vp = reinterpret_cast<const float4*>(xf + (size_t)row * 512) + lane * 2;
    float4 a = vp[0], b = vp[1];
    vals[0] = a.x; vals[1] = a.y; vals[2] = a.z; vals[3] = a.w;
    vals[4] = b.x; vals[5] = b.y; vals[6] = b.z; vals[7] = b.w;
  } else {
    uint4 v = *(reinterpret_cast<const uint4*>(xb + (size_t)row * 512) + lane);
    unsigned int a[4] = {v.x, v.y, v.z, v.w};
    #pragma unroll
    for (int i = 0; i < 4; i++) {
      vals[2 * i] = bf2f(a[i] & 0xffffu);
      vals[2 * i + 1] = bf2f(a[i] >> 16);
    }
  }
  #pragma unroll
  for (int i = 0; i < 8; i++) {
    ss += vals[i] * vals[i];
    mx = fmaxf(mx, fabsf(vals[i]));
    o.v[i] = (_Float16)vals[i];
  }
  *(reinterpret_cast<uint4*>(xo + (size_t)row * 512) + lane) = o.u;
  ss = wave_sum(ss);
  mx = wave_max(mx);
  float scale = (mx > 0.f) ? 127.0f / mx : 0.f;
  uint2 qo;
  unsigned int q0 = 0, q1 = 0;
  #pragma unroll
  for (int i = 0; i < 4; i++) {
    int q = (int)rintf(vals[i] * scale);
    q0 |= ((unsigned int)(q & 0xff)) << (8 * i);
  }
  #pragma unroll
  for (int i = 0; i < 4; i++) {
    int q = (int)rintf(vals[4 + i] * scale);
    q1 |= ((unsigned int)(q & 0xff)) << (8 * i);
  }
  qo.x = q0; qo.y = q1;
  *(reinterpret_cast<uint2*>(xq + (size_t)row * 512) + lane) = qo;
  if (lane == 0)
    invq[row] = (mx > 0.f && ss > 0.f) ? (mx / 127.0f) * rsqrtf(ss) : 0.f;
}

// fallback norm over raw x
__global__ __launch_bounds__(256) void norm8_kernel(const unsigned short* __restrict__ hb,
                                                    const float* __restrict__ hf,
                                                    const int* __restrict__ flags,
                                                    float* __restrict__ invn, int n) {
  int wid = blockIdx.x * 4 + (threadIdx.x >> 6);
  int lane = threadIdx.x & 63;
  if (wid >= n) return;
  float s = 0.f;
  if (flags[1]) {
    const float4* vp = reinterpret_cast<const float4*>(hf + (size_t)wid * 512) + lane * 2;
    float4 a = vp[0], b = vp[1];
    s = a.x*a.x + a.y*a.y + a.z*a.z + a.w*a.w + b.x*b.x + b.y*b.y + b.z*b.z + b.w*b.w;
  } else {
    uint4 v = *(reinterpret_cast<const uint4*>(hb + (size_t)wid * 512) + lane);
    unsigned int a[4] = {v.x, v.y, v.z, v.w};
    #pragma unroll
    for (int i = 0; i < 4; i++) {
      float lo = bf2f(a[i] & 0xffffu), hi = bf2f(a[i] >> 16);
      s += lo * lo + hi * hi;
    }
  }
  s = wave_sum(s);
  if (lane == 0) invn[wid] = (s == 0.f) ? 1.0f : rsqrtf(s);
}

// --- int8 cosine sim: 16-lane groups, 4 edges/wave x 2 batches, sdot4 ------

template<int RB>
__global__ __launch_bounds__(256) void simq2_kernel(const unsigned char* __restrict__ q,
                                                    const int* __restrict__ srcP,
                                                    const int* __restrict__ dstP,
                                                    const float* __restrict__ invq,
                                                    float* __restrict__ w,
                                                    float* __restrict__ rowsum,
                                                    float* __restrict__ degcnt,
                                                    int E, int chunk) {
  int nb = (blockIdx.x & 7) * chunk + (blockIdx.x >> 3);
  int lane = threadIdx.x & 63;
  int l = lane & 15, g = lane >> 4;
  int j0 = (nb * 4 + (threadIdx.x >> 6)) * 8;
  if (j0 >= E) return;
  int sj[2], tj[2];
  bool val[2];
  #pragma unroll
  for (int b = 0; b < 2; b++) {
    int j = j0 + b * 4 + g;
    val[b] = j < E;
    int jj = val[b] ? j : 0;
    sj[b] = srcP[jj];
    tj[b] = dstP[jj];
  }
  int acc[2];
  if constexpr (RB == 512) {
    uint4 sa[2][2], ta[2][2];
    #pragma unroll
    for (int b = 0; b < 2; b++) {
      const unsigned char* sp = q + (size_t)sj[b] * 512 + l * 16;
      const unsigned char* tp = q + (size_t)tj[b] * 512 + l * 16;
      sa[b][0] = *reinterpret_cast<const uint4*>(sp);
      sa[b][1] = *reinterpret_cast<const uint4*>(sp + 256);
      ta[b][0] = *reinterpret_cast<const uint4*>(tp);
      ta[b][1] = *reinterpret_cast<const uint4*>(tp + 256);
    }
    #pragma unroll
    for (int b = 0; b < 2; b++) {
      int a = 0;
      a = dot4i((int)sa[b][0].x, (int)ta[b][0].x, a);
      a = dot4i((int)sa[b][0].y, (int)ta[b][0].y, a);
      a = dot4i((int)sa[b][0].z, (int)ta[b][0].z, a);
      a = dot4i((int)sa[b][0].w, (int)ta[b][0].w, a);
      a = dot4i((int)sa[b][1].x, (int)ta[b][1].x, a);
      a = dot4i((int)sa[b][1].y, (int)ta[b][1].y, a);
      a = dot4i((int)sa[b][1].z, (int)ta[b][1].z, a);
      a = dot4i((int)sa[b][1].w, (int)ta[b][1].w, a);
      acc[b] = a;
    }
  } else if constexpr (RB == 256) {
    uint4 sa[2], ta[2];
    #pragma unroll
    for (int b = 0; b < 2; b++) {
      sa[b] = *reinterpret_cast<const uint4*>(q + (size_t)sj[b] * 256 + l * 16);
      ta[b] = *reinterpret_cast<const uint4*>(q + (size_t)tj[b] * 256 + l * 16);
    }
    #pragma unroll
    for (int b = 0; b < 2; b++) {
      int a = 0;
      a = dot4i((int)sa[b].x, (int)ta[b].x, a);
      a = dot4i((int)sa[b].y, (int)ta[b].y, a);
      a = dot4i((int)sa[b].z, (int)ta[b].z, a);
      a = dot4i((int)sa[b].w, (int)ta[b].w, a);
      acc[b] = a;
    }
  } else {  // RB == 64
    unsigned int sa[2], ta[2];
    #pragma unroll
    for (int b = 0; b < 2; b++) {
      sa[b] = *reinterpret_cast<const unsigned int*>(q + (size_t)sj[b] * 64 + l * 4);
      ta[b] = *reinterpret_cast<const unsigned int*>(q + (size_t)tj[b] * 64 + l * 4);
    }
    #pragma unroll
    for (int b = 0; b < 2; b++) acc[b] = dot4i((int)sa[b], (int)ta[b], 0);
  }
  #pragma unroll
  for (int m = 1; m < 16; m <<= 1) {
    acc[0] += __shfl_xor(acc[0], m, 64);
    acc[1] += __shfl_xor(acc[1], m, 64);
  }
  if (l == 0) {
    #pragma unroll
    for (int b = 0; b < 2; b++) {
      if (val[b]) {
        int j = j0 + b * 4 + g;
        float simv = (float)acc[b] * invq[sj[b]] * invq[tj[b]];
        float wv = (sj[b] != tj[b] && simv > 0.f) ? simv : 0.f;
        w[j] = wv;
        if (wv > 0.f) {
          atomicAdd(&rowsum[sj[b]], wv);
          atomicAdd(&degcnt[sj[b]], 1.0f);
        }
      }
    }
  }
}

// fallback layer-1 sim on raw x
__global__ __launch_bounds__(256) void simf_kernel(const unsigned short* __restrict__ hb,
                                                   const float* __restrict__ hf,
                                                   const int* __restrict__ flags,
                                                   const int* __restrict__ srcP,
                                                   const int* __restrict__ dstP,
                                                   const float* __restrict__ invn,
                                                   float* __restrict__ w,
                                                   float* __restrict__ rowsum,
                                                   float* __restrict__ degcnt, int E) {
  int j = blockIdx.x * 4 + (threadIdx.x >> 6);
  int lane = threadIdx.x & 63;
  if (j >= E) return;
  int s = srcP[j], t = dstP[j];
  float acc = 0.f;
  if (flags[1]) {
    const float4* ap = reinterpret_cast<const float4*>(hf + (size_t)s * 512) + lane * 2;
    const float4* bp = reinterpret_cast<const float4*>(hf + (size_t)t * 512) + lane * 2;
    float4 a0 = ap[0], a1 = ap[1], b0 = bp[0], b1 = bp[1];
    acc = a0.x*b0.x + a0.y*b0.y + a0.z*b0.z + a0.w*b0.w
        + a1.x*b1.x + a1.y*b1.y + a1.z*b1.z + a1.w*b1.w;
  } else {
    uint4 a = *(reinterpret_cast<const uint4*>(hb + (size_t)s * 512) + lane);
    uint4 b = *(reinterpret_cast<const uint4*>(hb + (size_t)t * 512) + lane);
    unsigned int av[4] = {a.x, a.y, a.z, a.w};
    unsigned int bv[4] = {b.x, b.y, b.z, b.w};
    #pragma unroll
    for (int i = 0; i < 4; i++)
      acc += bf2f(av[i] & 0xffffu) * bf2f(bv[i] & 0xffffu)
           + bf2f(av[i] >> 16) * bf2f(bv[i] >> 16);
  }
  acc = wave_sum(acc);
  if (lane == 0) {
    float simv = acc * invn[s] * invn[t];
    float wv = (s != t && simv > 0.f) ? simv : 0.f;
    w[j] = wv;
    if (wv > 0.f) {
      atomicAdd(&rowsum[s], wv);
      atomicAdd(&degcnt[s], 1.0f);
    }
  }
}

// ------ fused deg pass (CSR, wave-per-node): node_a + edge_b + node_b -------
// w -> ew = exp(w / rowsum[src]); deg2 = sw + sum(ew); sw, dinv out.

__global__ __launch_bounds__(256) void deg_kernel(
    float* __restrict__ w, const int* __restrict__ srcP, const int* __restrict__ off,
    const float* __restrict__ rowsum, const float* __restrict__ degcnt,
    float* __restrict__ sw, float* __restrict__ dinv, int n) {
  int i = blockIdx.x * 4 + (threadIdx.x >> 6);
  if (i >= n) return;
  int lane = threadIdx.x & 63;
  int e0 = off[i], e1 = off[i + 1];
  float sum = 0.f;
  for (int j = e0 + lane; j < e1; j += 64) {
    float wv = w[j];
    if (wv > 0.f) {
      // rowsum[src] >= wv > 0 (wv contributes to it), no div-by-zero
      float ew = expf(wv / rowsum[srcP[j]]);
      w[j] = ew;
      sum += ew;
    }
  }
  sum = wave_sum(sum);
  float swi = expf(1.0f / (degcnt[i] + 1.0f));
  if (lane == 0) {
    sw[i] = swi;
    dinv[i] = rsqrtf(swi + sum);
  }
}

// ---------------- GEMM (f16 MFMA) ----------------

// layers 2/3: plain n-major transpose
__global__ void transpose_kernel(const unsigned short* __restrict__ Wb,
                                 const float* __restrict__ Wf,
                                 const int* __restrict__ flags,
                                 _Float16* __restrict__ WT,
                                 int K, int Nc, int Npad) {
  int idx = blockIdx.x * blockDim.x + threadIdx.x;
  if (idx >= Npad * K) return;
  int nn = idx / K, k = idx - nn * K;
  _Float16 v = (_Float16)0.f;
  if (nn < Nc) {
    if (flags[1]) v = (_Float16)Wf[(size_t)k * Nc + nn];
    else          v = (_Float16)bf2f((unsigned int)Wb[(size_t)k * Nc + nn]);
  }
  WT[idx] = v;
}

// layer 1: k-blocked layout WTb[kk][nn][kidx], kk chunk = 256n x 32k = 8192
__global__ void transpose1_kernel(const unsigned short* __restrict__ Wb,
                                  const float* __restrict__ Wf,
                                  const int* __restrict__ flags,
                                  _Float16* __restrict__ WTb) {
  int idx = blockIdx.x * blockDim.x + threadIdx.x;
  if (idx >= 512 * 256) return;
  int kk = idx >> 13;
  int rem = idx & 8191;
  int nn = rem >> 5;
  int kidx = rem & 31;
  int k = kk * 32 + kidx;
  _Float16 v;
  if (flags[1]) v = (_Float16)Wf[k * 256 + nn];
  else          v = (_Float16)bf2f((unsigned int)Wb[k * 256 + nn]);
  WTb[idx] = v;
}

// layer-1 GEMM with LDS-staged B (4 waves share each 16KB B chunk)
__global__ __launch_bounds__(256) void gemm1_lds_kernel(
    const _Float16* __restrict__ Ah, const float* __restrict__ Af,
    const unsigned short* __restrict__ Abf, const int* __restrict__ flags,
    int useflags, const _Float16* __restrict__ BTb, _Float16* __restrict__ C,
    int M) {
  constexpr int NT = 16, KSTEPS = 16, K = 512, LS = 40;  // LS: padded k-stride (f16)
  __shared__ _Float16 bs[256 * LS];
  int t = threadIdx.x;
  int wid = t >> 6, lane = t & 63;
  int mt = blockIdx.x * 4 + wid;
  bool act = (mt * 16 < M);
  int r = lane & 15, quad = lane >> 4;
  int m0 = mt * 16;
  int mode = useflags ? (flags[1] ? 1 : 2) : 0;
  floatx4 acc[NT];
  #pragma unroll
  for (int nt = 0; nt < NT; nt++) acc[nt] = floatx4{0.f, 0.f, 0.f, 0.f};
  int arow = act ? (m0 + r) : 0;
  const uint4* ap = reinterpret_cast<const uint4*>(Ah + (size_t)arow * K);
  const float* af = Af + (size_t)arow * K + quad * 8;
  const unsigned short* ab = Abf + (size_t)arow * K + quad * 8;
  for (int kk = 0; kk < KSTEPS; kk++) {
    __syncthreads();
    {
      const uint4* bsrc = reinterpret_cast<const uint4*>(BTb + kk * 8192) + t * 4;
      uint4 b0 = bsrc[0], b1 = bsrc[1], b2 = bsrc[2], b3 = bsrc[3];
      uint4* bdst = reinterpret_cast<uint4*>(bs + t * LS);
      bdst[0] = b0; bdst[1] = b1; bdst[2] = b2; bdst[3] = b3;
    }
    __syncthreads();
    if (act) {
      H8 a;
      if (mode == 1) {
        float4 x0 = *reinterpret_cast<const float4*>(af + kk * 32);
        float4 x1 = *reinterpret_cast<const float4*>(af + kk * 32 + 4);
        a.v[0] = (_Float16)x0.x; a.v[1] = (_Float16)x0.y;
        a.v[2] = (_Float16)x0.z; a.v[3] = (_Float16)x0.w;
        a.v[4] = (_Float16)x1.x; a.v[5] = (_Float16)x1.y;
        a.v[6] = (_Float16)x1.z; a.v[7] = (_Float16)x1.w;
      } else if (mode == 2) {
        uint4 u = *reinterpret_cast<const uint4*>(ab + kk * 32);
        unsigned int uu[4] = {u.x, u.y, u.z, u.w};
        #pragma unroll
        for (int i = 0; i < 4; i++) {
          a.v[2 * i] = (_Float16)bf2f(uu[i] & 0xffffu);
          a.v[2 * i + 1] = (_Float16)bf2f(uu[i] >> 16);
        }
      } else {
        a.u = ap[(kk << 2) + quad];
      }
      #pragma unroll
      for (int nt = 0; nt < NT; nt++) {
        H8 b;
        b.u = *reinterpret_cast<const uint4*>(bs + (nt * 16 + r) * LS + quad * 8);
        acc[nt] = __builtin_amdgcn_mfma_f32_16x16x32_f16(a.v, b.v, acc[nt], 0, 0, 0);
      }
    }
  }
  if (act) {
    #pragma unroll
    for (int nt = 0; nt < NT; nt++) {
      #pragma unroll
      for (int i = 0; i < 4; i++)
        C[(size_t)(m0 + quad * 4 + i) * 256 + nt * 16 + r] = (_Float16)acc[nt][i];
    }
  }
}

// layers 2/3 wide GEMM (B small, reads from L2 directly)
template<int NT, int KSTEPS>
__global__ __launch_bounds__(256) void gemmw_kernel(const _Float16* __restrict__ Ah,
                                                    const _Float16* __restrict__ BT,
                                                    _Float16* __restrict__ C,
                                                    int M, int Npad) {
  constexpr int K = KSTEPS * 32;
  int mt = blockIdx.x * 4 + (threadIdx.x >> 6);
  if (mt * 16 >= M) return;
  int lane = threadIdx.x & 63;
  int r = lane & 15, quad = lane >> 4;
  int m0 = mt * 16;
  floatx4 acc[NT];
  #pragma unroll
  for (int nt = 0; nt < NT; nt++) acc[nt] = floatx4{0.f, 0.f, 0.f, 0.f};
  const uint4* ap = reinterpret_cast<const uint4*>(Ah + (size_t)(m0 + r) * K);
  for (int kk = 0; kk < KSTEPS; kk++) {
    H8 a;
    a.u = ap[(kk << 2) + quad];
    #pragma unroll
    for (int nt = 0; nt < NT; nt++) {
      H8 b;
      b.u = *reinterpret_cast<const uint4*>(BT + (size_t)(nt * 16 + r) * K + kk * 32 + quad * 8);
      acc[nt] = __builtin_amdgcn_mfma_f32_16x16x32_f16(a.v, b.v, acc[nt], 0, 0, 0);
    }
  }
  #pragma unroll
  for (int nt = 0; nt < NT; nt++) {
    #pragma unroll
    for (int i = 0; i < 4; i++)
      C[(size_t)(m0 + quad * 4 + i) * Npad + nt * 16 + r] = (_Float16)acc[nt][i];
  }
}

// ------- aggregation: wave-per-node, scalar broadcast, no LDS/barriers -------

template<int NC, int STRIDE, int VEC, bool DOQ>
__global__ __launch_bounds__(256) void aggw_relu_kernel(
    const _Float16* __restrict__ hp, const float* __restrict__ ew,
    const int* __restrict__ srcP, const int* __restrict__ off,
    const float* __restrict__ dinv, const float* __restrict__ sw,
    const unsigned short* __restrict__ biasb, const float* __restrict__ biasf,
    const int* __restrict__ flags, _Float16* __restrict__ out,
    unsigned char* __restrict__ qout, float* __restrict__ invn, int n) {
  constexpr int ACT = NC / VEC;
  int i = blockIdx.x * 4 + (threadIdx.x >> 6);
  if (i >= n) return;
  int lane = threadIdx.x & 63;
  float di = dinv[i];
  float sii = sw[i] * di * di;
  float acc[VEC];
  #pragma unroll
  for (int v = 0; v < VEC; v++) acc[v] = 0.f;
  if (lane < ACT) {
    if constexpr (VEC == 4) {
      H4 hv;
      hv.u = *reinterpret_cast<const uint2*>(hp + (size_t)i * STRIDE + lane * 4);
      #pragma unroll
      for (int v = 0; v < 4; v++) acc[v] = sii * (float)hv.e[v];
    } else {
      acc[0] = sii * (float)hp[(size_t)i * STRIDE + lane];
    }
  }
  int e0 = off[i], e1 = off[i + 1];
  for (int base = e0; base < e1; base += 64) {
    int j = base + lane;
    int sreg = 0;
    float creg = 0.f;
    if (j < e1) {
      sreg = srcP[j];
      float e = ew[j];
      if (e != 0.f) creg = e * dinv[sreg] * di;
    }
    int m = min(64, e1 - base);
    for (int k = 0; k < m; k++) {
      float cfk = rlf(creg, k);
      if (cfk != 0.f) {
        int sk = rl(sreg, k);
        if (lane < ACT) {
          if constexpr (VEC == 4) {
            H4 hv;
            hv.u = *reinterpret_cast<const uint2*>(hp + (size_t)sk * STRIDE + lane * 4);
            #pragma unroll
            for (int v = 0; v < 4; v++) acc[v] += cfk * (float)hv.e[v];
          } else {
            acc[0] += cfk * (float)hp[(size_t)sk * STRIDE + lane];
          }
        }
      }
    }
  }
  float nrm = 0.f, lmax = 0.f;
  float xv[VEC];
  if (lane < ACT) {
    if constexpr (VEC == 4) {
      H4 ov;
      #pragma unroll
      for (int v = 0; v < 4; v++) {
        int c = lane * 4 + v;
        float bb = flags[1] ? biasf[c] : bf2f((unsigned int)biasb[c]);
        float x = acc[v] + bb;
        x = x > 0.f ? x : 0.f;
        xv[v] = x;
        ov.e[v] = (_Float16)x;
        nrm += x * x;
        lmax = fmaxf(lmax, x);
      }
      *reinterpret_cast<uint2*>(out + (size_t)i * NC + lane * 4) = ov.u;
    } else {
      float bb = flags[1] ? biasf[lane] : bf2f((unsigned int)biasb[lane]);
      float x = acc[0] + bb;
      x = x > 0.f ? x : 0.f;
      xv[0] = x;
      out[(size_t)i * NC + lane] = (_Float16)x;
      nrm = x * x;
      lmax = x;
    }
  }
  nrm = wave_sum(nrm);
  if constexpr (DOQ) {
    float mx = wave_max(lmax);
    float scale = (mx > 0.f) ? 127.0f / mx : 0.f;
    if (lane < ACT) {
      if constexpr (VEC == 4) {
        unsigned int qw = 0;
        #pragma unroll
        for (int v = 0; v < 4; v++) {
          int qq = (int)(xv[v] * scale + 0.5f);
          qw |= ((unsigned int)(qq & 0xff)) << (8 * v);
        }
        *reinterpret_cast<unsigned int*>(qout + (size_t)i * NC + lane * 4) = qw;
      } else {
        qout[(size_t)i * NC + lane] = (unsigned char)(int)(xv[0] * scale + 0.5f);
      }
    }
    if (lane == 0)
      invn[i] = (mx > 0.f && nrm > 0.f) ? (mx / 127.0f) * rsqrtf(nrm) : 0.f;
  } else {
    if (lane == 0) invn[i] = (nrm == 0.f) ? 1.0f : rsqrtf(nrm);
  }
}

__global__ __launch_bounds__(256) void aggw_lsm_kernel(
    const _Float16* __restrict__ hp, const float* __restrict__ ew,
    const int* __restrict__ srcP, const int* __restrict__ off,
    const float* __restrict__ dinv, const float* __restrict__ sw,
    const unsigned short* __restrict__ biasb, const float* __restrict__ biasf,
    const int* __restrict__ flags, void* __restrict__ outv, int n) {
  constexpr int NC = 40, STRIDE = 48;
  int i = blockIdx.x * 4 + (threadIdx.x >> 6);
  if (i >= n) return;
  int lane = threadIdx.x & 63;
  float di = dinv[i];
  float acc = 0.f;
  if (lane < NC) acc = sw[i] * di * di * (float)hp[(size_t)i * STRIDE + lane];
  int e0 = off[i], e1 = off[i + 1];
  for (int base = e0; base < e1; base += 64) {
    int j = base + lane;
    int sreg = 0;
    float creg = 0.f;
    if (j < e1) {
      sreg = srcP[j];
      float e = ew[j];
      if (e != 0.f) creg = e * dinv[sreg] * di;
    }
    int m = min(64, e1 - base);
    for (int k = 0; k < m; k++) {
      float cfk = rlf(creg, k);
      if (cfk != 0.f) {
        int sk = rl(sreg, k);
        if (lane < NC) acc += cfk * (float)hp[(size_t)sk * STRIDE + lane];
      }
    }
  }
  int f32 = flags[1];
  float bb = 0.f;
  if (lane < NC) bb = f32 ? biasf[lane] : bf2f((unsigned int)biasb[lane]);
  float v = (lane < NC) ? acc + bb : -3.0e38f;
  float vm = wave_max(v);
  float ex = (lane < NC) ? expf(v - vm) : 0.f;
  float se = wave_sum(ex);
  float ls = logf(se);
  if (lane < NC) {
    float r = v - vm - ls;
    if (f32) ((float*)outv)[(size_t)i * NC + lane] = r;
    else ((unsigned short*)outv)[(size_t)i * NC + lane] = f2bf(r);
  }
}

// ---------------- host ----------------

extern "C" void kernel_launch(void* const* d_in, const int* in_sizes, int n_in,
                              void* d_out, int out_size, void* d_ws, size_t ws_size,
                              hipStream_t stream) {
  const unsigned short* xb = (const unsigned short*)d_in[0];
  const float* xf          = (const float*)d_in[0];
  const int* ei            = (const int*)d_in[1];

  const int H  = in_sizes[3];            // 256
  const int F  = in_sizes[2] / H;        // 512
  const int D2 = in_sizes[5];            // 64
  const int C  = in_sizes[7];            // 40
  const int N  = in_sizes[0] / F;        // 50000
  const int E  = in_sizes[1] / 2;        // 1600000
  const int CP = 48;

  char* p = (char*)d_ws;
  auto alloc = [&](size_t bytes) -> char* {
    char* r = p;
    p += (bytes + 255) & ~(size_t)255;
    return r;
  };
  int*   srcP   = (int*)alloc((size_t)E * 4 + 32);
  int*   dstP   = (int*)alloc((size_t)E * 4 + 32);
  float* wbuf   = (float*)alloc((size_t)E * 4);
  int*   off    = (int*)alloc((size_t)(N + 1) * 4);
  int*   cur    = (int*)alloc((size_t)N * 4);
  float* invn   = (float*)alloc((size_t)N * 4);
  float* rowsum = (float*)alloc((size_t)N * 4);
  float* degcnt = (float*)alloc((size_t)N * 4);
  float* sw     = (float*)alloc((size_t)N * 4);
  float* dinv   = (float*)alloc((size_t)N * 4);
  int*   flags  = (int*)alloc(256);
  int*   bsum   = (int*)alloc(4096 * 4);
  _Float16* WT  = (_Float16*)alloc((size_t)256 * 512 * 2);
  _Float16* hp  = (_Float16*)alloc((size_t)N * 256 * 2);
  size_t used = (size_t)(p - (char*)d_ws);
  size_t xh_bytes = (size_t)N * 512 * 2;
  bool big = (used + xh_bytes + 256) <= ws_size;
  _Float16* xh = big ? (_Float16*)alloc(xh_bytes) : hp;

  unsigned char* xq = (unsigned char*)hp;                         // N*512 B
  _Float16* h1 = (_Float16*)d_in[0];                              // N*512 B (f16)
  unsigned char* h1q = (unsigned char*)d_in[0] + (size_t)N * 512; // N*256 B
  unsigned char* h2q = (unsigned char*)d_in[0] + (size_t)N * 768; // N*64 B
  _Float16* h2 = hp + (size_t)N * 64;
  size_t rd_span = (size_t)((char*)degcnt - (char*)rowsum) + (size_t)N * 4;

  const int TB = 256;
  int nblk = (N + TB - 1) / TB;
  int eblk = (E + TB - 1) / TB;
  int nwav = (N + 3) / 4;
  int ewav = (E + 3) / 4;
  int mt4  = (N / 16 + 3) / 4;
  int nb1024 = (N + 1023) / 1024;
  int sblocks8 = (E + 31) / 32;
  int schunk8 = (sblocks8 + 7) / 8;
  int sgrid8 = schunk8 * 8;

  detect_kernel<<<1, 256, 0, stream>>>(ei, (const unsigned int*)d_in[2], flags, E);

  hipMemsetAsync(cur, 0, (size_t)N * 4, stream);
  count_kernel<<<eblk, TB, 0, stream>>>(ei, flags, cur, E, N);
  scan1_kernel<<<nb1024, 1024, 0, stream>>>(cur, off, bsum, N);
  scan2_kernel<<<1, 1024, 0, stream>>>(bsum, nb1024);
  scan3_kernel<<<nblk, TB, 0, stream>>>(off, cur, bsum, N);
  fill_kernel<<<eblk, TB, 0, stream>>>(ei, flags, cur, srcP, dstP, E, N);

  // ---------- layer 1: x(512) -> h1(256) ----------
  hipMemsetAsync(rowsum, 0, rd_span, stream);
  if (big) {
    convert_norm_kernel<<<nwav, TB, 0, stream>>>(xf, xb, flags, xh, xq, invn, N);
    simq2_kernel<512><<<sgrid8, TB, 0, stream>>>(xq, srcP, dstP, invn, wbuf, rowsum, degcnt, E, schunk8);
  } else {
    norm8_kernel<<<nwav, TB, 0, stream>>>(xb, xf, flags, invn, N);
    simf_kernel<<<ewav, TB, 0, stream>>>(xb, xf, flags, srcP, dstP, invn, wbuf, rowsum, degcnt, E);
  }
  deg_kernel<<<nwav, TB, 0, stream>>>(wbuf, srcP, off, rowsum, degcnt, sw, dinv, N);
  transpose1_kernel<<<(512 * 256 + TB - 1) / TB, TB, 0, stream>>>(
      (const unsigned short*)d_in[2], (const float*)d_in[2], flags, WT);
  gemm1_lds_kernel<<<mt4, TB, 0, stream>>>(
      xh, xf, xb, flags, big ? 0 : 1, WT, hp, N);
  aggw_relu_kernel<256, 256, 4, true><<<nwav, TB, 0, stream>>>(
      hp, wbuf, srcP, off, dinv, sw,
      (const unsigned short*)d_in[3], (const float*)d_in[3], flags, h1, h1q, invn, N);

  // ---------- layer 2: h1(256) -> h2(64) ----------
  hipMemsetAsync(rowsum, 0, rd_span, stream);
  simq2_kernel<256><<<sgrid8, TB, 0, stream>>>(h1q, srcP, dstP, invn, wbuf, rowsum, degcnt, E, schunk8);
  deg_kernel<<<nwav, TB, 0, stream>>>(wbuf, srcP, off, rowsum, degcnt, sw, dinv, N);
  transpose_kernel<<<(D2 * H + TB - 1) / TB, TB, 0, stream>>>(
      (const unsigned short*)d_in[4], (const float*)d_in[4], flags, WT, H, D2, D2);
  gemmw_kernel<4, 8><<<mt4, TB, 0, stream>>>(h1, WT, hp, N, D2);
  aggw_relu_kernel<64, 64, 1, true><<<nwav, TB, 0, stream>>>(
      hp, wbuf, srcP, off, dinv, sw,
      (const unsigned short*)d_in[5], (const float*)d_in[5], flags, h2, h2q, invn, N);

  // ---------- layer 3: h2(64) -> out(40), fused log_softmax ----------
  hipMemsetAsync(rowsum, 0, rd_span, stream);
  simq2_kernel<64><<<sgrid8, TB, 0, stream>>>(h2q, srcP, dstP, invn, wbuf, rowsum, degcnt, E, schunk8);
  deg_kernel<<<nwav, TB, 0, stream>>>(wbuf, srcP, off, rowsum, degcnt, sw, dinv, N);
  transpose_kernel<<<(CP * D2 + TB - 1) / TB, TB, 0, stream>>>(
      (const unsigned short*)d_in[6], (const float*)d_in[6], flags, WT, D2, C, CP);
  gemmw_kernel<3, 2><<<mt4, TB, 0, stream>>>(h2, WT, hp, N, CP);
  aggw_lsm_kernel<<<nwav, TB, 0, stream>>>(
      hp, wbuf, srcP, off, dinv, sw,
      (const unsigned short*)d_in[7], (const float*)d_in[7], flags, d_out, N);
}